// Round 1
// baseline (4633.614 us; speedup 1.0000x reference)
//
#include <hip/hip_runtime.h>
#include <math.h>

#define TPB 256

constexpr int Bc = 2, Tc = 2048, Ec = 1024, QKVc = 1024, Hc = 16, DHc = 64;
constexpr long BT = (long)Bc * Tc;     // 4096
constexpr int WR = 5 * QKVc + Ec;      // 6144
constexpr float F32_EPS = 1.1920928955078125e-07f;
constexpr int NCH = 16, CHL = Tc / NCH; // aft cumsum chunks

// ---------------- global std (ddof=1) -> scale = rs/(std+1e-8) ----------------
__global__ void k_std_partial(const float* __restrict__ p, long n, float* __restrict__ out) {
    __shared__ float ls[TPB], lss[TPB];
    float s = 0.f, ss = 0.f;
    for (long i = (long)blockIdx.x * TPB + threadIdx.x; i < n; i += (long)gridDim.x * TPB) {
        float v = p[i]; s += v; ss += v * v;
    }
    ls[threadIdx.x] = s; lss[threadIdx.x] = ss; __syncthreads();
    for (int o = 128; o > 0; o >>= 1) {
        if (threadIdx.x < o) { ls[threadIdx.x] += ls[threadIdx.x + o]; lss[threadIdx.x] += lss[threadIdx.x + o]; }
        __syncthreads();
    }
    if (threadIdx.x == 0) { out[blockIdx.x] = ls[0]; out[gridDim.x + blockIdx.x] = lss[0]; }
}

__global__ void k_std_final(const float* __restrict__ part, float n, float rs, float* __restrict__ scale) {
    __shared__ float ls[TPB], lss[TPB];
    ls[threadIdx.x] = part[threadIdx.x];
    lss[threadIdx.x] = part[TPB + threadIdx.x];
    __syncthreads();
    for (int o = 128; o > 0; o >>= 1) {
        if (threadIdx.x < o) { ls[threadIdx.x] += ls[threadIdx.x + o]; lss[threadIdx.x] += lss[threadIdx.x + o]; }
        __syncthreads();
    }
    if (threadIdx.x == 0) {
        float var = (lss[0] - ls[0] * ls[0] / n) / (n - 1.0f);
        scale[0] = rs / (sqrtf(fmaxf(var, 0.0f)) + 1e-8f);
    }
}

// ---------------- rmsnorm over 1024 cols (256 thr * float4) ----------------
__global__ void k_rms1024(const float* __restrict__ in, float* __restrict__ out, long ldin, long ldout) {
    __shared__ float red[TPB];
    long row = blockIdx.x;
    float4 v = *(const float4*)(in + row * ldin + threadIdx.x * 4);
    float ss = v.x * v.x + v.y * v.y + v.z * v.z + v.w * v.w;
    red[threadIdx.x] = ss; __syncthreads();
    for (int o = 128; o > 0; o >>= 1) {
        if (threadIdx.x < o) red[threadIdx.x] += red[threadIdx.x + o];
        __syncthreads();
    }
    float sc = rsqrtf(red[0] / 1024.0f + F32_EPS);
    float4 o4; o4.x = v.x * sc; o4.y = v.y * sc; o4.z = v.z * sc; o4.w = v.w * sc;
    *(float4*)(out + row * ldout + threadIdx.x * 4) = o4;
}

// ---------------- generic fp32 GEMM: C[M,N] = s*A?B? (+add) ----------------
// LA=0: A is MxK row-major (lda=K-ish). LA=1: A is KxM row-major.
// LB=0: B is KxN row-major.           LB=1: B is NxK row-major (i.e. B^T).
// Batched via blockIdx.z; optional split-K (nsplit>1): z = batch*nsplit+sp,
// K arg is per-split length, C offset sp*sSplit.
template<int LA, int LB>
__global__ __launch_bounds__(256)
void k_gemm(int M, int N, int K,
            const float* __restrict__ A, long lda, long sA,
            const float* __restrict__ B, long ldb, long sB,
            float* __restrict__ C, long ldc, long sC, long sSplit, int nsplit,
            const float* __restrict__ scale_ptr, float fscale,
            const float* __restrict__ addp, long ldadd) {
    __shared__ float As[32][64];
    __shared__ float Bs[32][64];
    int bz = blockIdx.z;
    int batch = bz, sp = 0;
    if (nsplit > 1) { batch = bz / nsplit; sp = bz - batch * nsplit; }
    const float* Ap = A + (long)batch * sA + (LA ? (long)sp * K * lda : (long)sp * K);
    const float* Bp = B + (long)batch * sB + (LB ? (long)sp * K : (long)sp * K * ldb);
    float* Cp = C + (long)batch * sC + (long)sp * sSplit;
    int m0 = blockIdx.y * 64, n0 = blockIdx.x * 64;
    int tid = threadIdx.x;
    int ty = tid >> 4, tx = tid & 15;
    float acc[4][4] = {{0.f}};
    for (int k0 = 0; k0 < K; k0 += 32) {
        if (LA == 0) {
            #pragma unroll
            for (int u = 0; u < 2; ++u) {
                int idx = tid + u * 256;
                int r = idx >> 3, c = idx & 7;
                float4 v = *(const float4*)(Ap + (long)(m0 + r) * lda + k0 + c * 4);
                As[c * 4 + 0][r] = v.x; As[c * 4 + 1][r] = v.y; As[c * 4 + 2][r] = v.z; As[c * 4 + 3][r] = v.w;
            }
        } else {
            #pragma unroll
            for (int u = 0; u < 2; ++u) {
                int idx = tid + u * 256;
                int r = idx >> 4, c = idx & 15;
                float4 v = *(const float4*)(Ap + (long)(k0 + r) * lda + m0 + c * 4);
                *(float4*)&As[r][c * 4] = v;
            }
        }
        if (LB == 1) {
            #pragma unroll
            for (int u = 0; u < 2; ++u) {
                int idx = tid + u * 256;
                int r = idx >> 3, c = idx & 7;
                float4 v = *(const float4*)(Bp + (long)(n0 + r) * ldb + k0 + c * 4);
                Bs[c * 4 + 0][r] = v.x; Bs[c * 4 + 1][r] = v.y; Bs[c * 4 + 2][r] = v.z; Bs[c * 4 + 3][r] = v.w;
            }
        } else {
            #pragma unroll
            for (int u = 0; u < 2; ++u) {
                int idx = tid + u * 256;
                int r = idx >> 4, c = idx & 15;
                float4 v = *(const float4*)(Bp + (long)(k0 + r) * ldb + n0 + c * 4);
                *(float4*)&Bs[r][c * 4] = v;
            }
        }
        __syncthreads();
        #pragma unroll
        for (int kk = 0; kk < 32; ++kk) {
            float4 a = *(const float4*)&As[kk][ty * 4];
            float4 b = *(const float4*)&Bs[kk][tx * 4];
            float av[4] = {a.x, a.y, a.z, a.w}, bv[4] = {b.x, b.y, b.z, b.w};
            #pragma unroll
            for (int i = 0; i < 4; ++i)
                #pragma unroll
                for (int j = 0; j < 4; ++j) acc[i][j] += av[i] * bv[j];
        }
        __syncthreads();
    }
    float s = fscale * (scale_ptr ? scale_ptr[0] : 1.0f);
    #pragma unroll
    for (int i = 0; i < 4; ++i) {
        long row = m0 + ty * 4 + i;
        float4 o;
        o.x = acc[i][0] * s; o.y = acc[i][1] * s; o.z = acc[i][2] * s; o.w = acc[i][3] * s;
        if (addp) {
            float4 ad = *(const float4*)(addp + row * ldadd + n0 + tx * 4);
            o.x += ad.x; o.y += ad.y; o.z += ad.z; o.w += ad.w;
        }
        *(float4*)(Cp + row * ldc + n0 + tx * 4) = o;
    }
}

// ---------------- AFT gated cumsum, 3-pass chunked ----------------
__global__ void k_aft_p1(const float* __restrict__ qkv, float* __restrict__ cw, float* __restrict__ cs) {
    int id = blockIdx.x * TPB + threadIdx.x;   // 2048*NCH threads
    int bc = id & 2047, ch = id >> 11;
    int b = bc >> 10, c = bc & 1023;
    const float* base = qkv + ((long)(b * Tc + ch * CHL)) * 3072 + c;
    float sw = 0.f, sv = 0.f;
    for (int i = 0; i < CHL; ++i) {
        float k = base[1024], v = base[2048];
        float e = expf(k);
        sw += e; sv += e * v;
        base += 3072;
    }
    cw[ch * 2048 + bc] = sw; cs[ch * 2048 + bc] = sv;
}

__global__ void k_aft_p2(float* __restrict__ cw, float* __restrict__ cs) {
    int bc = blockIdx.x * TPB + threadIdx.x;   // 2048 threads
    float rw = 0.f, rv = 0.f;
    for (int ch = 0; ch < NCH; ++ch) {
        long idx = (long)ch * 2048 + bc;
        float tw = cw[idx], tv = cs[idx];
        cw[idx] = rw; cs[idx] = rv; rw += tw; rv += tv;
    }
}

__global__ void k_aft_p3(const float* __restrict__ qkv, const float* __restrict__ cw,
                         const float* __restrict__ cs, float* __restrict__ y) {
    int id = blockIdx.x * TPB + threadIdx.x;
    int bc = id & 2047, ch = id >> 11;
    int b = bc >> 10, c = bc & 1023;
    long t0 = (long)b * Tc + ch * CHL;
    const float* base = qkv + t0 * 3072 + c;
    float* yp = y + t0 * 1024 + c;
    float aw = cw[ch * 2048 + bc], av = cs[ch * 2048 + bc];
    for (int i = 0; i < CHL; ++i) {
        float q = base[0], k = base[1024], v = base[2048];
        float e = expf(k);
        av += e * v; aw += e;
        float sig = 1.0f / (1.0f + expf(-q));
        yp[0] = sig * av / (aw + 1e-6f);
        base += 3072; yp += 1024;
    }
}

// ---------------- u * silu(v) from packed uv ----------------
__global__ void k_silu_gate(const float* __restrict__ uv, float* __restrict__ g, long n4) {
    long i = (long)blockIdx.x * TPB + threadIdx.x;
    if (i >= n4) return;
    long r = i >> 8, c4 = i & 255;
    float4 u = *(const float4*)(uv + r * 2048 + c4 * 4);
    float4 v = *(const float4*)(uv + r * 2048 + 1024 + c4 * 4);
    float4 o;
    o.x = u.x * v.x / (1.f + expf(-v.x));
    o.y = u.y * v.y / (1.f + expf(-v.y));
    o.z = u.z * v.z / (1.f + expf(-v.z));
    o.w = u.w * v.w / (1.f + expf(-v.w));
    *(float4*)(g + r * 1024 + c4 * 4) = o;
}

// ---------------- w = wT*s*silu(w) + w ----------------
__global__ void k_wupdate(float* __restrict__ w, const float* __restrict__ p,
                          const float* __restrict__ scale, long n4) {
    long i = (long)blockIdx.x * TPB + threadIdx.x;
    if (i >= n4) return;
    float s = scale[0];
    float4 wv = *(const float4*)(w + i * 4);
    float4 pv = *(const float4*)(p + i * 4);
    float4 o;
    o.x = pv.x * s * (wv.x / (1.f + expf(-wv.x))) + wv.x;
    o.y = pv.y * s * (wv.y / (1.f + expf(-wv.y))) + wv.y;
    o.z = pv.z * s * (wv.z / (1.f + expf(-wv.z))) + wv.z;
    o.w = pv.w * s * (wv.w / (1.f + expf(-wv.w))) + wv.w;
    *(float4*)(w + i * 4) = o;
}

// ---------------- row softmax (optional causal; zeros masked cols) ----------------
__global__ void k_softmax(float* __restrict__ buf, int cols, long ld, long slab, int causal) {
    __shared__ float red[TPB];
    long row = blockIdx.x;
    float* p = buf + (long)blockIdx.y * slab + row * ld;
    int limit = causal ? (int)row + 1 : cols;
    float m = -3.0e38f;
    for (int c = threadIdx.x; c < limit; c += TPB) m = fmaxf(m, p[c]);
    red[threadIdx.x] = m; __syncthreads();
    for (int o = 128; o > 0; o >>= 1) {
        if (threadIdx.x < o) red[threadIdx.x] = fmaxf(red[threadIdx.x], red[threadIdx.x + o]);
        __syncthreads();
    }
    m = red[0]; __syncthreads();
    float sum = 0.f;
    for (int c = threadIdx.x; c < limit; c += TPB) sum += expf(p[c] - m);
    red[threadIdx.x] = sum; __syncthreads();
    for (int o = 128; o > 0; o >>= 1) {
        if (threadIdx.x < o) red[threadIdx.x] += red[threadIdx.x + o];
        __syncthreads();
    }
    float inv = 1.0f / red[0];
    for (int c = threadIdx.x; c < cols; c += TPB) p[c] = (c < limit) ? expf(p[c] - m) * inv : 0.0f;
}

// ---------------- tea: rotary + per-head rmsnorm + split to (B,H,T,64) ----------------
__global__ void k_rot_split(const float* __restrict__ qkvp, const float* __restrict__ cosp,
                            const float* __restrict__ sinp, float* __restrict__ hq,
                            float* __restrict__ hk, float* __restrict__ hv) {
    __shared__ float row[3072];
    __shared__ float cs[32], sn[32];
    int bt = blockIdx.x;
    int b = bt >> 11, t = bt & 2047;
    const float* src = qkvp + (long)bt * 3072;
    #pragma unroll
    for (int u = 0; u < 3; ++u) {
        int idx = threadIdx.x + u * 256;
        *(float4*)&row[idx * 4] = *(const float4*)(src + idx * 4);
    }
    if (threadIdx.x < 32) { cs[threadIdx.x] = cosp[t * 32 + threadIdx.x]; sn[threadIdx.x] = sinp[t * 32 + threadIdx.x]; }
    __syncthreads();
    int h = threadIdx.x >> 4, li = threadIdx.x & 15;
    int base = h * 192;
    long obase = ((long)(b * Hc + h) * Tc + t) * 64 + li * 4;
    // q with rotary + rmsnorm(64)
    {
        float r[4]; float ss = 0.f;
        #pragma unroll
        for (int j = 0; j < 4; ++j) {
            int d = li * 4 + j;
            float val = (d < 32) ? (row[base + d] * cs[d] + row[base + d + 32] * sn[d])
                                 : (-row[base + d - 32] * sn[d - 32] + row[base + d] * cs[d - 32]);
            r[j] = val; ss += val * val;
        }
        ss += __shfl_xor(ss, 1); ss += __shfl_xor(ss, 2); ss += __shfl_xor(ss, 4); ss += __shfl_xor(ss, 8);
        float sc = rsqrtf(ss / 64.0f + F32_EPS);
        float4 o; o.x = r[0] * sc; o.y = r[1] * sc; o.z = r[2] * sc; o.w = r[3] * sc;
        *(float4*)(hq + obase) = o;
    }
    // k with rotary + rmsnorm(64)
    {
        int kb = base + 64;
        float r[4]; float ss = 0.f;
        #pragma unroll
        for (int j = 0; j < 4; ++j) {
            int d = li * 4 + j;
            float val = (d < 32) ? (row[kb + d] * cs[d] + row[kb + d + 32] * sn[d])
                                 : (-row[kb + d - 32] * sn[d - 32] + row[kb + d] * cs[d - 32]);
            r[j] = val; ss += val * val;
        }
        ss += __shfl_xor(ss, 1); ss += __shfl_xor(ss, 2); ss += __shfl_xor(ss, 4); ss += __shfl_xor(ss, 8);
        float sc = rsqrtf(ss / 64.0f + F32_EPS);
        float4 o; o.x = r[0] * sc; o.y = r[1] * sc; o.z = r[2] * sc; o.w = r[3] * sc;
        *(float4*)(hk + obase) = o;
    }
    // v copy
    {
        float4 v = *(const float4*)&row[base + 128 + li * 4];
        *(float4*)(hv + obase) = v;
    }
}

// ---------------- PV split-K merge + head re-interleave ----------------
__global__ void k_pv_merge(const float* __restrict__ part, float* __restrict__ yb, int bh0) {
    int i = blockIdx.x * TPB + threadIdx.x;     // 2*64*2048
    int d = i & 63, t = (i >> 6) & 2047, bhl = i >> 17;
    const float* p = part + (long)bhl * (8L * 64 * 2048) + (long)d * 2048 + t;
    float sum = 0.f;
    #pragma unroll
    for (int sp = 0; sp < 8; ++sp) sum += p[(long)sp * 64 * 2048];
    int bh = bh0 + bhl, b = bh >> 4, h = bh & 15;
    yb[((long)b * Tc + t) * 1024 + h * 64 + d] = sum;
}

extern "C" void kernel_launch(void* const* d_in, const int* in_sizes, int n_in,
                              void* d_out, int out_size, void* d_ws, size_t ws_size,
                              hipStream_t stream) {
    const float* x_in = (const float*)d_in[0];
    const float* w_in = (const float*)d_in[1];
    const float* cos_in = (const float*)d_in[2];
    const float* sin_in = (const float*)d_in[3];
    float* out = (float*)d_out;
    float* ws = (float*)d_ws;

    // workspace layout (floats); total ~45.2M floats ~181 MB
    long off = 0;
    float* w_cur = ws + off;  off += (long)WR * Ec;
    float* w_tmp = ws + off;  off += (long)WR * Ec;
    float* xbuf  = ws + off;  off += BT * Ec;
    float* xn    = ws + off;  off += BT * Ec;
    float* qkv   = ws + off;  off += BT * 3L * QKVc;
    float* ybuf  = ws + off;  off += BT * QKVc;
    float* oab   = ws + off;  off += (long)Ec * Ec;
    float* hq    = ws + off;  off += (long)Bc * Hc * Tc * DHc;
    float* hk    = ws + off;  off += (long)Bc * Hc * Tc * DHc;
    float* hv    = ws + off;  off += (long)Bc * Hc * Tc * DHc;
    float* red   = ws + off;  off += 1024;
    float* scales= ws + off;  off += 16;
    float* chw   = ws + off;  off += 2048L * NCH;
    float* chs   = ws + off;  off += 2048L * NCH;
    // aliases (region dead at time of use)
    float* uv     = qkv;                 // swiglu uv (8.39M)
    float* gbuf   = qkv + BT * 2L * Ec;  // u*silu(v) (4.19M)
    float* attnS  = qkv;                 // attention scores, 2 bh (8.39M)
    float* pvpart = w_tmp;               // PV split-K partials (2.10M)
    float* obuf   = xn;                  // rmsnorm(u)

    hipMemcpyAsync(w_cur, w_in, (size_t)WR * Ec * 4, hipMemcpyDeviceToDevice, stream);
    hipMemcpyAsync(xbuf, x_in, (size_t)BT * Ec * 4, hipMemcpyDeviceToDevice, stream);

    const float rs32 = 0.03125f;                 // 1024^-0.5
    const float rsWR = 1.0f / sqrtf(6144.0f);    // (5*QKV+E)^-0.5

    auto stdscale = [&](const float* p, long n, float rs, int slot) {
        k_std_partial<<<256, TPB, 0, stream>>>(p, n, red);
        k_std_final<<<1, TPB, 0, stream>>>(red, (float)n, rs, scales + slot);
    };

    for (int layer = 0; layer < 2; ++layer) {
        stdscale(w_cur,                3072L * 1024, rs32, 0);
        stdscale(w_cur + 3072L * 1024, 2048L * 1024, rs32, 1);
        stdscale(w_cur + 5120L * 1024, 1024L * 1024, rs32, 2);
        // xn = rmsnorm(x)
        k_rms1024<<<BT, TPB, 0, stream>>>(xbuf, xn, 1024, 1024);
        // qkv = xn @ w_qkv^T * s0
        k_gemm<0, 1><<<dim3(3072 / 64, 4096 / 64, 1), TPB, 0, stream>>>(
            4096, 3072, 1024, xn, 1024, 0, w_cur, 1024, 0, qkv, 3072, 0, 0, 1,
            scales + 0, 1.0f, nullptr, 0);
        // rmsnorm q,k in place
        k_rms1024<<<BT, TPB, 0, stream>>>(qkv, qkv, 3072, 3072);
        k_rms1024<<<BT, TPB, 0, stream>>>(qkv + 1024, qkv + 1024, 3072, 3072);
        // aft gated cumsum -> y
        k_aft_p1<<<(2048 * NCH) / TPB, TPB, 0, stream>>>(qkv, chw, chs);
        k_aft_p2<<<2048 / TPB, TPB, 0, stream>>>(chw, chs);
        k_aft_p3<<<(2048 * NCH) / TPB, TPB, 0, stream>>>(qkv, chw, chs, ybuf);
        // uv = y @ w_sw^T * s1
        k_gemm<0, 1><<<dim3(2048 / 64, 4096 / 64, 1), TPB, 0, stream>>>(
            4096, 2048, 1024, ybuf, 1024, 0, w_cur + 3072L * 1024, 1024, 0, uv, 2048, 0, 0, 1,
            scales + 1, 1.0f, nullptr, 0);
        k_silu_gate<<<(int)((BT * 1024 / 4) / TPB), TPB, 0, stream>>>(uv, gbuf, BT * 1024 / 4);
        // o = rmsnorm(u)
        k_rms1024<<<BT, TPB, 0, stream>>>(uv, obuf, 2048, 1024);
        // oa_pre = o^T @ v * E^-0.5
        k_gemm<1, 0><<<dim3(1024 / 64, 1024 / 64, 1), TPB, 0, stream>>>(
            1024, 1024, 4096, obuf, 1024, 0, uv + 1024, 2048, 0, oab, 1024, 0, 0, 1,
            nullptr, 0.03125f, nullptr, 0);
        k_softmax<<<dim3(1024, 1), TPB, 0, stream>>>(oab, 1024, 1024, 0, 0);
        // x = x + g @ w_out^T * s2 (in-place)
        k_gemm<0, 1><<<dim3(1024 / 64, 4096 / 64, 1), TPB, 0, stream>>>(
            4096, 1024, 1024, gbuf, 1024, 0, w_cur + 5120L * 1024, 1024, 0, xbuf, 1024, 0, 0, 1,
            scales + 2, 1.0f, xbuf, 1024);
        // w_tmp = w_cur @ oa
        k_gemm<0, 0><<<dim3(1024 / 64, 6144 / 64, 1), TPB, 0, stream>>>(
            6144, 1024, 1024, w_cur, 1024, 0, oab, 1024, 0, w_tmp, 1024, 0, 0, 1,
            nullptr, 1.0f, nullptr, 0);
        stdscale(w_tmp, (long)WR * 1024, rsWR, 3);
        k_wupdate<<<(int)(((long)WR * 1024 / 4) / TPB), TPB, 0, stream>>>(w_cur, w_tmp, scales + 3, (long)WR * 1024 / 4);
    }

    // -------- final tea (NOTE: no w_norm here, per reference) --------
    k_rms1024<<<BT, TPB, 0, stream>>>(xbuf, xn, 1024, 1024);
    k_gemm<0, 1><<<dim3(3072 / 64, 4096 / 64, 1), TPB, 0, stream>>>(
        4096, 3072, 1024, xn, 1024, 0, w_cur, 1024, 0, qkv, 3072, 0, 0, 1,
        nullptr, 1.0f, nullptr, 0);
    k_rot_split<<<BT, TPB, 0, stream>>>(qkv, cos_in, sin_in, hq, hk, hv);
    for (int gI = 0; gI < 16; ++gI) {
        long hoff = (long)gI * 2 * Tc * DHc;
        // S = q @ k^T * DH^-0.5 (2 heads)
        k_gemm<0, 1><<<dim3(2048 / 64, 2048 / 64, 2), TPB, 0, stream>>>(
            2048, 2048, 64, hq + hoff, 64, (long)Tc * 64, hk + hoff, 64, (long)Tc * 64,
            attnS, 2048, (long)Tc * Tc, 0, 1, nullptr, 0.125f, nullptr, 0);
        k_softmax<<<dim3(2048, 2), TPB, 0, stream>>>(attnS, 2048, 2048, (long)Tc * Tc, 1);
        // Yt = V^T @ P^T, split-K x8
        k_gemm<1, 1><<<dim3(2048 / 64, 1, 16), TPB, 0, stream>>>(
            64, 2048, 256, hv + hoff, 64, (long)Tc * 64, attnS, 2048, (long)Tc * Tc,
            pvpart, 2048, 8L * 64 * 2048, 64L * 2048, 8, nullptr, 1.0f, nullptr, 0);
        k_pv_merge<<<(2 * 64 * 2048) / TPB, TPB, 0, stream>>>(pvpart, ybuf, gI * 2);
    }
    // final swiglu -> d_out
    k_gemm<0, 1><<<dim3(2048 / 64, 4096 / 64, 1), TPB, 0, stream>>>(
        4096, 2048, 1024, ybuf, 1024, 0, w_cur + 3072L * 1024, 1024, 0, uv, 2048, 0, 0, 1,
        nullptr, 1.0f, nullptr, 0);
    k_silu_gate<<<(int)((BT * 1024 / 4) / TPB), TPB, 0, stream>>>(uv, gbuf, BT * 1024 / 4);
    k_gemm<0, 1><<<dim3(1024 / 64, 4096 / 64, 1), TPB, 0, stream>>>(
        4096, 1024, 1024, gbuf, 1024, 0, w_cur + 5120L * 1024, 1024, 0, out, 1024, 0, 0, 1,
        nullptr, 1.0f, xbuf, 1024);
}

// Round 2
// 2313.327 us; speedup vs baseline: 2.0030x; 2.0030x over previous
//
#include <hip/hip_runtime.h>
#include <hip/hip_bf16.h>
#include <math.h>

#define TPB 256

constexpr int Bc = 2, Tc = 2048, Ec = 1024, QKVc = 1024, Hc = 16, DHc = 64;
constexpr long BT = (long)Bc * Tc;     // 4096
constexpr int WR = 5 * QKVc + Ec;      // 6144
constexpr float F32_EPS = 1.1920928955078125e-07f;
constexpr int NCH = 16, CHL = Tc / NCH;

typedef __attribute__((ext_vector_type(8))) short short8;
typedef __attribute__((ext_vector_type(4))) float f32x4;

__device__ __forceinline__ unsigned short f2bu(float f) {
    union { __hip_bfloat16 h; unsigned short u; } c; c.h = __float2bfloat16(f); return c.u;
}
__device__ __forceinline__ float bu2f(unsigned short u) {
    union { __hip_bfloat16 h; unsigned short u; } c; c.u = u; return __bfloat162float(c.h);
}
__device__ __forceinline__ float ldval(const float* p) { return *p; }
__device__ __forceinline__ float ldval(const unsigned short* p) { return bu2f(*p); }

__device__ __forceinline__ void gload_lds16(const void* g, void* l) {
    __builtin_amdgcn_global_load_lds((const __attribute__((address_space(1))) void*)g,
                                     (__attribute__((address_space(3))) void*)l, 16, 0, 0);
}

// ---------------- global std (ddof=1) -> scale = rs/(std+1e-8) ----------------
__global__ void k_std_partial(const float* __restrict__ p, long n, float* __restrict__ out) {
    __shared__ float ls[TPB], lss[TPB];
    float s = 0.f, ss = 0.f;
    for (long i = (long)blockIdx.x * TPB + threadIdx.x; i < n; i += (long)gridDim.x * TPB) {
        float v = p[i]; s += v; ss += v * v;
    }
    ls[threadIdx.x] = s; lss[threadIdx.x] = ss; __syncthreads();
    for (int o = 128; o > 0; o >>= 1) {
        if (threadIdx.x < o) { ls[threadIdx.x] += ls[threadIdx.x + o]; lss[threadIdx.x] += lss[threadIdx.x + o]; }
        __syncthreads();
    }
    if (threadIdx.x == 0) { out[blockIdx.x] = ls[0]; out[gridDim.x + blockIdx.x] = lss[0]; }
}

__global__ void k_std_final(const float* __restrict__ part, float n, float rs, float* __restrict__ scale) {
    __shared__ float ls[TPB], lss[TPB];
    ls[threadIdx.x] = part[threadIdx.x];
    lss[threadIdx.x] = part[TPB + threadIdx.x];
    __syncthreads();
    for (int o = 128; o > 0; o >>= 1) {
        if (threadIdx.x < o) { ls[threadIdx.x] += ls[threadIdx.x + o]; lss[threadIdx.x] += lss[threadIdx.x + o]; }
        __syncthreads();
    }
    if (threadIdx.x == 0) {
        float var = (lss[0] - ls[0] * ls[0] / n) / (n - 1.0f);
        scale[0] = rs / (sqrtf(fmaxf(var, 0.0f)) + 1e-8f);
    }
}

// ---------------- rmsnorm over 1024 cols, fp32 out ----------------
__global__ void k_rms1024(const float* __restrict__ in, float* __restrict__ out, long ldin, long ldout) {
    __shared__ float red[TPB];
    long row = blockIdx.x;
    float4 v = *(const float4*)(in + row * ldin + threadIdx.x * 4);
    float ss = v.x * v.x + v.y * v.y + v.z * v.z + v.w * v.w;
    red[threadIdx.x] = ss; __syncthreads();
    for (int o = 128; o > 0; o >>= 1) {
        if (threadIdx.x < o) red[threadIdx.x] += red[threadIdx.x + o];
        __syncthreads();
    }
    float sc = rsqrtf(red[0] / 1024.0f + F32_EPS);
    float4 o4; o4.x = v.x * sc; o4.y = v.y * sc; o4.z = v.z * sc; o4.w = v.w * sc;
    *(float4*)(out + row * ldout + threadIdx.x * 4) = o4;
}

// ---------------- rmsnorm over 1024 cols, bf16 out ----------------
__global__ void k_rms1024b(const float* __restrict__ in, unsigned short* __restrict__ out, long ldin, long ldout) {
    __shared__ float red[TPB];
    long row = blockIdx.x;
    float4 v = *(const float4*)(in + row * ldin + threadIdx.x * 4);
    float ss = v.x * v.x + v.y * v.y + v.z * v.z + v.w * v.w;
    red[threadIdx.x] = ss; __syncthreads();
    for (int o = 128; o > 0; o >>= 1) {
        if (threadIdx.x < o) red[threadIdx.x] += red[threadIdx.x + o];
        __syncthreads();
    }
    float sc = rsqrtf(red[0] / 1024.0f + F32_EPS);
    ushort4 o4; o4.x = f2bu(v.x * sc); o4.y = f2bu(v.y * sc); o4.z = f2bu(v.z * sc); o4.w = f2bu(v.w * sc);
    *(ushort4*)(out + row * ldout + threadIdx.x * 4) = o4;
}

// ---------------- per-row rms scale (1024 cols) ----------------
__global__ void k_rowrms(const float* __restrict__ in, long ld, float* __restrict__ rs) {
    __shared__ float red[TPB];
    long row = blockIdx.x;
    float4 v = *(const float4*)(in + row * ld + threadIdx.x * 4);
    red[threadIdx.x] = v.x * v.x + v.y * v.y + v.z * v.z + v.w * v.w;
    __syncthreads();
    for (int o = 128; o > 0; o >>= 1) {
        if (threadIdx.x < o) red[threadIdx.x] += red[threadIdx.x + o];
        __syncthreads();
    }
    if (threadIdx.x == 0) rs[row] = rsqrtf(red[0] / 1024.0f + F32_EPS);
}

// ---------------- fp32 -> bf16 cast ----------------
__global__ void k_cast_bf16(const float* __restrict__ in, unsigned short* __restrict__ out, long n4) {
    long i = (long)blockIdx.x * TPB + threadIdx.x;
    if (i >= n4) return;
    float4 v = *(const float4*)(in + i * 4);
    ushort4 o; o.x = f2bu(v.x); o.y = f2bu(v.y); o.z = f2bu(v.z); o.w = f2bu(v.w);
    *(ushort4*)(out + i * 4) = o;
}

// ---------------- transpose-cast: in[R][C] (ld, opt rowscale) -> bf16 out[C][R] ----------------
template<typename TI>
__global__ void k_tcast(const TI* __restrict__ in, long ldi, long sIn,
                        unsigned short* __restrict__ out, long ldo, long sOut,
                        const float* __restrict__ rowscale) {
    __shared__ float tile[64][65];
    const TI* ip = in + (long)blockIdx.z * sIn;
    unsigned short* op = out + (long)blockIdx.z * sOut;
    int r0 = blockIdx.y * 64, c0 = blockIdx.x * 64;
    int tid = threadIdx.x;
    int rr = tid >> 4, cc = (tid & 15) * 4;
    #pragma unroll
    for (int u = 0; u < 4; ++u) {
        int r = rr + u * 16;
        float sc = rowscale ? rowscale[r0 + r] : 1.0f;
        #pragma unroll
        for (int j = 0; j < 4; ++j)
            tile[r][cc + j] = ldval(ip + (long)(r0 + r) * ldi + c0 + cc + j) * sc;
    }
    __syncthreads();
    #pragma unroll
    for (int u = 0; u < 4; ++u) {
        int c = rr + u * 16;
        ushort4 o;
        o.x = f2bu(tile[cc + 0][c]); o.y = f2bu(tile[cc + 1][c]);
        o.z = f2bu(tile[cc + 2][c]); o.w = f2bu(tile[cc + 3][c]);
        *(ushort4*)(op + (long)(c0 + c) * ldo + r0 + cc) = o;
    }
}

// ---------------- bf16 MFMA GEMM, NT: C[M,N] = s * A[M,K] @ B[N,K]^T (+add) ----------------
// 256 thr = 4 waves; wave grid WGM x WGN; tile (WGM*64) x (WGN*64); BK=32.
// LDS layout per operand: row-major [rows][32] bf16, 16B chunks XOR-swizzled:
// chunk holding k-group gu of row r sits at slot gu ^ ((r>>1)&3).
template<int WGM, int WGN, int WRITE_BF16>
__global__ __launch_bounds__(256)
void k_bgemm(int K,
             const unsigned short* __restrict__ A, int lda, long sA,
             const unsigned short* __restrict__ B, int ldb, long sB,
             void* __restrict__ C, int ldc, long sCi,
             const float* __restrict__ scale_ptr, float fscale,
             const float* __restrict__ addp, int ldadd,
             int causal_skip, int kcap) {
    constexpr int TM = WGM * 64, TN = WGN * 64;
    __shared__ unsigned short Asl[TM * 32];
    __shared__ unsigned short Bsl[TN * 32];
    int z = blockIdx.z;
    int m0 = blockIdx.y * TM, n0 = blockIdx.x * TN;
    if (causal_skip && n0 >= m0 + TM) return;
    const unsigned short* Ap = A + (long)z * sA;
    const unsigned short* Bp = B + (long)z * sB;
    int tid = threadIdx.x, lane = tid & 63, wave = tid >> 6;
    int wr = wave / WGN, wc = wave % WGN;
    f32x4 acc[4][4] = {};
    int kend = kcap ? ((m0 + TM < K) ? m0 + TM : K) : K;
    constexpr int CAW = TM / 64;   // global_load_lds calls per wave for A
    constexpr int CBW = TN / 64;
    for (int k0 = 0; k0 < kend; k0 += 32) {
        #pragma unroll
        for (int c = 0; c < CAW; ++c) {
            int bu = (wave * CAW + c) * 64;
            int uidx = bu + lane;
            int r = uidx >> 2, slot = uidx & 3;
            int gu = slot ^ ((r >> 1) & 3);
            gload_lds16(Ap + (long)(m0 + r) * lda + k0 + gu * 8, Asl + bu * 8);
        }
        #pragma unroll
        for (int c = 0; c < CBW; ++c) {
            int bu = (wave * CBW + c) * 64;
            int uidx = bu + lane;
            int r = uidx >> 2, slot = uidx & 3;
            int gu = slot ^ ((r >> 1) & 3);
            gload_lds16(Bp + (long)(n0 + r) * ldb + k0 + gu * 8, Bsl + bu * 8);
        }
        __syncthreads();
        short8 av[4], bv[4];
        #pragma unroll
        for (int m = 0; m < 4; ++m) {
            int r = wr * 64 + m * 16 + (lane & 15);
            int slot = (lane >> 4) ^ ((r >> 1) & 3);
            av[m] = *(const short8*)(Asl + r * 32 + slot * 8);
        }
        #pragma unroll
        for (int n = 0; n < 4; ++n) {
            int r = wc * 64 + n * 16 + (lane & 15);
            int slot = (lane >> 4) ^ ((r >> 1) & 3);
            bv[n] = *(const short8*)(Bsl + r * 32 + slot * 8);
        }
        #pragma unroll
        for (int m = 0; m < 4; ++m)
            #pragma unroll
            for (int n = 0; n < 4; ++n)
                acc[m][n] = __builtin_amdgcn_mfma_f32_16x16x32_bf16(av[m], bv[n], acc[m][n], 0, 0, 0);
        __syncthreads();
    }
    float s = fscale * (scale_ptr ? scale_ptr[0] : 1.0f);
    long cbase = (long)z * sCi;
    int row0 = m0 + wr * 64, col0 = n0 + wc * 64 + (lane & 15);
    int rbase = (lane >> 4) * 4;
    #pragma unroll
    for (int m = 0; m < 4; ++m)
        #pragma unroll
        for (int i = 0; i < 4; ++i) {
            long row = row0 + m * 16 + rbase + i;
            #pragma unroll
            for (int n = 0; n < 4; ++n) {
                long col = col0 + n * 16;
                float v = acc[m][n][i] * s;
                if (addp) v += addp[row * (long)ldadd + col];
                long idx = cbase + row * ldc + col;
                if (WRITE_BF16) ((unsigned short*)C)[idx] = f2bu(v);
                else ((float*)C)[idx] = v;
            }
        }
}

// ---------------- AFT gated cumsum, 3-pass chunked ----------------
__global__ void k_aft_p1(const float* __restrict__ qkv, float* __restrict__ cw, float* __restrict__ cs) {
    int id = blockIdx.x * TPB + threadIdx.x;
    int bc = id & 2047, ch = id >> 11;
    int b = bc >> 10, c = bc & 1023;
    const float* base = qkv + ((long)(b * Tc + ch * CHL)) * 3072 + c;
    float sw = 0.f, sv = 0.f;
    for (int i = 0; i < CHL; ++i) {
        float k = base[1024], v = base[2048];
        float e = expf(k);
        sw += e; sv += e * v;
        base += 3072;
    }
    cw[ch * 2048 + bc] = sw; cs[ch * 2048 + bc] = sv;
}

__global__ void k_aft_p2(float* __restrict__ cw, float* __restrict__ cs) {
    int bc = blockIdx.x * TPB + threadIdx.x;
    float rw = 0.f, rv = 0.f;
    for (int ch = 0; ch < NCH; ++ch) {
        long idx = (long)ch * 2048 + bc;
        float tw = cw[idx], tv = cs[idx];
        cw[idx] = rw; cs[idx] = rv; rw += tw; rv += tv;
    }
}

__global__ void k_aft_p3(const float* __restrict__ qkv, const float* __restrict__ cw,
                         const float* __restrict__ cs, unsigned short* __restrict__ y) {
    int id = blockIdx.x * TPB + threadIdx.x;
    int bc = id & 2047, ch = id >> 11;
    int b = bc >> 10, c = bc & 1023;
    long t0 = (long)b * Tc + ch * CHL;
    const float* base = qkv + t0 * 3072 + c;
    unsigned short* yp = y + t0 * 1024 + c;
    float aw = cw[ch * 2048 + bc], av = cs[ch * 2048 + bc];
    for (int i = 0; i < CHL; ++i) {
        float q = base[0], k = base[1024], v = base[2048];
        float e = expf(k);
        av += e * v; aw += e;
        float sig = 1.0f / (1.0f + expf(-q));
        yp[0] = f2bu(sig * av / (aw + 1e-6f));
        base += 3072; yp += 1024;
    }
}

// ---------------- u * silu(v) -> bf16 ----------------
__global__ void k_silu_gate(const float* __restrict__ uv, unsigned short* __restrict__ g, long n4) {
    long i = (long)blockIdx.x * TPB + threadIdx.x;
    if (i >= n4) return;
    long r = i >> 8, c4 = i & 255;
    float4 u = *(const float4*)(uv + r * 2048 + c4 * 4);
    float4 v = *(const float4*)(uv + r * 2048 + 1024 + c4 * 4);
    ushort4 o;
    o.x = f2bu(u.x * v.x / (1.f + expf(-v.x)));
    o.y = f2bu(u.y * v.y / (1.f + expf(-v.y)));
    o.z = f2bu(u.z * v.z / (1.f + expf(-v.z)));
    o.w = f2bu(u.w * v.w / (1.f + expf(-v.w)));
    *(ushort4*)(g + r * 1024 + c4 * 4) = o;
}

// ---------------- w = wT*s*silu(w) + w ----------------
__global__ void k_wupdate(float* __restrict__ w, const float* __restrict__ p,
                          const float* __restrict__ scale, long n4) {
    long i = (long)blockIdx.x * TPB + threadIdx.x;
    if (i >= n4) return;
    float s = scale[0];
    float4 wv = *(const float4*)(w + i * 4);
    float4 pv = *(const float4*)(p + i * 4);
    float4 o;
    o.x = pv.x * s * (wv.x / (1.f + expf(-wv.x))) + wv.x;
    o.y = pv.y * s * (wv.y / (1.f + expf(-wv.y))) + wv.y;
    o.z = pv.z * s * (wv.z / (1.f + expf(-wv.z))) + wv.z;
    o.w = pv.w * s * (wv.w / (1.f + expf(-wv.w))) + wv.w;
    *(float4*)(w + i * 4) = o;
}

// ---------------- row softmax fp32 in place (oa) ----------------
__global__ void k_softmax(float* __restrict__ buf, int cols) {
    __shared__ float red[TPB];
    long row = blockIdx.x;
    float* p = buf + row * cols;
    float m = -3.0e38f;
    for (int c = threadIdx.x; c < cols; c += TPB) m = fmaxf(m, p[c]);
    red[threadIdx.x] = m; __syncthreads();
    for (int o = 128; o > 0; o >>= 1) {
        if (threadIdx.x < o) red[threadIdx.x] = fmaxf(red[threadIdx.x], red[threadIdx.x + o]);
        __syncthreads();
    }
    m = red[0]; __syncthreads();
    float sum = 0.f;
    for (int c = threadIdx.x; c < cols; c += TPB) sum += expf(p[c] - m);
    red[threadIdx.x] = sum; __syncthreads();
    for (int o = 128; o > 0; o >>= 1) {
        if (threadIdx.x < o) red[threadIdx.x] += red[threadIdx.x + o];
        __syncthreads();
    }
    float inv = 1.0f / red[0];
    for (int c = threadIdx.x; c < cols; c += TPB) p[c] = expf(p[c] - m) * inv;
}

// ---------------- causal softmax fp32 S -> bf16 P (2048 cols) ----------------
__global__ void k_softmax_b16(const float* __restrict__ S, unsigned short* __restrict__ P) {
    __shared__ float red[TPB];
    int row = blockIdx.x;
    long base = (long)blockIdx.y * (2048L * 2048) + (long)row * 2048;
    const float* p = S + base;
    unsigned short* po = P + base;
    int limit = row + 1;
    float m = -3.0e38f;
    for (int c = threadIdx.x; c < limit; c += TPB) m = fmaxf(m, p[c]);
    red[threadIdx.x] = m; __syncthreads();
    for (int o = 128; o > 0; o >>= 1) {
        if (threadIdx.x < o) red[threadIdx.x] = fmaxf(red[threadIdx.x], red[threadIdx.x + o]);
        __syncthreads();
    }
    m = red[0]; __syncthreads();
    float sum = 0.f;
    for (int c = threadIdx.x; c < limit; c += TPB) sum += expf(p[c] - m);
    red[threadIdx.x] = sum; __syncthreads();
    for (int o = 128; o > 0; o >>= 1) {
        if (threadIdx.x < o) red[threadIdx.x] += red[threadIdx.x + o];
        __syncthreads();
    }
    float inv = 1.0f / red[0];
    for (int c = threadIdx.x; c < 2048; c += TPB)
        po[c] = f2bu(c < limit ? expf(p[c] - m) * inv : 0.0f);
}

// ---------------- tea: rotary + per-head rmsnorm + split, bf16 out ----------------
__global__ void k_rot_split(const float* __restrict__ qkvp, const float* __restrict__ cosp,
                            const float* __restrict__ sinp, unsigned short* __restrict__ hq,
                            unsigned short* __restrict__ hk, unsigned short* __restrict__ hv) {
    __shared__ float row[3072];
    __shared__ float cs[32], sn[32];
    int bt = blockIdx.x;
    int b = bt >> 11, t = bt & 2047;
    const float* src = qkvp + (long)bt * 3072;
    #pragma unroll
    for (int u = 0; u < 3; ++u) {
        int idx = threadIdx.x + u * 256;
        *(float4*)&row[idx * 4] = *(const float4*)(src + idx * 4);
    }
    if (threadIdx.x < 32) { cs[threadIdx.x] = cosp[t * 32 + threadIdx.x]; sn[threadIdx.x] = sinp[t * 32 + threadIdx.x]; }
    __syncthreads();
    int h = threadIdx.x >> 4, li = threadIdx.x & 15;
    int base = h * 192;
    long obase = ((long)(b * Hc + h) * Tc + t) * 64 + li * 4;
    {
        float r[4]; float ss = 0.f;
        #pragma unroll
        for (int j = 0; j < 4; ++j) {
            int d = li * 4 + j;
            float val = (d < 32) ? (row[base + d] * cs[d] + row[base + d + 32] * sn[d])
                                 : (-row[base + d - 32] * sn[d - 32] + row[base + d] * cs[d - 32]);
            r[j] = val; ss += val * val;
        }
        ss += __shfl_xor(ss, 1); ss += __shfl_xor(ss, 2); ss += __shfl_xor(ss, 4); ss += __shfl_xor(ss, 8);
        float sc = rsqrtf(ss / 64.0f + F32_EPS);
        ushort4 o; o.x = f2bu(r[0] * sc); o.y = f2bu(r[1] * sc); o.z = f2bu(r[2] * sc); o.w = f2bu(r[3] * sc);
        *(ushort4*)(hq + obase) = o;
    }
    {
        int kb = base + 64;
        float r[4]; float ss = 0.f;
        #pragma unroll
        for (int j = 0; j < 4; ++j) {
            int d = li * 4 + j;
            float val = (d < 32) ? (row[kb + d] * cs[d] + row[kb + d + 32] * sn[d])
                                 : (-row[kb + d - 32] * sn[d - 32] + row[kb + d] * cs[d - 32]);
            r[j] = val; ss += val * val;
        }
        ss += __shfl_xor(ss, 1); ss += __shfl_xor(ss, 2); ss += __shfl_xor(ss, 4); ss += __shfl_xor(ss, 8);
        float sc = rsqrtf(ss / 64.0f + F32_EPS);
        ushort4 o; o.x = f2bu(r[0] * sc); o.y = f2bu(r[1] * sc); o.z = f2bu(r[2] * sc); o.w = f2bu(r[3] * sc);
        *(ushort4*)(hk + obase) = o;
    }
    {
        ushort4 o;
        o.x = f2bu(row[base + 128 + li * 4 + 0]); o.y = f2bu(row[base + 128 + li * 4 + 1]);
        o.z = f2bu(row[base + 128 + li * 4 + 2]); o.w = f2bu(row[base + 128 + li * 4 + 3]);
        *(ushort4*)(hv + obase) = o;
    }
}

extern "C" void kernel_launch(void* const* d_in, const int* in_sizes, int n_in,
                              void* d_out, int out_size, void* d_ws, size_t ws_size,
                              hipStream_t stream) {
    const float* x_in = (const float*)d_in[0];
    const float* w_in = (const float*)d_in[1];
    const float* cos_in = (const float*)d_in[2];
    const float* sin_in = (const float*)d_in[3];
    float* out = (float*)d_out;
    float* ws = (float*)d_ws;

    // fp32 region (~122 MB)
    long off = 0;
    float* w_cur = ws + off;  off += (long)WR * Ec;          // 6.29M
    float* w_tmp = ws + off;  off += (long)WR * Ec;          // 6.29M
    float* xbuf  = ws + off;  off += BT * Ec;                // 4.19M
    float* qkv   = ws + off;  off += BT * 3L * QKVc;         // 12.58M (alias: uv, attnS)
    float* oab   = ws + off;  off += (long)Ec * Ec;          // 1.05M
    float* red   = ws + off;  off += 1024;
    float* scales= ws + off;  off += 16;
    float* uscale= ws + off;  off += 4096;
    float* chw   = ws + off;  off += 2048L * NCH;
    float* chs   = ws + off;  off += 2048L * NCH;
    float* uv    = qkv;                  // fp32 alias
    float* attnS = qkv;                  // fp32 alias

    // bf16 region (~80 MB)
    unsigned short* bp = (unsigned short*)(ws + off);
    long bo = 0;
    unsigned short* wb  = bp + bo; bo += (long)WR * Ec;      // 6.29M
    unsigned short* xbn = bp + bo; bo += BT * Ec;            // 4.19M
    unsigned short* ybn = bp + bo; bo += BT * Ec;
    unsigned short* gbn = bp + bo; bo += BT * Ec;
    unsigned short* t1  = bp + bo; bo += BT * Ec;            // o^T | hq
    unsigned short* t2  = bp + bo; bo += BT * Ec;            // v^T | hk
    unsigned short* t3  = bp + bo; bo += BT * Ec;            // oa^T | hvS
    unsigned short* t4  = bp + bo; bo += BT * Ec;            // hvT
    unsigned short* Pb  = bp + bo; bo += 2L * Tc * Tc;       // 8.39M

    hipMemcpyAsync(w_cur, w_in, (size_t)WR * Ec * 4, hipMemcpyDeviceToDevice, stream);
    hipMemcpyAsync(xbuf, x_in, (size_t)BT * Ec * 4, hipMemcpyDeviceToDevice, stream);

    const float rs32 = 0.03125f;
    const float rsWR = 1.0f / sqrtf(6144.0f);
    const long wsw = 3072L * 1024, wout = 5120L * 1024;

    auto stdscale = [&](const float* p, long n, float rs, int slot) {
        k_std_partial<<<256, TPB, 0, stream>>>(p, n, red);
        k_std_final<<<1, TPB, 0, stream>>>(red, (float)n, rs, scales + slot);
    };

    for (int layer = 0; layer < 2; ++layer) {
        stdscale(w_cur,        3072L * 1024, rs32, 0);
        stdscale(w_cur + wsw,  2048L * 1024, rs32, 1);
        stdscale(w_cur + wout, 1024L * 1024, rs32, 2);
        k_cast_bf16<<<(int)(((long)WR * Ec / 4) / TPB), TPB, 0, stream>>>(w_cur, wb, (long)WR * Ec / 4);
        k_rms1024b<<<BT, TPB, 0, stream>>>(xbuf, xbn, 1024, 1024);
        // qkv = rmsnorm(x) @ w_qkv^T * s0
        k_bgemm<2, 2, 0><<<dim3(24, 32, 1), TPB, 0, stream>>>(
            1024, xbn, 1024, 0, wb, 1024, 0, qkv, 3072, 0, scales + 0, 1.0f, nullptr, 0, 0, 0);
        k_rms1024<<<BT, TPB, 0, stream>>>(qkv, qkv, 3072, 3072);
        k_rms1024<<<BT, TPB, 0, stream>>>(qkv + 1024, qkv + 1024, 3072, 3072);
        k_aft_p1<<<(2048 * NCH) / TPB, TPB, 0, stream>>>(qkv, chw, chs);
        k_aft_p2<<<2048 / TPB, TPB, 0, stream>>>(chw, chs);
        k_aft_p3<<<(2048 * NCH) / TPB, TPB, 0, stream>>>(qkv, chw, chs, ybn);
        // uv = y @ w_sw^T * s1   (overwrites qkv region)
        k_bgemm<2, 2, 0><<<dim3(16, 32, 1), TPB, 0, stream>>>(
            1024, ybn, 1024, 0, wb + wsw, 1024, 0, uv, 2048, 0, scales + 1, 1.0f, nullptr, 0, 0, 0);
        k_silu_gate<<<(int)((BT * 1024 / 4) / TPB), TPB, 0, stream>>>(uv, gbn, BT * 1024 / 4);
        // o = rmsnorm(u): row scales, then transposed casts of o and v
        k_rowrms<<<BT, TPB, 0, stream>>>(uv, 2048, uscale);
        k_tcast<float><<<dim3(16, 64, 1), TPB, 0, stream>>>(uv, 2048, 0, t1, 4096, 0, uscale);
        k_tcast<float><<<dim3(16, 64, 1), TPB, 0, stream>>>(uv + 1024, 2048, 0, t2, 4096, 0, nullptr);
        // oa = softmax(o^T @ a * E^-0.5)
        k_bgemm<2, 2, 0><<<dim3(8, 8, 1), TPB, 0, stream>>>(
            4096, t1, 4096, 0, t2, 4096, 0, oab, 1024, 0, nullptr, 0.03125f, nullptr, 0, 0, 0);
        k_softmax<<<1024, TPB, 0, stream>>>(oab, 1024);
        k_tcast<float><<<dim3(16, 16, 1), TPB, 0, stream>>>(oab, 1024, 0, t3, 1024, 0, nullptr);
        // x += g @ w_out^T * s2
        k_bgemm<2, 2, 0><<<dim3(8, 32, 1), TPB, 0, stream>>>(
            1024, gbn, 1024, 0, wb + wout, 1024, 0, xbuf, 1024, 0, scales + 2, 1.0f, xbuf, 1024, 0, 0);
        // w_tmp = w @ oa
        k_bgemm<2, 2, 0><<<dim3(8, 48, 1), TPB, 0, stream>>>(
            1024, wb, 1024, 0, t3, 1024, 0, w_tmp, 1024, 0, nullptr, 1.0f, nullptr, 0, 0, 0);
        stdscale(w_tmp, (long)WR * 1024, rsWR, 3);
        k_wupdate<<<(int)(((long)WR * 1024 / 4) / TPB), TPB, 0, stream>>>(w_cur, w_tmp, scales + 3, (long)WR * 1024 / 4);
    }

    // -------- final tea (no w_norm) --------
    k_cast_bf16<<<(int)(((long)WR * Ec / 4) / TPB), TPB, 0, stream>>>(w_cur, wb, (long)WR * Ec / 4);
    k_rms1024b<<<BT, TPB, 0, stream>>>(xbuf, xbn, 1024, 1024);
    k_bgemm<2, 2, 0><<<dim3(24, 32, 1), TPB, 0, stream>>>(
        1024, xbn, 1024, 0, wb, 1024, 0, qkv, 3072, 0, nullptr, 1.0f, nullptr, 0, 0, 0);
    k_rot_split<<<BT, TPB, 0, stream>>>(qkv, cos_in, sin_in, t1, t2, t3);
    // hvT[bh][64][2048] from hvS[bh][2048][64]
    k_tcast<unsigned short><<<dim3(1, 32, 32), TPB, 0, stream>>>(
        t3, 64, (long)Tc * 64, t4, 2048, (long)Tc * 64, nullptr);
    for (int gI = 0; gI < 16; ++gI) {
        long hoff = (long)gI * 2 * Tc * 64;
        int bh0 = gI * 2, b = bh0 >> 4, h0 = bh0 & 15;
        // S = q @ k^T * DH^-0.5 (2 heads), causal block skip
        k_bgemm<2, 2, 0><<<dim3(16, 16, 2), TPB, 0, stream>>>(
            64, t1 + hoff, 64, (long)Tc * 64, t2 + hoff, 64, (long)Tc * 64,
            attnS, 2048, (long)Tc * Tc, nullptr, 0.125f, nullptr, 0, 1, 0);
        k_softmax_b16<<<dim3(2048, 2), TPB, 0, stream>>>(attnS, Pb);
        // Y = P @ V   (P bf16, V^T bf16), causal K-cap, bf16 out into ybn head-interleaved
        k_bgemm<4, 1, 1><<<dim3(1, 8, 2), TPB, 0, stream>>>(
            2048, Pb, 2048, (long)Tc * Tc, t4 + (long)bh0 * 64 * Tc, 2048, 64L * Tc,
            ybn + (long)b * Tc * 1024 + h0 * 64, 1024, 64, nullptr, 1.0f, nullptr, 0, 0, 1);
    }
    // final swiglu -> d_out
    k_bgemm<2, 2, 0><<<dim3(16, 32, 1), TPB, 0, stream>>>(
        1024, ybn, 1024, 0, wb + wsw, 1024, 0, uv, 2048, 0, nullptr, 1.0f, nullptr, 0, 0, 0);
    k_silu_gate<<<(int)((BT * 1024 / 4) / TPB), TPB, 0, stream>>>(uv, gbn, BT * 1024 / 4);
    k_bgemm<2, 2, 0><<<dim3(8, 32, 1), TPB, 0, stream>>>(
        1024, gbn, 1024, 0, wb + wout, 1024, 0, out, 1024, 0, nullptr, 1.0f, xbuf, 1024, 0, 0);
}

// Round 3
// 1118.381 us; speedup vs baseline: 4.1431x; 2.0685x over previous
//
#include <hip/hip_runtime.h>
#include <hip/hip_bf16.h>
#include <math.h>

#define TPB 256

constexpr int Bc = 2, Tc = 2048, Ec = 1024, QKVc = 1024, Hc = 16, DHc = 64;
constexpr long BT = (long)Bc * Tc;     // 4096
constexpr int WR = 5 * QKVc + Ec;      // 6144
constexpr float F32_EPS = 1.1920928955078125e-07f;
constexpr int NCH = 16, CHL = Tc / NCH;

typedef __attribute__((ext_vector_type(8))) short short8;
typedef __attribute__((ext_vector_type(4))) float f32x4;

__device__ __forceinline__ unsigned short f2bu(float f) {
    union { __hip_bfloat16 h; unsigned short u; } c; c.h = __float2bfloat16(f); return c.u;
}
__device__ __forceinline__ float bu2f(unsigned short u) {
    union { __hip_bfloat16 h; unsigned short u; } c; c.u = u; return __bfloat162float(c.h);
}
__device__ __forceinline__ float ldval(const float* p) { return *p; }
__device__ __forceinline__ float ldval(const unsigned short* p) { return bu2f(*p); }

__device__ __forceinline__ void gload_lds16(const void* g, void* l) {
    __builtin_amdgcn_global_load_lds((const __attribute__((address_space(1))) void*)g,
                                     (__attribute__((address_space(3))) void*)l, 16, 0, 0);
}

// ---------------- global std (ddof=1) -> scale = rs/(std+1e-8) ----------------
__global__ void k_std_partial(const float* __restrict__ p, long n, float* __restrict__ out) {
    __shared__ float ls[TPB], lss[TPB];
    float s = 0.f, ss = 0.f;
    for (long i = (long)blockIdx.x * TPB + threadIdx.x; i < n; i += (long)gridDim.x * TPB) {
        float v = p[i]; s += v; ss += v * v;
    }
    ls[threadIdx.x] = s; lss[threadIdx.x] = ss; __syncthreads();
    for (int o = 128; o > 0; o >>= 1) {
        if (threadIdx.x < o) { ls[threadIdx.x] += ls[threadIdx.x + o]; lss[threadIdx.x] += lss[threadIdx.x + o]; }
        __syncthreads();
    }
    if (threadIdx.x == 0) { out[blockIdx.x] = ls[0]; out[gridDim.x + blockIdx.x] = lss[0]; }
}

__global__ void k_std_final(const float* __restrict__ part, float n, float rs, float* __restrict__ scale) {
    __shared__ float ls[TPB], lss[TPB];
    ls[threadIdx.x] = part[threadIdx.x];
    lss[threadIdx.x] = part[TPB + threadIdx.x];
    __syncthreads();
    for (int o = 128; o > 0; o >>= 1) {
        if (threadIdx.x < o) { ls[threadIdx.x] += ls[threadIdx.x + o]; lss[threadIdx.x] += lss[threadIdx.x + o]; }
        __syncthreads();
    }
    if (threadIdx.x == 0) {
        float var = (lss[0] - ls[0] * ls[0] / n) / (n - 1.0f);
        scale[0] = rs / (sqrtf(fmaxf(var, 0.0f)) + 1e-8f);
    }
}

// ---------------- rmsnorm over 1024 cols, fp32 out ----------------
__global__ void k_rms1024(const float* __restrict__ in, float* __restrict__ out, long ldin, long ldout) {
    __shared__ float red[TPB];
    long row = blockIdx.x;
    float4 v = *(const float4*)(in + row * ldin + threadIdx.x * 4);
    float ss = v.x * v.x + v.y * v.y + v.z * v.z + v.w * v.w;
    red[threadIdx.x] = ss; __syncthreads();
    for (int o = 128; o > 0; o >>= 1) {
        if (threadIdx.x < o) red[threadIdx.x] += red[threadIdx.x + o];
        __syncthreads();
    }
    float sc = rsqrtf(red[0] / 1024.0f + F32_EPS);
    float4 o4; o4.x = v.x * sc; o4.y = v.y * sc; o4.z = v.z * sc; o4.w = v.w * sc;
    *(float4*)(out + row * ldout + threadIdx.x * 4) = o4;
}

// ---------------- rmsnorm over 1024 cols, bf16 out ----------------
__global__ void k_rms1024b(const float* __restrict__ in, unsigned short* __restrict__ out, long ldin, long ldout) {
    __shared__ float red[TPB];
    long row = blockIdx.x;
    float4 v = *(const float4*)(in + row * ldin + threadIdx.x * 4);
    float ss = v.x * v.x + v.y * v.y + v.z * v.z + v.w * v.w;
    red[threadIdx.x] = ss; __syncthreads();
    for (int o = 128; o > 0; o >>= 1) {
        if (threadIdx.x < o) red[threadIdx.x] += red[threadIdx.x + o];
        __syncthreads();
    }
    float sc = rsqrtf(red[0] / 1024.0f + F32_EPS);
    ushort4 o4; o4.x = f2bu(v.x * sc); o4.y = f2bu(v.y * sc); o4.z = f2bu(v.z * sc); o4.w = f2bu(v.w * sc);
    *(ushort4*)(out + row * ldout + threadIdx.x * 4) = o4;
}

// ---------------- per-row rms scale (1024 cols) ----------------
__global__ void k_rowrms(const float* __restrict__ in, long ld, float* __restrict__ rs) {
    __shared__ float red[TPB];
    long row = blockIdx.x;
    float4 v = *(const float4*)(in + row * ld + threadIdx.x * 4);
    red[threadIdx.x] = v.x * v.x + v.y * v.y + v.z * v.z + v.w * v.w;
    __syncthreads();
    for (int o = 128; o > 0; o >>= 1) {
        if (threadIdx.x < o) red[threadIdx.x] += red[threadIdx.x + o];
        __syncthreads();
    }
    if (threadIdx.x == 0) rs[row] = rsqrtf(red[0] / 1024.0f + F32_EPS);
}

// ---------------- fp32 -> bf16 cast ----------------
__global__ void k_cast_bf16(const float* __restrict__ in, unsigned short* __restrict__ out, long n4) {
    long i = (long)blockIdx.x * TPB + threadIdx.x;
    if (i >= n4) return;
    float4 v = *(const float4*)(in + i * 4);
    ushort4 o; o.x = f2bu(v.x); o.y = f2bu(v.y); o.z = f2bu(v.z); o.w = f2bu(v.w);
    *(ushort4*)(out + i * 4) = o;
}

// ---------------- transpose-cast: in[R][C] (ld, opt rowscale) -> bf16 out[C][R] ----------------
template<typename TI>
__global__ void k_tcast(const TI* __restrict__ in, long ldi, long sIn,
                        unsigned short* __restrict__ out, long ldo, long sOut,
                        const float* __restrict__ rowscale) {
    __shared__ float tile[64][65];
    const TI* ip = in + (long)blockIdx.z * sIn;
    unsigned short* op = out + (long)blockIdx.z * sOut;
    int r0 = blockIdx.y * 64, c0 = blockIdx.x * 64;
    int tid = threadIdx.x;
    int rr = tid >> 4, cc = (tid & 15) * 4;
    #pragma unroll
    for (int u = 0; u < 4; ++u) {
        int r = rr + u * 16;
        float sc = rowscale ? rowscale[r0 + r] : 1.0f;
        #pragma unroll
        for (int j = 0; j < 4; ++j)
            tile[r][cc + j] = ldval(ip + (long)(r0 + r) * ldi + c0 + cc + j) * sc;
    }
    __syncthreads();
    #pragma unroll
    for (int u = 0; u < 4; ++u) {
        int c = rr + u * 16;
        ushort4 o;
        o.x = f2bu(tile[cc + 0][c]); o.y = f2bu(tile[cc + 1][c]);
        o.z = f2bu(tile[cc + 2][c]); o.w = f2bu(tile[cc + 3][c]);
        *(ushort4*)(op + (long)(c0 + c) * ldo + r0 + cc) = o;
    }
}

// ---------------- bf16 MFMA GEMM, NT: C[M,N] = s * A[M,K] @ B[N,K]^T (+add) ----------------
template<int WGM, int WGN, int WRITE_BF16>
__global__ __launch_bounds__(256)
void k_bgemm(int K,
             const unsigned short* __restrict__ A, int lda, long sA,
             const unsigned short* __restrict__ B, int ldb, long sB,
             void* __restrict__ C, int ldc, long sCi,
             const float* __restrict__ scale_ptr, float fscale,
             const float* __restrict__ addp, int ldadd) {
    constexpr int TM = WGM * 64, TN = WGN * 64;
    __shared__ unsigned short Asl[TM * 32];
    __shared__ unsigned short Bsl[TN * 32];
    int z = blockIdx.z;
    int m0 = blockIdx.y * TM, n0 = blockIdx.x * TN;
    const unsigned short* Ap = A + (long)z * sA;
    const unsigned short* Bp = B + (long)z * sB;
    int tid = threadIdx.x, lane = tid & 63, wave = tid >> 6;
    int wr = wave / WGN, wc = wave % WGN;
    f32x4 acc[4][4] = {};
    constexpr int CAW = TM / 64;
    constexpr int CBW = TN / 64;
    for (int k0 = 0; k0 < K; k0 += 32) {
        #pragma unroll
        for (int c = 0; c < CAW; ++c) {
            int bu = (wave * CAW + c) * 64;
            int uidx = bu + lane;
            int r = uidx >> 2, slot = uidx & 3;
            int gu = slot ^ ((r >> 1) & 3);
            gload_lds16(Ap + (long)(m0 + r) * lda + k0 + gu * 8, Asl + bu * 8);
        }
        #pragma unroll
        for (int c = 0; c < CBW; ++c) {
            int bu = (wave * CBW + c) * 64;
            int uidx = bu + lane;
            int r = uidx >> 2, slot = uidx & 3;
            int gu = slot ^ ((r >> 1) & 3);
            gload_lds16(Bp + (long)(n0 + r) * ldb + k0 + gu * 8, Bsl + bu * 8);
        }
        __syncthreads();
        short8 av[4], bv[4];
        #pragma unroll
        for (int m = 0; m < 4; ++m) {
            int r = wr * 64 + m * 16 + (lane & 15);
            int slot = (lane >> 4) ^ ((r >> 1) & 3);
            av[m] = *(const short8*)(Asl + r * 32 + slot * 8);
        }
        #pragma unroll
        for (int n = 0; n < 4; ++n) {
            int r = wc * 64 + n * 16 + (lane & 15);
            int slot = (lane >> 4) ^ ((r >> 1) & 3);
            bv[n] = *(const short8*)(Bsl + r * 32 + slot * 8);
        }
        #pragma unroll
        for (int m = 0; m < 4; ++m)
            #pragma unroll
            for (int n = 0; n < 4; ++n)
                acc[m][n] = __builtin_amdgcn_mfma_f32_16x16x32_bf16(av[m], bv[n], acc[m][n], 0, 0, 0);
        __syncthreads();
    }
    float s = fscale * (scale_ptr ? scale_ptr[0] : 1.0f);
    long cbase = (long)z * sCi;
    int row0 = m0 + wr * 64, col0 = n0 + wc * 64 + (lane & 15);
    int rbase = (lane >> 4) * 4;
    #pragma unroll
    for (int m = 0; m < 4; ++m)
        #pragma unroll
        for (int i = 0; i < 4; ++i) {
            long row = row0 + m * 16 + rbase + i;
            #pragma unroll
            for (int n = 0; n < 4; ++n) {
                long col = col0 + n * 16;
                float v = acc[m][n][i] * s;
                if (addp) v += addp[row * (long)ldadd + col];
                long idx = cbase + row * ldc + col;
                if (WRITE_BF16) ((unsigned short*)C)[idx] = f2bu(v);
                else ((float*)C)[idx] = v;
            }
        }
}

// ---------------- fused causal flash attention ----------------
// Q,K: [bh][T][64] bf16; V^T: [bh][64][T] bf16; out: ybn [b][T][1024] head-interleaved.
// 4 independent waves/block, wave owns 32 q-rows (strip s = wave*16 + blockIdx.x).
__global__ __launch_bounds__(256)
void k_flash(const unsigned short* __restrict__ hq, const unsigned short* __restrict__ hk,
             const unsigned short* __restrict__ hvT, unsigned short* __restrict__ yout) {
    __shared__ unsigned short P_lds[4][32 * 72];
    int lane = threadIdx.x & 63, wave = threadIdx.x >> 6;
    int g = lane >> 4, c = lane & 15;
    int bh = blockIdx.y, b = bh >> 4, h = bh & 15;
    int s = wave * 16 + blockIdx.x;
    int q0 = s * 32;
    const unsigned short* qb = hq + (long)bh * Tc * 64;
    const unsigned short* kb = hk + (long)bh * Tc * 64;
    const unsigned short* vtb = hvT + (long)bh * 64 * Tc;
    unsigned short* P = P_lds[wave];

    short8 qf[2][2];
    #pragma unroll
    for (int mf = 0; mf < 2; ++mf)
        #pragma unroll
        for (int ks = 0; ks < 2; ++ks)
            qf[mf][ks] = *(const short8*)(qb + (long)(q0 + mf * 16 + c) * 64 + ks * 32 + g * 8);

    f32x4 o_acc[2][4] = {};
    float m_run[2][4], l_run[2][4];
    #pragma unroll
    for (int mf = 0; mf < 2; ++mf)
        #pragma unroll
        for (int i = 0; i < 4; ++i) { m_run[mf][i] = -3.0e38f; l_run[mf][i] = 0.f; }

    int nt = (q0 + 32 + 63) >> 6;
    for (int ti = 0; ti < nt; ++ti) {
        int kt = ti * 64;
        f32x4 s_acc[2][4] = {};
        #pragma unroll
        for (int ks = 0; ks < 2; ++ks) {
            short8 kf[4];
            #pragma unroll
            for (int nf = 0; nf < 4; ++nf)
                kf[nf] = *(const short8*)(kb + (long)(kt + nf * 16 + c) * 64 + ks * 32 + g * 8);
            #pragma unroll
            for (int mf = 0; mf < 2; ++mf)
                #pragma unroll
                for (int nf = 0; nf < 4; ++nf)
                    s_acc[mf][nf] = __builtin_amdgcn_mfma_f32_16x16x32_bf16(qf[mf][ks], kf[nf], s_acc[mf][nf], 0, 0, 0);
        }
        bool diag = (kt + 64 > q0);
        #pragma unroll
        for (int mf = 0; mf < 2; ++mf) {
            float sv[4][4];
            float pm[4] = {-3.0e38f, -3.0e38f, -3.0e38f, -3.0e38f};
            #pragma unroll
            for (int nf = 0; nf < 4; ++nf)
                #pragma unroll
                for (int i = 0; i < 4; ++i) {
                    float v = s_acc[mf][nf][i] * 0.125f;
                    if (diag) {
                        int kg = kt + nf * 16 + c;
                        int qg = q0 + mf * 16 + g * 4 + i;
                        if (kg > qg) v = -3.0e38f;
                    }
                    sv[nf][i] = v;
                    pm[i] = fmaxf(pm[i], v);
                }
            #pragma unroll
            for (int i = 0; i < 4; ++i) {
                float t = pm[i];
                t = fmaxf(t, __shfl_xor(t, 1));
                t = fmaxf(t, __shfl_xor(t, 2));
                t = fmaxf(t, __shfl_xor(t, 4));
                t = fmaxf(t, __shfl_xor(t, 8));
                float mn = fmaxf(m_run[mf][i], t);
                float corr = __expf(m_run[mf][i] - mn);
                m_run[mf][i] = mn;
                float ls = 0.f;
                #pragma unroll
                for (int nf = 0; nf < 4; ++nf) {
                    float p = __expf(sv[nf][i] - mn);
                    unsigned short pb = f2bu(p);
                    P[(mf * 16 + g * 4 + i) * 72 + nf * 16 + c] = pb;
                    ls += bu2f(pb);
                }
                ls += __shfl_xor(ls, 1); ls += __shfl_xor(ls, 2);
                ls += __shfl_xor(ls, 4); ls += __shfl_xor(ls, 8);
                l_run[mf][i] = l_run[mf][i] * corr + ls;
                #pragma unroll
                for (int df = 0; df < 4; ++df) o_acc[mf][df][i] *= corr;
            }
        }
        #pragma unroll
        for (int ks = 0; ks < 2; ++ks) {
            short8 pa[2], vf[4];
            #pragma unroll
            for (int mf = 0; mf < 2; ++mf)
                pa[mf] = *(const short8*)(P + (mf * 16 + c) * 72 + ks * 32 + g * 8);
            #pragma unroll
            for (int df = 0; df < 4; ++df)
                vf[df] = *(const short8*)(vtb + (long)(df * 16 + c) * Tc + kt + ks * 32 + g * 8);
            #pragma unroll
            for (int mf = 0; mf < 2; ++mf)
                #pragma unroll
                for (int df = 0; df < 4; ++df)
                    o_acc[mf][df] = __builtin_amdgcn_mfma_f32_16x16x32_bf16(pa[mf], vf[df], o_acc[mf][df], 0, 0, 0);
        }
    }
    #pragma unroll
    for (int mf = 0; mf < 2; ++mf)
        #pragma unroll
        for (int i = 0; i < 4; ++i) {
            float inv = 1.0f / l_run[mf][i];
            long row = (long)b * Tc + q0 + mf * 16 + g * 4 + i;
            #pragma unroll
            for (int df = 0; df < 4; ++df)
                yout[row * 1024 + h * 64 + df * 16 + c] = f2bu(o_acc[mf][df][i] * inv);
        }
}

// ---------------- AFT gated cumsum, 3-pass chunked ----------------
__global__ void k_aft_p1(const float* __restrict__ qkv, float* __restrict__ cw, float* __restrict__ cs) {
    int id = blockIdx.x * TPB + threadIdx.x;
    int bc = id & 2047, ch = id >> 11;
    int b = bc >> 10, c = bc & 1023;
    const float* base = qkv + ((long)(b * Tc + ch * CHL)) * 3072 + c;
    float sw = 0.f, sv = 0.f;
    for (int i = 0; i < CHL; ++i) {
        float k = base[1024], v = base[2048];
        float e = expf(k);
        sw += e; sv += e * v;
        base += 3072;
    }
    cw[ch * 2048 + bc] = sw; cs[ch * 2048 + bc] = sv;
}

__global__ void k_aft_p2(float* __restrict__ cw, float* __restrict__ cs) {
    int bc = blockIdx.x * TPB + threadIdx.x;
    float rw = 0.f, rv = 0.f;
    for (int ch = 0; ch < NCH; ++ch) {
        long idx = (long)ch * 2048 + bc;
        float tw = cw[idx], tv = cs[idx];
        cw[idx] = rw; cs[idx] = rv; rw += tw; rv += tv;
    }
}

__global__ void k_aft_p3(const float* __restrict__ qkv, const float* __restrict__ cw,
                         const float* __restrict__ cs, unsigned short* __restrict__ y) {
    int id = blockIdx.x * TPB + threadIdx.x;
    int bc = id & 2047, ch = id >> 11;
    int b = bc >> 10, c = bc & 1023;
    long t0 = (long)b * Tc + ch * CHL;
    const float* base = qkv + t0 * 3072 + c;
    unsigned short* yp = y + t0 * 1024 + c;
    float aw = cw[ch * 2048 + bc], av = cs[ch * 2048 + bc];
    for (int i = 0; i < CHL; ++i) {
        float q = base[0], k = base[1024], v = base[2048];
        float e = expf(k);
        av += e * v; aw += e;
        float sig = 1.0f / (1.0f + expf(-q));
        yp[0] = f2bu(sig * av / (aw + 1e-6f));
        base += 3072; yp += 1024;
    }
}

// ---------------- u * silu(v) -> bf16 ----------------
__global__ void k_silu_gate(const float* __restrict__ uv, unsigned short* __restrict__ g, long n4) {
    long i = (long)blockIdx.x * TPB + threadIdx.x;
    if (i >= n4) return;
    long r = i >> 8, c4 = i & 255;
    float4 u = *(const float4*)(uv + r * 2048 + c4 * 4);
    float4 v = *(const float4*)(uv + r * 2048 + 1024 + c4 * 4);
    ushort4 o;
    o.x = f2bu(u.x * v.x / (1.f + expf(-v.x)));
    o.y = f2bu(u.y * v.y / (1.f + expf(-v.y)));
    o.z = f2bu(u.z * v.z / (1.f + expf(-v.z)));
    o.w = f2bu(u.w * v.w / (1.f + expf(-v.w)));
    *(ushort4*)(g + r * 1024 + c4 * 4) = o;
}

// ---------------- w = wT*s*silu(w) + w ----------------
__global__ void k_wupdate(float* __restrict__ w, const float* __restrict__ p,
                          const float* __restrict__ scale, long n4) {
    long i = (long)blockIdx.x * TPB + threadIdx.x;
    if (i >= n4) return;
    float s = scale[0];
    float4 wv = *(const float4*)(w + i * 4);
    float4 pv = *(const float4*)(p + i * 4);
    float4 o;
    o.x = pv.x * s * (wv.x / (1.f + expf(-wv.x))) + wv.x;
    o.y = pv.y * s * (wv.y / (1.f + expf(-wv.y))) + wv.y;
    o.z = pv.z * s * (wv.z / (1.f + expf(-wv.z))) + wv.z;
    o.w = pv.w * s * (wv.w / (1.f + expf(-wv.w))) + wv.w;
    *(float4*)(w + i * 4) = o;
}

// ---------------- row softmax fp32 in place (oa) ----------------
__global__ void k_softmax(float* __restrict__ buf, int cols) {
    __shared__ float red[TPB];
    long row = blockIdx.x;
    float* p = buf + row * cols;
    float m = -3.0e38f;
    for (int c = threadIdx.x; c < cols; c += TPB) m = fmaxf(m, p[c]);
    red[threadIdx.x] = m; __syncthreads();
    for (int o = 128; o > 0; o >>= 1) {
        if (threadIdx.x < o) red[threadIdx.x] = fmaxf(red[threadIdx.x], red[threadIdx.x + o]);
        __syncthreads();
    }
    m = red[0]; __syncthreads();
    float sum = 0.f;
    for (int c = threadIdx.x; c < cols; c += TPB) sum += expf(p[c] - m);
    red[threadIdx.x] = sum; __syncthreads();
    for (int o = 128; o > 0; o >>= 1) {
        if (threadIdx.x < o) red[threadIdx.x] += red[threadIdx.x + o];
        __syncthreads();
    }
    float inv = 1.0f / red[0];
    for (int c = threadIdx.x; c < cols; c += TPB) p[c] = expf(p[c] - m) * inv;
}

// ---------------- tea: rotary + per-head rmsnorm + split, bf16 out ----------------
__global__ void k_rot_split(const float* __restrict__ qkvp, const float* __restrict__ cosp,
                            const float* __restrict__ sinp, unsigned short* __restrict__ hq,
                            unsigned short* __restrict__ hk, unsigned short* __restrict__ hv) {
    __shared__ float row[3072];
    __shared__ float cs[32], sn[32];
    int bt = blockIdx.x;
    int b = bt >> 11, t = bt & 2047;
    const float* src = qkvp + (long)bt * 3072;
    #pragma unroll
    for (int u = 0; u < 3; ++u) {
        int idx = threadIdx.x + u * 256;
        *(float4*)&row[idx * 4] = *(const float4*)(src + idx * 4);
    }
    if (threadIdx.x < 32) { cs[threadIdx.x] = cosp[t * 32 + threadIdx.x]; sn[threadIdx.x] = sinp[t * 32 + threadIdx.x]; }
    __syncthreads();
    int h = threadIdx.x >> 4, li = threadIdx.x & 15;
    int base = h * 192;
    long obase = ((long)(b * Hc + h) * Tc + t) * 64 + li * 4;
    {
        float r[4]; float ss = 0.f;
        #pragma unroll
        for (int j = 0; j < 4; ++j) {
            int d = li * 4 + j;
            float val = (d < 32) ? (row[base + d] * cs[d] + row[base + d + 32] * sn[d])
                                 : (-row[base + d - 32] * sn[d - 32] + row[base + d] * cs[d - 32]);
            r[j] = val; ss += val * val;
        }
        ss += __shfl_xor(ss, 1); ss += __shfl_xor(ss, 2); ss += __shfl_xor(ss, 4); ss += __shfl_xor(ss, 8);
        float sc = rsqrtf(ss / 64.0f + F32_EPS);
        ushort4 o; o.x = f2bu(r[0] * sc); o.y = f2bu(r[1] * sc); o.z = f2bu(r[2] * sc); o.w = f2bu(r[3] * sc);
        *(ushort4*)(hq + obase) = o;
    }
    {
        int kb = base + 64;
        float r[4]; float ss = 0.f;
        #pragma unroll
        for (int j = 0; j < 4; ++j) {
            int d = li * 4 + j;
            float val = (d < 32) ? (row[kb + d] * cs[d] + row[kb + d + 32] * sn[d])
                                 : (-row[kb + d - 32] * sn[d - 32] + row[kb + d] * cs[d - 32]);
            r[j] = val; ss += val * val;
        }
        ss += __shfl_xor(ss, 1); ss += __shfl_xor(ss, 2); ss += __shfl_xor(ss, 4); ss += __shfl_xor(ss, 8);
        float sc = rsqrtf(ss / 64.0f + F32_EPS);
        ushort4 o; o.x = f2bu(r[0] * sc); o.y = f2bu(r[1] * sc); o.z = f2bu(r[2] * sc); o.w = f2bu(r[3] * sc);
        *(ushort4*)(hk + obase) = o;
    }
    {
        ushort4 o;
        o.x = f2bu(row[base + 128 + li * 4 + 0]); o.y = f2bu(row[base + 128 + li * 4 + 1]);
        o.z = f2bu(row[base + 128 + li * 4 + 2]); o.w = f2bu(row[base + 128 + li * 4 + 3]);
        *(ushort4*)(hv + obase) = o;
    }
}

extern "C" void kernel_launch(void* const* d_in, const int* in_sizes, int n_in,
                              void* d_out, int out_size, void* d_ws, size_t ws_size,
                              hipStream_t stream) {
    const float* x_in = (const float*)d_in[0];
    const float* w_in = (const float*)d_in[1];
    const float* cos_in = (const float*)d_in[2];
    const float* sin_in = (const float*)d_in[3];
    float* out = (float*)d_out;
    float* ws = (float*)d_ws;

    long off = 0;
    float* w_cur = ws + off;  off += (long)WR * Ec;
    float* w_tmp = ws + off;  off += (long)WR * Ec;
    float* xbuf  = ws + off;  off += BT * Ec;
    float* qkv   = ws + off;  off += BT * 3L * QKVc;
    float* oab   = ws + off;  off += (long)Ec * Ec;
    float* red   = ws + off;  off += 1024;
    float* scales= ws + off;  off += 16;
    float* uscale= ws + off;  off += 4096;
    float* chw   = ws + off;  off += 2048L * NCH;
    float* chs   = ws + off;  off += 2048L * NCH;
    float* uv    = qkv;

    unsigned short* bp = (unsigned short*)(ws + off);
    long bo = 0;
    unsigned short* wb  = bp + bo; bo += (long)WR * Ec;
    unsigned short* xbn = bp + bo; bo += BT * Ec;
    unsigned short* ybn = bp + bo; bo += BT * Ec;
    unsigned short* gbn = bp + bo; bo += BT * Ec;
    unsigned short* t1  = bp + bo; bo += BT * Ec;            // o^T | hq
    unsigned short* t2  = bp + bo; bo += BT * Ec;            // v^T | hk
    unsigned short* t3  = bp + bo; bo += BT * Ec;            // oa^T | hvS
    unsigned short* t4  = bp + bo; bo += BT * Ec;            // hvT

    hipMemcpyAsync(w_cur, w_in, (size_t)WR * Ec * 4, hipMemcpyDeviceToDevice, stream);
    hipMemcpyAsync(xbuf, x_in, (size_t)BT * Ec * 4, hipMemcpyDeviceToDevice, stream);

    const float rs32 = 0.03125f;
    const float rsWR = 1.0f / sqrtf(6144.0f);
    const long wsw = 3072L * 1024, wout = 5120L * 1024;

    auto stdscale = [&](const float* p, long n, float rs, int slot) {
        k_std_partial<<<256, TPB, 0, stream>>>(p, n, red);
        k_std_final<<<1, TPB, 0, stream>>>(red, (float)n, rs, scales + slot);
    };

    for (int layer = 0; layer < 2; ++layer) {
        stdscale(w_cur,        3072L * 1024, rs32, 0);
        stdscale(w_cur + wsw,  2048L * 1024, rs32, 1);
        stdscale(w_cur + wout, 1024L * 1024, rs32, 2);
        k_cast_bf16<<<(int)(((long)WR * Ec / 4) / TPB), TPB, 0, stream>>>(w_cur, wb, (long)WR * Ec / 4);
        k_rms1024b<<<BT, TPB, 0, stream>>>(xbuf, xbn, 1024, 1024);
        k_bgemm<2, 2, 0><<<dim3(24, 32, 1), TPB, 0, stream>>>(
            1024, xbn, 1024, 0, wb, 1024, 0, qkv, 3072, 0, scales + 0, 1.0f, nullptr, 0);
        k_rms1024<<<BT, TPB, 0, stream>>>(qkv, qkv, 3072, 3072);
        k_rms1024<<<BT, TPB, 0, stream>>>(qkv + 1024, qkv + 1024, 3072, 3072);
        k_aft_p1<<<(2048 * NCH) / TPB, TPB, 0, stream>>>(qkv, chw, chs);
        k_aft_p2<<<2048 / TPB, TPB, 0, stream>>>(chw, chs);
        k_aft_p3<<<(2048 * NCH) / TPB, TPB, 0, stream>>>(qkv, chw, chs, ybn);
        k_bgemm<2, 2, 0><<<dim3(16, 32, 1), TPB, 0, stream>>>(
            1024, ybn, 1024, 0, wb + wsw, 1024, 0, uv, 2048, 0, scales + 1, 1.0f, nullptr, 0);
        k_silu_gate<<<(int)((BT * 1024 / 4) / TPB), TPB, 0, stream>>>(uv, gbn, BT * 1024 / 4);
        k_rowrms<<<BT, TPB, 0, stream>>>(uv, 2048, uscale);
        k_tcast<float><<<dim3(16, 64, 1), TPB, 0, stream>>>(uv, 2048, 0, t1, 4096, 0, uscale);
        k_tcast<float><<<dim3(16, 64, 1), TPB, 0, stream>>>(uv + 1024, 2048, 0, t2, 4096, 0, nullptr);
        k_bgemm<2, 2, 0><<<dim3(8, 8, 1), TPB, 0, stream>>>(
            4096, t1, 4096, 0, t2, 4096, 0, oab, 1024, 0, nullptr, 0.03125f, nullptr, 0);
        k_softmax<<<1024, TPB, 0, stream>>>(oab, 1024);
        k_tcast<float><<<dim3(16, 16, 1), TPB, 0, stream>>>(oab, 1024, 0, t3, 1024, 0, nullptr);
        k_bgemm<2, 2, 0><<<dim3(8, 32, 1), TPB, 0, stream>>>(
            1024, gbn, 1024, 0, wb + wout, 1024, 0, xbuf, 1024, 0, scales + 2, 1.0f, xbuf, 1024);
        k_bgemm<2, 2, 0><<<dim3(8, 48, 1), TPB, 0, stream>>>(
            1024, wb, 1024, 0, t3, 1024, 0, w_tmp, 1024, 0, nullptr, 1.0f, nullptr, 0);
        stdscale(w_tmp, (long)WR * 1024, rsWR, 3);
        k_wupdate<<<(int)(((long)WR * 1024 / 4) / TPB), TPB, 0, stream>>>(w_cur, w_tmp, scales + 3, (long)WR * 1024 / 4);
    }

    // -------- final tea (no w_norm) --------
    k_cast_bf16<<<(int)(((long)WR * Ec / 4) / TPB), TPB, 0, stream>>>(w_cur, wb, (long)WR * Ec / 4);
    k_rms1024b<<<BT, TPB, 0, stream>>>(xbuf, xbn, 1024, 1024);
    k_bgemm<2, 2, 0><<<dim3(24, 32, 1), TPB, 0, stream>>>(
        1024, xbn, 1024, 0, wb, 1024, 0, qkv, 3072, 0, nullptr, 1.0f, nullptr, 0);
    k_rot_split<<<BT, TPB, 0, stream>>>(qkv, cos_in, sin_in, t1, t2, t3);
    k_tcast<unsigned short><<<dim3(1, 32, 32), TPB, 0, stream>>>(
        t3, 64, (long)Tc * 64, t4, 2048, (long)Tc * 64, nullptr);
    // fused causal flash attention over all 32 bh
    k_flash<<<dim3(16, 32), TPB, 0, stream>>>(t1, t2, t4, ybn);
    // final swiglu -> d_out
    k_bgemm<2, 2, 0><<<dim3(16, 32, 1), TPB, 0, stream>>>(
        1024, ybn, 1024, 0, wb + wsw, 1024, 0, uv, 2048, 0, nullptr, 1.0f, nullptr, 0);
    k_silu_gate<<<(int)((BT * 1024 / 4) / TPB), TPB, 0, stream>>>(uv, gbn, BT * 1024 / 4);
    k_bgemm<2, 2, 0><<<dim3(8, 32, 1), TPB, 0, stream>>>(
        1024, gbn, 1024, 0, wb + wout, 1024, 0, out, 1024, 0, nullptr, 1.0f, xbuf, 1024);
}

// Round 4
// 968.407 us; speedup vs baseline: 4.7848x; 1.1549x over previous
//
#include <hip/hip_runtime.h>
#include <hip/hip_bf16.h>
#include <math.h>

#define TPB 256

constexpr int Bc = 2, Tc = 2048, Ec = 1024, QKVc = 1024, Hc = 16, DHc = 64;
constexpr long BT = (long)Bc * Tc;     // 4096
constexpr int WR = 5 * QKVc + Ec;      // 6144
constexpr float F32_EPS = 1.1920928955078125e-07f;
constexpr int NCH = 32, CHL = Tc / NCH;

typedef __attribute__((ext_vector_type(8))) short short8;
typedef __attribute__((ext_vector_type(4))) float f32x4;

__device__ __forceinline__ unsigned short f2bu(float f) {
    union { __hip_bfloat16 h; unsigned short u; } c; c.h = __float2bfloat16(f); return c.u;
}
__device__ __forceinline__ float bu2f(unsigned short u) {
    union { __hip_bfloat16 h; unsigned short u; } c; c.u = u; return __bfloat162float(c.h);
}
__device__ __forceinline__ float ldval(const float* p) { return *p; }
__device__ __forceinline__ float ldval(const unsigned short* p) { return bu2f(*p); }

__device__ __forceinline__ void gload_lds16(const void* g, void* l) {
    __builtin_amdgcn_global_load_lds((const __attribute__((address_space(1))) void*)g,
                                     (__attribute__((address_space(3))) void*)l, 16, 0, 0);
}

// ---------------- global std (ddof=1) -> scale = rs/(std+1e-8) ----------------
__global__ void k_std_partial(const float* __restrict__ p, long n, float* __restrict__ out) {
    __shared__ float ls[TPB], lss[TPB];
    float s = 0.f, ss = 0.f;
    for (long i = (long)blockIdx.x * TPB + threadIdx.x; i < n; i += (long)gridDim.x * TPB) {
        float v = p[i]; s += v; ss += v * v;
    }
    ls[threadIdx.x] = s; lss[threadIdx.x] = ss; __syncthreads();
    for (int o = 128; o > 0; o >>= 1) {
        if (threadIdx.x < o) { ls[threadIdx.x] += ls[threadIdx.x + o]; lss[threadIdx.x] += lss[threadIdx.x + o]; }
        __syncthreads();
    }
    if (threadIdx.x == 0) { out[blockIdx.x] = ls[0]; out[gridDim.x + blockIdx.x] = lss[0]; }
}

__global__ void k_std_final(const float* __restrict__ part, float n, float rs, float* __restrict__ scale) {
    __shared__ float ls[TPB], lss[TPB];
    ls[threadIdx.x] = part[threadIdx.x];
    lss[threadIdx.x] = part[TPB + threadIdx.x];
    __syncthreads();
    for (int o = 128; o > 0; o >>= 1) {
        if (threadIdx.x < o) { ls[threadIdx.x] += ls[threadIdx.x + o]; lss[threadIdx.x] += lss[threadIdx.x + o]; }
        __syncthreads();
    }
    if (threadIdx.x == 0) {
        float var = (lss[0] - ls[0] * ls[0] / n) / (n - 1.0f);
        scale[0] = rs / (sqrtf(fmaxf(var, 0.0f)) + 1e-8f);
    }
}

// ---------------- rmsnorm over 1024 cols, fp32 out ----------------
__global__ void k_rms1024(const float* __restrict__ in, float* __restrict__ out, long ldin, long ldout) {
    __shared__ float red[TPB];
    long row = blockIdx.x;
    float4 v = *(const float4*)(in + row * ldin + threadIdx.x * 4);
    float ss = v.x * v.x + v.y * v.y + v.z * v.z + v.w * v.w;
    red[threadIdx.x] = ss; __syncthreads();
    for (int o = 128; o > 0; o >>= 1) {
        if (threadIdx.x < o) red[threadIdx.x] += red[threadIdx.x + o];
        __syncthreads();
    }
    float sc = rsqrtf(red[0] / 1024.0f + F32_EPS);
    float4 o4; o4.x = v.x * sc; o4.y = v.y * sc; o4.z = v.z * sc; o4.w = v.w * sc;
    *(float4*)(out + row * ldout + threadIdx.x * 4) = o4;
}

// ---------------- rmsnorm over 1024 cols, bf16 out ----------------
__global__ void k_rms1024b(const float* __restrict__ in, unsigned short* __restrict__ out, long ldin, long ldout) {
    __shared__ float red[TPB];
    long row = blockIdx.x;
    float4 v = *(const float4*)(in + row * ldin + threadIdx.x * 4);
    float ss = v.x * v.x + v.y * v.y + v.z * v.z + v.w * v.w;
    red[threadIdx.x] = ss; __syncthreads();
    for (int o = 128; o > 0; o >>= 1) {
        if (threadIdx.x < o) red[threadIdx.x] += red[threadIdx.x + o];
        __syncthreads();
    }
    float sc = rsqrtf(red[0] / 1024.0f + F32_EPS);
    ushort4 o4; o4.x = f2bu(v.x * sc); o4.y = f2bu(v.y * sc); o4.z = f2bu(v.z * sc); o4.w = f2bu(v.w * sc);
    *(ushort4*)(out + row * ldout + threadIdx.x * 4) = o4;
}

// ---------------- per-row rms scale (1024 cols) ----------------
__global__ void k_rowrms(const float* __restrict__ in, long ld, float* __restrict__ rs) {
    __shared__ float red[TPB];
    long row = blockIdx.x;
    float4 v = *(const float4*)(in + row * ld + threadIdx.x * 4);
    red[threadIdx.x] = v.x * v.x + v.y * v.y + v.z * v.z + v.w * v.w;
    __syncthreads();
    for (int o = 128; o > 0; o >>= 1) {
        if (threadIdx.x < o) red[threadIdx.x] += red[threadIdx.x + o];
        __syncthreads();
    }
    if (threadIdx.x == 0) rs[row] = rsqrtf(red[0] / 1024.0f + F32_EPS);
}

// ---------------- fp32 -> bf16 cast ----------------
__global__ void k_cast_bf16(const float* __restrict__ in, unsigned short* __restrict__ out, long n4) {
    long i = (long)blockIdx.x * TPB + threadIdx.x;
    if (i >= n4) return;
    float4 v = *(const float4*)(in + i * 4);
    ushort4 o; o.x = f2bu(v.x); o.y = f2bu(v.y); o.z = f2bu(v.z); o.w = f2bu(v.w);
    *(ushort4*)(out + i * 4) = o;
}

// ---------------- transpose-cast: in[R][C] (ld, opt rowscale) -> bf16 out[C][R] ----------------
template<typename TI>
__global__ void k_tcast(const TI* __restrict__ in, long ldi, long sIn,
                        unsigned short* __restrict__ out, long ldo, long sOut,
                        const float* __restrict__ rowscale) {
    __shared__ float tile[64][65];
    const TI* ip = in + (long)blockIdx.z * sIn;
    unsigned short* op = out + (long)blockIdx.z * sOut;
    int r0 = blockIdx.y * 64, c0 = blockIdx.x * 64;
    int tid = threadIdx.x;
    int rr = tid >> 4, cc = (tid & 15) * 4;
    #pragma unroll
    for (int u = 0; u < 4; ++u) {
        int r = rr + u * 16;
        float sc = rowscale ? rowscale[r0 + r] : 1.0f;
        #pragma unroll
        for (int j = 0; j < 4; ++j)
            tile[r][cc + j] = ldval(ip + (long)(r0 + r) * ldi + c0 + cc + j) * sc;
    }
    __syncthreads();
    #pragma unroll
    for (int u = 0; u < 4; ++u) {
        int c = rr + u * 16;
        ushort4 o;
        o.x = f2bu(tile[cc + 0][c]); o.y = f2bu(tile[cc + 1][c]);
        o.z = f2bu(tile[cc + 2][c]); o.w = f2bu(tile[cc + 3][c]);
        *(ushort4*)(op + (long)(c0 + c) * ldo + r0 + cc) = o;
    }
}

// ---------------- bf16 MFMA GEMM, NT: C[M,N] = s * A[M,K] @ B[N,K]^T (+add), opt split-K ----------------
template<int WGM, int WGN, int WRITE_BF16>
__global__ __launch_bounds__(256)
void k_bgemm(int K,
             const unsigned short* __restrict__ A, int lda, long sA,
             const unsigned short* __restrict__ B, int ldb, long sB,
             void* __restrict__ C, int ldc, long sCi, long sSplit, int nsplit,
             const float* __restrict__ scale_ptr, float fscale,
             const float* __restrict__ addp, int ldadd) {
    constexpr int TM = WGM * 64, TN = WGN * 64;
    __shared__ unsigned short Asl[TM * 32];
    __shared__ unsigned short Bsl[TN * 32];
    int bz = blockIdx.z;
    int batch = bz, sp = 0;
    if (nsplit > 1) { batch = bz / nsplit; sp = bz - batch * nsplit; }
    int m0 = blockIdx.y * TM, n0 = blockIdx.x * TN;
    const unsigned short* Ap = A + (long)batch * sA + (long)sp * K;
    const unsigned short* Bp = B + (long)batch * sB + (long)sp * K;
    int tid = threadIdx.x, lane = tid & 63, wave = tid >> 6;
    int wr = wave / WGN, wc = wave % WGN;
    f32x4 acc[4][4] = {};
    constexpr int CAW = TM / 64;
    constexpr int CBW = TN / 64;
    for (int k0 = 0; k0 < K; k0 += 32) {
        #pragma unroll
        for (int c = 0; c < CAW; ++c) {
            int bu = (wave * CAW + c) * 64;
            int uidx = bu + lane;
            int r = uidx >> 2, slot = uidx & 3;
            int gu = slot ^ ((r >> 1) & 3);
            gload_lds16(Ap + (long)(m0 + r) * lda + k0 + gu * 8, Asl + bu * 8);
        }
        #pragma unroll
        for (int c = 0; c < CBW; ++c) {
            int bu = (wave * CBW + c) * 64;
            int uidx = bu + lane;
            int r = uidx >> 2, slot = uidx & 3;
            int gu = slot ^ ((r >> 1) & 3);
            gload_lds16(Bp + (long)(n0 + r) * ldb + k0 + gu * 8, Bsl + bu * 8);
        }
        __syncthreads();
        short8 av[4], bv[4];
        #pragma unroll
        for (int m = 0; m < 4; ++m) {
            int r = wr * 64 + m * 16 + (lane & 15);
            int slot = (lane >> 4) ^ ((r >> 1) & 3);
            av[m] = *(const short8*)(Asl + r * 32 + slot * 8);
        }
        #pragma unroll
        for (int n = 0; n < 4; ++n) {
            int r = wc * 64 + n * 16 + (lane & 15);
            int slot = (lane >> 4) ^ ((r >> 1) & 3);
            bv[n] = *(const short8*)(Bsl + r * 32 + slot * 8);
        }
        #pragma unroll
        for (int m = 0; m < 4; ++m)
            #pragma unroll
            for (int n = 0; n < 4; ++n)
                acc[m][n] = __builtin_amdgcn_mfma_f32_16x16x32_bf16(av[m], bv[n], acc[m][n], 0, 0, 0);
        __syncthreads();
    }
    float s = fscale * (scale_ptr ? scale_ptr[0] : 1.0f);
    long cbase = (long)batch * sCi + (long)sp * sSplit;
    int row0 = m0 + wr * 64, col0 = n0 + wc * 64 + (lane & 15);
    int rbase = (lane >> 4) * 4;
    #pragma unroll
    for (int m = 0; m < 4; ++m)
        #pragma unroll
        for (int i = 0; i < 4; ++i) {
            long row = row0 + m * 16 + rbase + i;
            #pragma unroll
            for (int n = 0; n < 4; ++n) {
                long col = col0 + n * 16;
                float v = acc[m][n][i] * s;
                if (addp) v += addp[row * (long)ldadd + col];
                long idx = cbase + row * ldc + col;
                if (WRITE_BF16) ((unsigned short*)C)[idx] = f2bu(v);
                else ((float*)C)[idx] = v;
            }
        }
}

// ---------------- fused causal flash attention, 1 wave / block ----------------
// Q,K: [bh][T][64] bf16; V^T: [bh][64][T] bf16; out: ybn [b][T][1024] head-interleaved.
// 1D grid of 2048: XCD-swizzled (each XCD owns 4 bh), longest strip first.
__global__ __launch_bounds__(64)
void k_flash(const unsigned short* __restrict__ hq, const unsigned short* __restrict__ hk,
             const unsigned short* __restrict__ hvT, unsigned short* __restrict__ yout) {
    __shared__ unsigned short P[32 * 72];
    int lane = threadIdx.x;
    int g = lane >> 4, c = lane & 15;
    unsigned swz = (blockIdx.x & 7) * 256 + (blockIdx.x >> 3);
    int strip = 63 - (swz & 63);
    int bh = swz >> 6, b = bh >> 4, h = bh & 15;
    int q0 = strip * 32;
    const unsigned short* qb = hq + (long)bh * Tc * 64;
    const unsigned short* kb = hk + (long)bh * Tc * 64;
    const unsigned short* vtb = hvT + (long)bh * 64 * Tc;

    short8 qf[2][2];
    #pragma unroll
    for (int mf = 0; mf < 2; ++mf)
        #pragma unroll
        for (int ks = 0; ks < 2; ++ks)
            qf[mf][ks] = *(const short8*)(qb + (long)(q0 + mf * 16 + c) * 64 + ks * 32 + g * 8);

    f32x4 o_acc[2][4] = {};
    float m_run[2][4], l_run[2][4];
    #pragma unroll
    for (int mf = 0; mf < 2; ++mf)
        #pragma unroll
        for (int i = 0; i < 4; ++i) { m_run[mf][i] = -3.0e38f; l_run[mf][i] = 0.f; }

    int nt = (q0 + 32 + 63) >> 6;
    for (int ti = 0; ti < nt; ++ti) {
        int kt = ti * 64;
        f32x4 s_acc[2][4] = {};
        #pragma unroll
        for (int ks = 0; ks < 2; ++ks) {
            short8 kf[4];
            #pragma unroll
            for (int nf = 0; nf < 4; ++nf)
                kf[nf] = *(const short8*)(kb + (long)(kt + nf * 16 + c) * 64 + ks * 32 + g * 8);
            #pragma unroll
            for (int mf = 0; mf < 2; ++mf)
                #pragma unroll
                for (int nf = 0; nf < 4; ++nf)
                    s_acc[mf][nf] = __builtin_amdgcn_mfma_f32_16x16x32_bf16(qf[mf][ks], kf[nf], s_acc[mf][nf], 0, 0, 0);
        }
        bool diag = (kt + 64 > q0);
        #pragma unroll
        for (int mf = 0; mf < 2; ++mf) {
            float sv[4][4];
            float pm[4] = {-3.0e38f, -3.0e38f, -3.0e38f, -3.0e38f};
            #pragma unroll
            for (int nf = 0; nf < 4; ++nf)
                #pragma unroll
                for (int i = 0; i < 4; ++i) {
                    float v = s_acc[mf][nf][i] * 0.125f;
                    if (diag) {
                        int kg = kt + nf * 16 + c;
                        int qg = q0 + mf * 16 + g * 4 + i;
                        if (kg > qg) v = -3.0e38f;
                    }
                    sv[nf][i] = v;
                    pm[i] = fmaxf(pm[i], v);
                }
            #pragma unroll
            for (int i = 0; i < 4; ++i) {
                float t = pm[i];
                t = fmaxf(t, __shfl_xor(t, 1));
                t = fmaxf(t, __shfl_xor(t, 2));
                t = fmaxf(t, __shfl_xor(t, 4));
                t = fmaxf(t, __shfl_xor(t, 8));
                float mn = fmaxf(m_run[mf][i], t);
                float corr = __expf(m_run[mf][i] - mn);
                m_run[mf][i] = mn;
                float ls = 0.f;
                #pragma unroll
                for (int nf = 0; nf < 4; ++nf) {
                    float p = __expf(sv[nf][i] - mn);
                    unsigned short pb = f2bu(p);
                    P[(mf * 16 + g * 4 + i) * 72 + nf * 16 + c] = pb;
                    ls += bu2f(pb);
                }
                ls += __shfl_xor(ls, 1); ls += __shfl_xor(ls, 2);
                ls += __shfl_xor(ls, 4); ls += __shfl_xor(ls, 8);
                l_run[mf][i] = l_run[mf][i] * corr + ls;
                #pragma unroll
                for (int df = 0; df < 4; ++df) o_acc[mf][df][i] *= corr;
            }
        }
        #pragma unroll
        for (int ks = 0; ks < 2; ++ks) {
            short8 pa[2], vf[4];
            #pragma unroll
            for (int mf = 0; mf < 2; ++mf)
                pa[mf] = *(const short8*)(P + (mf * 16 + c) * 72 + ks * 32 + g * 8);
            #pragma unroll
            for (int df = 0; df < 4; ++df)
                vf[df] = *(const short8*)(vtb + (long)(df * 16 + c) * Tc + kt + ks * 32 + g * 8);
            #pragma unroll
            for (int mf = 0; mf < 2; ++mf)
                #pragma unroll
                for (int df = 0; df < 4; ++df)
                    o_acc[mf][df] = __builtin_amdgcn_mfma_f32_16x16x32_bf16(pa[mf], vf[df], o_acc[mf][df], 0, 0, 0);
        }
    }
    #pragma unroll
    for (int mf = 0; mf < 2; ++mf)
        #pragma unroll
        for (int i = 0; i < 4; ++i) {
            float inv = 1.0f / l_run[mf][i];
            long row = (long)b * Tc + q0 + mf * 16 + g * 4 + i;
            #pragma unroll
            for (int df = 0; df < 4; ++df)
                yout[row * 1024 + h * 64 + df * 16 + c] = f2bu(o_acc[mf][df][i] * inv);
        }
}

// ---------------- AFT gated cumsum, 3-pass chunked ----------------
__global__ void k_aft_p1(const float* __restrict__ qkv, float* __restrict__ cw, float* __restrict__ cs) {
    int id = blockIdx.x * TPB + threadIdx.x;
    int bc = id & 2047, ch = id >> 11;
    int b = bc >> 10, c = bc & 1023;
    const float* base = qkv + ((long)(b * Tc + ch * CHL)) * 3072 + c;
    float sw = 0.f, sv = 0.f;
    for (int i = 0; i < CHL; ++i) {
        float k = base[1024], v = base[2048];
        float e = expf(k);
        sw += e; sv += e * v;
        base += 3072;
    }
    cw[ch * 2048 + bc] = sw; cs[ch * 2048 + bc] = sv;
}

__global__ void k_aft_p2(float* __restrict__ cw, float* __restrict__ cs) {
    int bc = blockIdx.x * TPB + threadIdx.x;
    float rw = 0.f, rv = 0.f;
    for (int ch = 0; ch < NCH; ++ch) {
        long idx = (long)ch * 2048 + bc;
        float tw = cw[idx], tv = cs[idx];
        cw[idx] = rw; cs[idx] = rv; rw += tw; rv += tv;
    }
}

__global__ void k_aft_p3(const float* __restrict__ qkv, const float* __restrict__ cw,
                         const float* __restrict__ cs, unsigned short* __restrict__ y) {
    int id = blockIdx.x * TPB + threadIdx.x;
    int bc = id & 2047, ch = id >> 11;
    int b = bc >> 10, c = bc & 1023;
    long t0 = (long)b * Tc + ch * CHL;
    const float* base = qkv + t0 * 3072 + c;
    unsigned short* yp = y + t0 * 1024 + c;
    float aw = cw[ch * 2048 + bc], av = cs[ch * 2048 + bc];
    for (int i = 0; i < CHL; ++i) {
        float q = base[0], k = base[1024], v = base[2048];
        float e = expf(k);
        av += e * v; aw += e;
        float sig = 1.0f / (1.0f + expf(-q));
        yp[0] = f2bu(sig * av / (aw + 1e-6f));
        base += 3072; yp += 1024;
    }
}

// ---------------- u * silu(v) -> bf16 ----------------
__global__ void k_silu_gate(const float* __restrict__ uv, unsigned short* __restrict__ g, long n4) {
    long i = (long)blockIdx.x * TPB + threadIdx.x;
    if (i >= n4) return;
    long r = i >> 8, c4 = i & 255;
    float4 u = *(const float4*)(uv + r * 2048 + c4 * 4);
    float4 v = *(const float4*)(uv + r * 2048 + 1024 + c4 * 4);
    ushort4 o;
    o.x = f2bu(u.x * v.x / (1.f + expf(-v.x)));
    o.y = f2bu(u.y * v.y / (1.f + expf(-v.y)));
    o.z = f2bu(u.z * v.z / (1.f + expf(-v.z)));
    o.w = f2bu(u.w * v.w / (1.f + expf(-v.w)));
    *(ushort4*)(g + r * 1024 + c4 * 4) = o;
}

// ---------------- w = wT*s*silu(w) + w  (also emits bf16 copy) ----------------
__global__ void k_wupdate(float* __restrict__ w, const float* __restrict__ p,
                          const float* __restrict__ scale, unsigned short* __restrict__ wb, long n4) {
    long i = (long)blockIdx.x * TPB + threadIdx.x;
    if (i >= n4) return;
    float s = scale[0];
    float4 wv = *(const float4*)(w + i * 4);
    float4 pv = *(const float4*)(p + i * 4);
    float4 o;
    o.x = pv.x * s * (wv.x / (1.f + expf(-wv.x))) + wv.x;
    o.y = pv.y * s * (wv.y / (1.f + expf(-wv.y))) + wv.y;
    o.z = pv.z * s * (wv.z / (1.f + expf(-wv.z))) + wv.z;
    o.w = pv.w * s * (wv.w / (1.f + expf(-wv.w))) + wv.w;
    *(float4*)(w + i * 4) = o;
    ushort4 ob; ob.x = f2bu(o.x); ob.y = f2bu(o.y); ob.z = f2bu(o.z); ob.w = f2bu(o.w);
    *(ushort4*)(wb + i * 4) = ob;
}

// ---------------- 4-slab reduce + scale + row softmax -> fp32 out ----------------
__global__ void k_softmax4(const float* __restrict__ parts, float* __restrict__ outb, float fscale) {
    __shared__ float red[TPB];
    __shared__ float rowbuf[1024];
    long row = blockIdx.x;
    const float* p0 = parts + row * 1024;
    for (int c = threadIdx.x; c < 1024; c += TPB) {
        float v = p0[c] + p0[c + 1048576] + p0[c + 2097152] + p0[c + 3145728];
        rowbuf[c] = v * fscale;
    }
    __syncthreads();
    float m = -3.0e38f;
    for (int c = threadIdx.x; c < 1024; c += TPB) m = fmaxf(m, rowbuf[c]);
    red[threadIdx.x] = m; __syncthreads();
    for (int o = 128; o > 0; o >>= 1) {
        if (threadIdx.x < o) red[threadIdx.x] = fmaxf(red[threadIdx.x], red[threadIdx.x + o]);
        __syncthreads();
    }
    m = red[0]; __syncthreads();
    float sum = 0.f;
    for (int c = threadIdx.x; c < 1024; c += TPB) sum += expf(rowbuf[c] - m);
    red[threadIdx.x] = sum; __syncthreads();
    for (int o = 128; o > 0; o >>= 1) {
        if (threadIdx.x < o) red[threadIdx.x] += red[threadIdx.x + o];
        __syncthreads();
    }
    float inv = 1.0f / red[0];
    for (int c = threadIdx.x; c < 1024; c += TPB)
        outb[row * 1024 + c] = expf(rowbuf[c] - m) * inv;
}

// ---------------- tea: rotary + per-head rmsnorm + split, bf16 out ----------------
__global__ void k_rot_split(const float* __restrict__ qkvp, const float* __restrict__ cosp,
                            const float* __restrict__ sinp, unsigned short* __restrict__ hq,
                            unsigned short* __restrict__ hk, unsigned short* __restrict__ hv) {
    __shared__ float row[3072];
    __shared__ float cs[32], sn[32];
    int bt = blockIdx.x;
    int b = bt >> 11, t = bt & 2047;
    const float* src = qkvp + (long)bt * 3072;
    #pragma unroll
    for (int u = 0; u < 3; ++u) {
        int idx = threadIdx.x + u * 256;
        *(float4*)&row[idx * 4] = *(const float4*)(src + idx * 4);
    }
    if (threadIdx.x < 32) { cs[threadIdx.x] = cosp[t * 32 + threadIdx.x]; sn[threadIdx.x] = sinp[t * 32 + threadIdx.x]; }
    __syncthreads();
    int h = threadIdx.x >> 4, li = threadIdx.x & 15;
    int base = h * 192;
    long obase = ((long)(b * Hc + h) * Tc + t) * 64 + li * 4;
    {
        float r[4]; float ss = 0.f;
        #pragma unroll
        for (int j = 0; j < 4; ++j) {
            int d = li * 4 + j;
            float val = (d < 32) ? (row[base + d] * cs[d] + row[base + d + 32] * sn[d])
                                 : (-row[base + d - 32] * sn[d - 32] + row[base + d] * cs[d - 32]);
            r[j] = val; ss += val * val;
        }
        ss += __shfl_xor(ss, 1); ss += __shfl_xor(ss, 2); ss += __shfl_xor(ss, 4); ss += __shfl_xor(ss, 8);
        float sc = rsqrtf(ss / 64.0f + F32_EPS);
        ushort4 o; o.x = f2bu(r[0] * sc); o.y = f2bu(r[1] * sc); o.z = f2bu(r[2] * sc); o.w = f2bu(r[3] * sc);
        *(ushort4*)(hq + obase) = o;
    }
    {
        int kb = base + 64;
        float r[4]; float ss = 0.f;
        #pragma unroll
        for (int j = 0; j < 4; ++j) {
            int d = li * 4 + j;
            float val = (d < 32) ? (row[kb + d] * cs[d] + row[kb + d + 32] * sn[d])
                                 : (-row[kb + d - 32] * sn[d - 32] + row[kb + d] * cs[d - 32]);
            r[j] = val; ss += val * val;
        }
        ss += __shfl_xor(ss, 1); ss += __shfl_xor(ss, 2); ss += __shfl_xor(ss, 4); ss += __shfl_xor(ss, 8);
        float sc = rsqrtf(ss / 64.0f + F32_EPS);
        ushort4 o; o.x = f2bu(r[0] * sc); o.y = f2bu(r[1] * sc); o.z = f2bu(r[2] * sc); o.w = f2bu(r[3] * sc);
        *(ushort4*)(hk + obase) = o;
    }
    {
        ushort4 o;
        o.x = f2bu(row[base + 128 + li * 4 + 0]); o.y = f2bu(row[base + 128 + li * 4 + 1]);
        o.z = f2bu(row[base + 128 + li * 4 + 2]); o.w = f2bu(row[base + 128 + li * 4 + 3]);
        *(ushort4*)(hv + obase) = o;
    }
}

extern "C" void kernel_launch(void* const* d_in, const int* in_sizes, int n_in,
                              void* d_out, int out_size, void* d_ws, size_t ws_size,
                              hipStream_t stream) {
    const float* x_in = (const float*)d_in[0];
    const float* w_in = (const float*)d_in[1];
    const float* cos_in = (const float*)d_in[2];
    const float* sin_in = (const float*)d_in[3];
    float* out = (float*)d_out;
    float* ws = (float*)d_ws;

    long off = 0;
    float* w_cur = ws + off;  off += (long)WR * Ec;
    float* w_tmp = ws + off;  off += (long)WR * Ec;   // also: oa split-K partials (4M floats)
    float* xbuf  = ws + off;  off += BT * Ec;
    float* qkv   = ws + off;  off += BT * 3L * QKVc;
    float* oab   = ws + off;  off += (long)Ec * Ec;
    float* red   = ws + off;  off += 1024;
    float* scales= ws + off;  off += 16;
    float* uscale= ws + off;  off += 4096;
    float* chw   = ws + off;  off += 2048L * NCH;
    float* chs   = ws + off;  off += 2048L * NCH;
    float* uv    = qkv;

    unsigned short* bp = (unsigned short*)(ws + off);
    long bo = 0;
    unsigned short* wb  = bp + bo; bo += (long)WR * Ec;
    unsigned short* xbn = bp + bo; bo += BT * Ec;
    unsigned short* ybn = bp + bo; bo += BT * Ec;
    unsigned short* gbn = bp + bo; bo += BT * Ec;
    unsigned short* t1  = bp + bo; bo += BT * Ec;            // o^T | hq
    unsigned short* t2  = bp + bo; bo += BT * Ec;            // v^T | hk
    unsigned short* t3  = bp + bo; bo += BT * Ec;            // oa^T | hvS
    unsigned short* t4  = bp + bo; bo += BT * Ec;            // hvT

    hipMemcpyAsync(w_cur, w_in, (size_t)WR * Ec * 4, hipMemcpyDeviceToDevice, stream);
    hipMemcpyAsync(xbuf, x_in, (size_t)BT * Ec * 4, hipMemcpyDeviceToDevice, stream);

    const float rs32 = 0.03125f;
    const float rsWR = 1.0f / sqrtf(6144.0f);
    const long wsw = 3072L * 1024, wout = 5120L * 1024;

    auto stdscale = [&](const float* p, long n, float rs, int slot) {
        k_std_partial<<<256, TPB, 0, stream>>>(p, n, red);
        k_std_final<<<1, TPB, 0, stream>>>(red, (float)n, rs, scales + slot);
    };

    // one-time bf16 copy of w
    k_cast_bf16<<<(int)(((long)WR * Ec / 4) / TPB), TPB, 0, stream>>>(w_cur, wb, (long)WR * Ec / 4);

    for (int layer = 0; layer < 2; ++layer) {
        stdscale(w_cur,        3072L * 1024, rs32, 0);
        stdscale(w_cur + wsw,  2048L * 1024, rs32, 1);
        stdscale(w_cur + wout, 1024L * 1024, rs32, 2);
        k_rms1024b<<<BT, TPB, 0, stream>>>(xbuf, xbn, 1024, 1024);
        k_bgemm<2, 2, 0><<<dim3(24, 32, 1), TPB, 0, stream>>>(
            1024, xbn, 1024, 0, wb, 1024, 0, qkv, 3072, 0, 0, 1, scales + 0, 1.0f, nullptr, 0);
        k_rms1024<<<BT, TPB, 0, stream>>>(qkv, qkv, 3072, 3072);
        k_rms1024<<<BT, TPB, 0, stream>>>(qkv + 1024, qkv + 1024, 3072, 3072);
        k_aft_p1<<<(2048 * NCH) / TPB, TPB, 0, stream>>>(qkv, chw, chs);
        k_aft_p2<<<2048 / TPB, TPB, 0, stream>>>(chw, chs);
        k_aft_p3<<<(2048 * NCH) / TPB, TPB, 0, stream>>>(qkv, chw, chs, ybn);
        k_bgemm<2, 2, 0><<<dim3(16, 32, 1), TPB, 0, stream>>>(
            1024, ybn, 1024, 0, wb + wsw, 1024, 0, uv, 2048, 0, 0, 1, scales + 1, 1.0f, nullptr, 0);
        k_silu_gate<<<(int)((BT * 1024 / 4) / TPB), TPB, 0, stream>>>(uv, gbn, BT * 1024 / 4);
        k_rowrms<<<BT, TPB, 0, stream>>>(uv, 2048, uscale);
        k_tcast<float><<<dim3(16, 64, 1), TPB, 0, stream>>>(uv, 2048, 0, t1, 4096, 0, uscale);
        k_tcast<float><<<dim3(16, 64, 1), TPB, 0, stream>>>(uv + 1024, 2048, 0, t2, 4096, 0, nullptr);
        // oa = softmax(o^T @ a * E^-0.5), split-K x4 into w_tmp partials
        k_bgemm<2, 2, 0><<<dim3(8, 8, 4), TPB, 0, stream>>>(
            1024, t1, 4096, 0, t2, 4096, 0, w_tmp, 1024, 0, 1048576L, 4, nullptr, 1.0f, nullptr, 0);
        k_softmax4<<<1024, TPB, 0, stream>>>(w_tmp, oab, 0.03125f);
        k_tcast<float><<<dim3(16, 16, 1), TPB, 0, stream>>>(oab, 1024, 0, t3, 1024, 0, nullptr);
        k_bgemm<2, 2, 0><<<dim3(8, 32, 1), TPB, 0, stream>>>(
            1024, gbn, 1024, 0, wb + wout, 1024, 0, xbuf, 1024, 0, 0, 1, scales + 2, 1.0f, xbuf, 1024);
        k_bgemm<2, 2, 0><<<dim3(8, 48, 1), TPB, 0, stream>>>(
            1024, wb, 1024, 0, t3, 1024, 0, w_tmp, 1024, 0, 0, 1, nullptr, 1.0f, nullptr, 0);
        stdscale(w_tmp, (long)WR * 1024, rsWR, 3);
        k_wupdate<<<(int)(((long)WR * 1024 / 4) / TPB), TPB, 0, stream>>>(
            w_cur, w_tmp, scales + 3, wb, (long)WR * 1024 / 4);
    }

    // -------- final tea (no w_norm) --------
    k_rms1024b<<<BT, TPB, 0, stream>>>(xbuf, xbn, 1024, 1024);
    k_bgemm<2, 2, 0><<<dim3(24, 32, 1), TPB, 0, stream>>>(
        1024, xbn, 1024, 0, wb, 1024, 0, qkv, 3072, 0, 0, 1, nullptr, 1.0f, nullptr, 0);
    k_rot_split<<<BT, TPB, 0, stream>>>(qkv, cos_in, sin_in, t1, t2, t3);
    k_tcast<unsigned short><<<dim3(1, 32, 32), TPB, 0, stream>>>(
        t3, 64, (long)Tc * 64, t4, 2048, (long)Tc * 64, nullptr);
    // fused causal flash attention, 1 wave per block, XCD-swizzled
    k_flash<<<dim3(2048), 64, 0, stream>>>(t1, t2, t4, ybn);
    // final swiglu -> d_out
    k_bgemm<2, 2, 0><<<dim3(16, 32, 1), TPB, 0, stream>>>(
        1024, ybn, 1024, 0, wb + wsw, 1024, 0, uv, 2048, 0, 0, 1, nullptr, 1.0f, nullptr, 0);
    k_silu_gate<<<(int)((BT * 1024 / 4) / TPB), TPB, 0, stream>>>(uv, gbn, BT * 1024 / 4);
    k_bgemm<2, 2, 0><<<dim3(8, 32, 1), TPB, 0, stream>>>(
        1024, gbn, 1024, 0, wb + wout, 1024, 0, out, 1024, 0, 0, 1, nullptr, 1.0f, xbuf, 1024);
}

// Round 5
// 928.088 us; speedup vs baseline: 4.9926x; 1.0434x over previous
//
#include <hip/hip_runtime.h>
#include <hip/hip_bf16.h>
#include <math.h>

#define TPB 256

constexpr int Bc = 2, Tc = 2048, Ec = 1024, QKVc = 1024, Hc = 16, DHc = 64;
constexpr long BT = (long)Bc * Tc;     // 4096
constexpr int WR = 5 * QKVc + Ec;      // 6144
constexpr float F32_EPS = 1.1920928955078125e-07f;
constexpr int NCH = 32, CHL = Tc / NCH;

typedef __attribute__((ext_vector_type(8))) short short8;
typedef __attribute__((ext_vector_type(4))) float f32x4;

__device__ __forceinline__ unsigned short f2bu(float f) {
    union { __hip_bfloat16 h; unsigned short u; } c; c.h = __float2bfloat16(f); return c.u;
}
__device__ __forceinline__ float bu2f(unsigned short u) {
    union { __hip_bfloat16 h; unsigned short u; } c; c.u = u; return __bfloat162float(c.h);
}
__device__ __forceinline__ float ldval(const float* p) { return *p; }
__device__ __forceinline__ float ldval(const unsigned short* p) { return bu2f(*p); }

__device__ __forceinline__ void gload_lds16(const void* g, void* l) {
    __builtin_amdgcn_global_load_lds((const __attribute__((address_space(1))) void*)g,
                                     (__attribute__((address_space(3))) void*)l, 16, 0, 0);
}

// ---------------- global std (ddof=1) -> scale = rs/(std+1e-8) ----------------
__global__ void k_std_partial(const float* __restrict__ p, long n, float* __restrict__ out) {
    __shared__ float ls[TPB], lss[TPB];
    float s = 0.f, ss = 0.f;
    for (long i = (long)blockIdx.x * TPB + threadIdx.x; i < n; i += (long)gridDim.x * TPB) {
        float v = p[i]; s += v; ss += v * v;
    }
    ls[threadIdx.x] = s; lss[threadIdx.x] = ss; __syncthreads();
    for (int o = 128; o > 0; o >>= 1) {
        if (threadIdx.x < o) { ls[threadIdx.x] += ls[threadIdx.x + o]; lss[threadIdx.x] += lss[threadIdx.x + o]; }
        __syncthreads();
    }
    if (threadIdx.x == 0) { out[blockIdx.x] = ls[0]; out[gridDim.x + blockIdx.x] = lss[0]; }
}

__global__ void k_std_final(const float* __restrict__ part, float n, float rs, float* __restrict__ scale) {
    __shared__ float ls[TPB], lss[TPB];
    ls[threadIdx.x] = part[threadIdx.x];
    lss[threadIdx.x] = part[TPB + threadIdx.x];
    __syncthreads();
    for (int o = 128; o > 0; o >>= 1) {
        if (threadIdx.x < o) { ls[threadIdx.x] += ls[threadIdx.x + o]; lss[threadIdx.x] += lss[threadIdx.x + o]; }
        __syncthreads();
    }
    if (threadIdx.x == 0) {
        float var = (lss[0] - ls[0] * ls[0] / n) / (n - 1.0f);
        scale[0] = rs / (sqrtf(fmaxf(var, 0.0f)) + 1e-8f);
    }
}

// ---------------- rmsnorm over 1024 cols, fp32 out ----------------
__global__ void k_rms1024(const float* __restrict__ in, float* __restrict__ out, long ldin, long ldout) {
    __shared__ float red[TPB];
    long row = blockIdx.x;
    float4 v = *(const float4*)(in + row * ldin + threadIdx.x * 4);
    float ss = v.x * v.x + v.y * v.y + v.z * v.z + v.w * v.w;
    red[threadIdx.x] = ss; __syncthreads();
    for (int o = 128; o > 0; o >>= 1) {
        if (threadIdx.x < o) red[threadIdx.x] += red[threadIdx.x + o];
        __syncthreads();
    }
    float sc = rsqrtf(red[0] / 1024.0f + F32_EPS);
    float4 o4; o4.x = v.x * sc; o4.y = v.y * sc; o4.z = v.z * sc; o4.w = v.w * sc;
    *(float4*)(out + row * ldout + threadIdx.x * 4) = o4;
}

// ---------------- rmsnorm over 1024 cols, bf16 out ----------------
__global__ void k_rms1024b(const float* __restrict__ in, unsigned short* __restrict__ out, long ldin, long ldout) {
    __shared__ float red[TPB];
    long row = blockIdx.x;
    float4 v = *(const float4*)(in + row * ldin + threadIdx.x * 4);
    float ss = v.x * v.x + v.y * v.y + v.z * v.z + v.w * v.w;
    red[threadIdx.x] = ss; __syncthreads();
    for (int o = 128; o > 0; o >>= 1) {
        if (threadIdx.x < o) red[threadIdx.x] += red[threadIdx.x + o];
        __syncthreads();
    }
    float sc = rsqrtf(red[0] / 1024.0f + F32_EPS);
    ushort4 o4; o4.x = f2bu(v.x * sc); o4.y = f2bu(v.y * sc); o4.z = f2bu(v.z * sc); o4.w = f2bu(v.w * sc);
    *(ushort4*)(out + row * ldout + threadIdx.x * 4) = o4;
}

// ---------------- per-row rms scale (1024 cols) ----------------
__global__ void k_rowrms(const float* __restrict__ in, long ld, float* __restrict__ rs) {
    __shared__ float red[TPB];
    long row = blockIdx.x;
    float4 v = *(const float4*)(in + row * ld + threadIdx.x * 4);
    red[threadIdx.x] = v.x * v.x + v.y * v.y + v.z * v.z + v.w * v.w;
    __syncthreads();
    for (int o = 128; o > 0; o >>= 1) {
        if (threadIdx.x < o) red[threadIdx.x] += red[threadIdx.x + o];
        __syncthreads();
    }
    if (threadIdx.x == 0) rs[row] = rsqrtf(red[0] / 1024.0f + F32_EPS);
}

// ---------------- fp32 -> bf16 cast ----------------
__global__ void k_cast_bf16(const float* __restrict__ in, unsigned short* __restrict__ out, long n4) {
    long i = (long)blockIdx.x * TPB + threadIdx.x;
    if (i >= n4) return;
    float4 v = *(const float4*)(in + i * 4);
    ushort4 o; o.x = f2bu(v.x); o.y = f2bu(v.y); o.z = f2bu(v.z); o.w = f2bu(v.w);
    *(ushort4*)(out + i * 4) = o;
}

// ---------------- transpose-cast: in[R][C] (ld, opt rowscale) -> bf16 out[C][R] ----------------
template<typename TI>
__global__ void k_tcast(const TI* __restrict__ in, long ldi, long sIn,
                        unsigned short* __restrict__ out, long ldo, long sOut,
                        const float* __restrict__ rowscale) {
    __shared__ float tile[64][65];
    const TI* ip = in + (long)blockIdx.z * sIn;
    unsigned short* op = out + (long)blockIdx.z * sOut;
    int r0 = blockIdx.y * 64, c0 = blockIdx.x * 64;
    int tid = threadIdx.x;
    int rr = tid >> 4, cc = (tid & 15) * 4;
    #pragma unroll
    for (int u = 0; u < 4; ++u) {
        int r = rr + u * 16;
        float sc = rowscale ? rowscale[r0 + r] : 1.0f;
        #pragma unroll
        for (int j = 0; j < 4; ++j)
            tile[r][cc + j] = ldval(ip + (long)(r0 + r) * ldi + c0 + cc + j) * sc;
    }
    __syncthreads();
    #pragma unroll
    for (int u = 0; u < 4; ++u) {
        int c = rr + u * 16;
        ushort4 o;
        o.x = f2bu(tile[cc + 0][c]); o.y = f2bu(tile[cc + 1][c]);
        o.z = f2bu(tile[cc + 2][c]); o.w = f2bu(tile[cc + 3][c]);
        *(ushort4*)(op + (long)(c0 + c) * ldo + r0 + cc) = o;
    }
}

// ---------------- bf16 MFMA GEMM, NT: C[M,N] = s * A[M,K] @ B[N,K]^T (+add), opt split-K ----------------
template<int WGM, int WGN, int WRITE_BF16>
__global__ __launch_bounds__(256)
void k_bgemm(int K,
             const unsigned short* __restrict__ A, int lda, long sA,
             const unsigned short* __restrict__ B, int ldb, long sB,
             void* __restrict__ C, int ldc, long sCi, long sSplit, int nsplit,
             const float* __restrict__ scale_ptr, float fscale,
             const float* __restrict__ addp, int ldadd) {
    constexpr int TM = WGM * 64, TN = WGN * 64;
    __shared__ unsigned short Asl[TM * 32];
    __shared__ unsigned short Bsl[TN * 32];
    int bz = blockIdx.z;
    int batch = bz, sp = 0;
    if (nsplit > 1) { batch = bz / nsplit; sp = bz - batch * nsplit; }
    int m0 = blockIdx.y * TM, n0 = blockIdx.x * TN;
    const unsigned short* Ap = A + (long)batch * sA + (long)sp * K;
    const unsigned short* Bp = B + (long)batch * sB + (long)sp * K;
    int tid = threadIdx.x, lane = tid & 63, wave = tid >> 6;
    int wr = wave / WGN, wc = wave % WGN;
    f32x4 acc[4][4] = {};
    constexpr int CAW = TM / 64;
    constexpr int CBW = TN / 64;
    for (int k0 = 0; k0 < K; k0 += 32) {
        #pragma unroll
        for (int c = 0; c < CAW; ++c) {
            int bu = (wave * CAW + c) * 64;
            int uidx = bu + lane;
            int r = uidx >> 2, slot = uidx & 3;
            int gu = slot ^ ((r >> 1) & 3);
            gload_lds16(Ap + (long)(m0 + r) * lda + k0 + gu * 8, Asl + bu * 8);
        }
        #pragma unroll
        for (int c = 0; c < CBW; ++c) {
            int bu = (wave * CBW + c) * 64;
            int uidx = bu + lane;
            int r = uidx >> 2, slot = uidx & 3;
            int gu = slot ^ ((r >> 1) & 3);
            gload_lds16(Bp + (long)(n0 + r) * ldb + k0 + gu * 8, Bsl + bu * 8);
        }
        __syncthreads();
        short8 av[4], bv[4];
        #pragma unroll
        for (int m = 0; m < 4; ++m) {
            int r = wr * 64 + m * 16 + (lane & 15);
            int slot = (lane >> 4) ^ ((r >> 1) & 3);
            av[m] = *(const short8*)(Asl + r * 32 + slot * 8);
        }
        #pragma unroll
        for (int n = 0; n < 4; ++n) {
            int r = wc * 64 + n * 16 + (lane & 15);
            int slot = (lane >> 4) ^ ((r >> 1) & 3);
            bv[n] = *(const short8*)(Bsl + r * 32 + slot * 8);
        }
        #pragma unroll
        for (int m = 0; m < 4; ++m)
            #pragma unroll
            for (int n = 0; n < 4; ++n)
                acc[m][n] = __builtin_amdgcn_mfma_f32_16x16x32_bf16(av[m], bv[n], acc[m][n], 0, 0, 0);
        __syncthreads();
    }
    float s = fscale * (scale_ptr ? scale_ptr[0] : 1.0f);
    long cbase = (long)batch * sCi + (long)sp * sSplit;
    int row0 = m0 + wr * 64, col0 = n0 + wc * 64 + (lane & 15);
    int rbase = (lane >> 4) * 4;
    #pragma unroll
    for (int m = 0; m < 4; ++m)
        #pragma unroll
        for (int i = 0; i < 4; ++i) {
            long row = row0 + m * 16 + rbase + i;
            #pragma unroll
            for (int n = 0; n < 4; ++n) {
                long col = col0 + n * 16;
                float v = acc[m][n][i] * s;
                if (addp) v += addp[row * (long)ldadd + col];
                long idx = cbase + row * ldc + col;
                if (WRITE_BF16) ((unsigned short*)C)[idx] = f2bu(v);
                else ((float*)C)[idx] = v;
            }
        }
}

// ---------------- flash-decoding split: item = (bh, strip32, K-chunk of <=8 tiles) ----------------
// 160 items per bh (strips 0-15:1 chunk, 16-31:2, 32-47:3, 48-63:4), 5120 total.
// Writes unnormalized o partials (fp32) + running m,l per row.
__global__ __launch_bounds__(64)
void k_flash_split(const unsigned short* __restrict__ hq, const unsigned short* __restrict__ hk,
                   const unsigned short* __restrict__ hvT,
                   float* __restrict__ opart, float* __restrict__ mpart, float* __restrict__ lpart) {
    __shared__ unsigned short P[32 * 72];
    int lane = threadIdx.x;
    int g = lane >> 4, c = lane & 15;
    unsigned bid = blockIdx.x;
    unsigned swz = (bid & 7) * 640 + (bid >> 3);        // XCD-bijective: 4 bh per XCD
    unsigned bh = swz / 160, itr = swz % 160;
    int item = 159 - (int)itr;                           // longest chunks first
    int strip, chunk;
    if (item < 16)      { strip = item;                 chunk = 0; }
    else if (item < 48) { strip = 16 + (item - 16) / 2; chunk = (item - 16) & 1; }
    else if (item < 96) { strip = 32 + (item - 48) / 3; chunk = (item - 48) % 3; }
    else                { strip = 48 + (item - 96) / 4; chunk = (item - 96) & 3; }
    int q0 = strip * 32;
    int nt = (q0 + 32 + 63) >> 6;
    int ti0 = chunk * 8;
    int ti1 = ti0 + 8 < nt ? ti0 + 8 : nt;
    const unsigned short* qb = hq + (long)bh * Tc * 64;
    const unsigned short* kb = hk + (long)bh * Tc * 64;
    const unsigned short* vtb = hvT + (long)bh * 64 * Tc;

    short8 qf[2][2];
    #pragma unroll
    for (int mf = 0; mf < 2; ++mf)
        #pragma unroll
        for (int ks = 0; ks < 2; ++ks)
            qf[mf][ks] = *(const short8*)(qb + (long)(q0 + mf * 16 + c) * 64 + ks * 32 + g * 8);

    f32x4 o_acc[2][4] = {};
    float m_run[2][4], l_run[2][4];
    #pragma unroll
    for (int mf = 0; mf < 2; ++mf)
        #pragma unroll
        for (int i = 0; i < 4; ++i) { m_run[mf][i] = -3.0e38f; l_run[mf][i] = 0.f; }

    for (int ti = ti0; ti < ti1; ++ti) {
        int kt = ti * 64;
        f32x4 s_acc[2][4] = {};
        #pragma unroll
        for (int ks = 0; ks < 2; ++ks) {
            short8 kf[4];
            #pragma unroll
            for (int nf = 0; nf < 4; ++nf)
                kf[nf] = *(const short8*)(kb + (long)(kt + nf * 16 + c) * 64 + ks * 32 + g * 8);
            #pragma unroll
            for (int mf = 0; mf < 2; ++mf)
                #pragma unroll
                for (int nf = 0; nf < 4; ++nf)
                    s_acc[mf][nf] = __builtin_amdgcn_mfma_f32_16x16x32_bf16(qf[mf][ks], kf[nf], s_acc[mf][nf], 0, 0, 0);
        }
        bool diag = (kt + 64 > q0);
        #pragma unroll
        for (int mf = 0; mf < 2; ++mf) {
            float sv[4][4];
            float pm[4] = {-3.0e38f, -3.0e38f, -3.0e38f, -3.0e38f};
            #pragma unroll
            for (int nf = 0; nf < 4; ++nf)
                #pragma unroll
                for (int i = 0; i < 4; ++i) {
                    float v = s_acc[mf][nf][i] * 0.125f;
                    if (diag) {
                        int kg = kt + nf * 16 + c;
                        int qg = q0 + mf * 16 + g * 4 + i;
                        if (kg > qg) v = -3.0e38f;
                    }
                    sv[nf][i] = v;
                    pm[i] = fmaxf(pm[i], v);
                }
            #pragma unroll
            for (int i = 0; i < 4; ++i) {
                float t = pm[i];
                t = fmaxf(t, __shfl_xor(t, 1));
                t = fmaxf(t, __shfl_xor(t, 2));
                t = fmaxf(t, __shfl_xor(t, 4));
                t = fmaxf(t, __shfl_xor(t, 8));
                float mn = fmaxf(m_run[mf][i], t);
                float corr = __expf(m_run[mf][i] - mn);
                m_run[mf][i] = mn;
                float ls = 0.f;
                #pragma unroll
                for (int nf = 0; nf < 4; ++nf) {
                    float p = __expf(sv[nf][i] - mn);
                    unsigned short pb = f2bu(p);
                    P[(mf * 16 + g * 4 + i) * 72 + nf * 16 + c] = pb;
                    ls += bu2f(pb);
                }
                ls += __shfl_xor(ls, 1); ls += __shfl_xor(ls, 2);
                ls += __shfl_xor(ls, 4); ls += __shfl_xor(ls, 8);
                l_run[mf][i] = l_run[mf][i] * corr + ls;
                #pragma unroll
                for (int df = 0; df < 4; ++df) o_acc[mf][df][i] *= corr;
            }
        }
        #pragma unroll
        for (int ks = 0; ks < 2; ++ks) {
            short8 pa[2], vf[4];
            #pragma unroll
            for (int mf = 0; mf < 2; ++mf)
                pa[mf] = *(const short8*)(P + (mf * 16 + c) * 72 + ks * 32 + g * 8);
            #pragma unroll
            for (int df = 0; df < 4; ++df)
                vf[df] = *(const short8*)(vtb + (long)(df * 16 + c) * Tc + kt + ks * 32 + g * 8);
            #pragma unroll
            for (int mf = 0; mf < 2; ++mf)
                #pragma unroll
                for (int df = 0; df < 4; ++df)
                    o_acc[mf][df] = __builtin_amdgcn_mfma_f32_16x16x32_bf16(pa[mf], vf[df], o_acc[mf][df], 0, 0, 0);
        }
    }
    long pbase = (long)(bh * 160 + item);
    #pragma unroll
    for (int mf = 0; mf < 2; ++mf)
        #pragma unroll
        for (int i = 0; i < 4; ++i) {
            int row_l = mf * 16 + g * 4 + i;
            #pragma unroll
            for (int df = 0; df < 4; ++df)
                opart[pbase * 2048 + row_l * 64 + df * 16 + c] = o_acc[mf][df][i];
            if (c == 0) {
                mpart[pbase * 32 + row_l] = m_run[mf][i];
                lpart[pbase * 32 + row_l] = l_run[mf][i];
            }
        }
}

// ---------------- flash merge: combine <=4 partials per (bh,strip) -> bf16 y ----------------
__global__ __launch_bounds__(256)
void k_flash_merge(const float* __restrict__ opart, const float* __restrict__ mpart,
                   const float* __restrict__ lpart, unsigned short* __restrict__ yout) {
    int bs = blockIdx.x;
    int bh = bs >> 6, strip = bs & 63;
    int b = bh >> 4, h = bh & 15;
    int np, base;
    if (strip < 16)      { np = 1; base = strip; }
    else if (strip < 32) { np = 2; base = 16 + (strip - 16) * 2; }
    else if (strip < 48) { np = 3; base = 48 + (strip - 32) * 3; }
    else                 { np = 4; base = 96 + (strip - 48) * 4; }
    long p0 = (long)(bh * 160 + base);
    int tid = threadIdx.x;
    int r = tid >> 3, c0 = (tid & 7) * 8;
    float M = -3.0e38f;
    for (int p = 0; p < np; ++p) M = fmaxf(M, mpart[(p0 + p) * 32 + r]);
    float L = 0.f;
    float acc[8] = {};
    for (int p = 0; p < np; ++p) {
        float sc = __expf(mpart[(p0 + p) * 32 + r] - M);
        L += lpart[(p0 + p) * 32 + r] * sc;
        const float* op = opart + (p0 + p) * 2048 + r * 64 + c0;
        #pragma unroll
        for (int j = 0; j < 8; ++j) acc[j] += op[j] * sc;
    }
    float inv = 1.0f / L;
    long row = (long)b * Tc + strip * 32 + r;
    unsigned short* yp = yout + row * 1024 + h * 64 + c0;
    ushort4 o1, o2;
    o1.x = f2bu(acc[0] * inv); o1.y = f2bu(acc[1] * inv); o1.z = f2bu(acc[2] * inv); o1.w = f2bu(acc[3] * inv);
    o2.x = f2bu(acc[4] * inv); o2.y = f2bu(acc[5] * inv); o2.z = f2bu(acc[6] * inv); o2.w = f2bu(acc[7] * inv);
    *(ushort4*)yp = o1;
    *(ushort4*)(yp + 4) = o2;
}

// ---------------- AFT gated cumsum, 3-pass chunked ----------------
__global__ void k_aft_p1(const float* __restrict__ qkv, float* __restrict__ cw, float* __restrict__ cs) {
    int id = blockIdx.x * TPB + threadIdx.x;
    int bc = id & 2047, ch = id >> 11;
    int b = bc >> 10, c = bc & 1023;
    const float* base = qkv + ((long)(b * Tc + ch * CHL)) * 3072 + c;
    float sw = 0.f, sv = 0.f;
    for (int i = 0; i < CHL; ++i) {
        float k = base[1024], v = base[2048];
        float e = expf(k);
        sw += e; sv += e * v;
        base += 3072;
    }
    cw[ch * 2048 + bc] = sw; cs[ch * 2048 + bc] = sv;
}

__global__ void k_aft_p2(float* __restrict__ cw, float* __restrict__ cs) {
    int bc = blockIdx.x * TPB + threadIdx.x;
    float rw = 0.f, rv = 0.f;
    for (int ch = 0; ch < NCH; ++ch) {
        long idx = (long)ch * 2048 + bc;
        float tw = cw[idx], tv = cs[idx];
        cw[idx] = rw; cs[idx] = rv; rw += tw; rv += tv;
    }
}

__global__ void k_aft_p3(const float* __restrict__ qkv, const float* __restrict__ cw,
                         const float* __restrict__ cs, unsigned short* __restrict__ y) {
    int id = blockIdx.x * TPB + threadIdx.x;
    int bc = id & 2047, ch = id >> 11;
    int b = bc >> 10, c = bc & 1023;
    long t0 = (long)b * Tc + ch * CHL;
    const float* base = qkv + t0 * 3072 + c;
    unsigned short* yp = y + t0 * 1024 + c;
    float aw = cw[ch * 2048 + bc], av = cs[ch * 2048 + bc];
    for (int i = 0; i < CHL; ++i) {
        float q = base[0], k = base[1024], v = base[2048];
        float e = expf(k);
        av += e * v; aw += e;
        float sig = 1.0f / (1.0f + expf(-q));
        yp[0] = f2bu(sig * av / (aw + 1e-6f));
        base += 3072; yp += 1024;
    }
}

// ---------------- u * silu(v) -> bf16 ----------------
__global__ void k_silu_gate(const float* __restrict__ uv, unsigned short* __restrict__ g, long n4) {
    long i = (long)blockIdx.x * TPB + threadIdx.x;
    if (i >= n4) return;
    long r = i >> 8, c4 = i & 255;
    float4 u = *(const float4*)(uv + r * 2048 + c4 * 4);
    float4 v = *(const float4*)(uv + r * 2048 + 1024 + c4 * 4);
    ushort4 o;
    o.x = f2bu(u.x * v.x / (1.f + expf(-v.x)));
    o.y = f2bu(u.y * v.y / (1.f + expf(-v.y)));
    o.z = f2bu(u.z * v.z / (1.f + expf(-v.z)));
    o.w = f2bu(u.w * v.w / (1.f + expf(-v.w)));
    *(ushort4*)(g + r * 1024 + c4 * 4) = o;
}

// ---------------- w = wT*s*silu(w) + w  (also emits bf16 copy) ----------------
__global__ void k_wupdate(float* __restrict__ w, const float* __restrict__ p,
                          const float* __restrict__ scale, unsigned short* __restrict__ wb, long n4) {
    long i = (long)blockIdx.x * TPB + threadIdx.x;
    if (i >= n4) return;
    float s = scale[0];
    float4 wv = *(const float4*)(w + i * 4);
    float4 pv = *(const float4*)(p + i * 4);
    float4 o;
    o.x = pv.x * s * (wv.x / (1.f + expf(-wv.x))) + wv.x;
    o.y = pv.y * s * (wv.y / (1.f + expf(-wv.y))) + wv.y;
    o.z = pv.z * s * (wv.z / (1.f + expf(-wv.z))) + wv.z;
    o.w = pv.w * s * (wv.w / (1.f + expf(-wv.w))) + wv.w;
    *(float4*)(w + i * 4) = o;
    ushort4 ob; ob.x = f2bu(o.x); ob.y = f2bu(o.y); ob.z = f2bu(o.z); ob.w = f2bu(o.w);
    *(ushort4*)(wb + i * 4) = ob;
}

// ---------------- 4-slab reduce + scale + row softmax -> fp32 out ----------------
__global__ void k_softmax4(const float* __restrict__ parts, float* __restrict__ outb, float fscale) {
    __shared__ float red[TPB];
    __shared__ float rowbuf[1024];
    long row = blockIdx.x;
    const float* p0 = parts + row * 1024;
    for (int c = threadIdx.x; c < 1024; c += TPB) {
        float v = p0[c] + p0[c + 1048576] + p0[c + 2097152] + p0[c + 3145728];
        rowbuf[c] = v * fscale;
    }
    __syncthreads();
    float m = -3.0e38f;
    for (int c = threadIdx.x; c < 1024; c += TPB) m = fmaxf(m, rowbuf[c]);
    red[threadIdx.x] = m; __syncthreads();
    for (int o = 128; o > 0; o >>= 1) {
        if (threadIdx.x < o) red[threadIdx.x] = fmaxf(red[threadIdx.x], red[threadIdx.x + o]);
        __syncthreads();
    }
    m = red[0]; __syncthreads();
    float sum = 0.f;
    for (int c = threadIdx.x; c < 1024; c += TPB) sum += expf(rowbuf[c] - m);
    red[threadIdx.x] = sum; __syncthreads();
    for (int o = 128; o > 0; o >>= 1) {
        if (threadIdx.x < o) red[threadIdx.x] += red[threadIdx.x + o];
        __syncthreads();
    }
    float inv = 1.0f / red[0];
    for (int c = threadIdx.x; c < 1024; c += TPB)
        outb[row * 1024 + c] = expf(rowbuf[c] - m) * inv;
}

// ---------------- tea: rotary + per-head rmsnorm + split, bf16 out ----------------
__global__ void k_rot_split(const float* __restrict__ qkvp, const float* __restrict__ cosp,
                            const float* __restrict__ sinp, unsigned short* __restrict__ hq,
                            unsigned short* __restrict__ hk, unsigned short* __restrict__ hv) {
    __shared__ float row[3072];
    __shared__ float cs[32], sn[32];
    int bt = blockIdx.x;
    int b = bt >> 11, t = bt & 2047;
    const float* src = qkvp + (long)bt * 3072;
    #pragma unroll
    for (int u = 0; u < 3; ++u) {
        int idx = threadIdx.x + u * 256;
        *(float4*)&row[idx * 4] = *(const float4*)(src + idx * 4);
    }
    if (threadIdx.x < 32) { cs[threadIdx.x] = cosp[t * 32 + threadIdx.x]; sn[threadIdx.x] = sinp[t * 32 + threadIdx.x]; }
    __syncthreads();
    int h = threadIdx.x >> 4, li = threadIdx.x & 15;
    int base = h * 192;
    long obase = ((long)(b * Hc + h) * Tc + t) * 64 + li * 4;
    {
        float r[4]; float ss = 0.f;
        #pragma unroll
        for (int j = 0; j < 4; ++j) {
            int d = li * 4 + j;
            float val = (d < 32) ? (row[base + d] * cs[d] + row[base + d + 32] * sn[d])
                                 : (-row[base + d - 32] * sn[d - 32] + row[base + d] * cs[d - 32]);
            r[j] = val; ss += val * val;
        }
        ss += __shfl_xor(ss, 1); ss += __shfl_xor(ss, 2); ss += __shfl_xor(ss, 4); ss += __shfl_xor(ss, 8);
        float sc = rsqrtf(ss / 64.0f + F32_EPS);
        ushort4 o; o.x = f2bu(r[0] * sc); o.y = f2bu(r[1] * sc); o.z = f2bu(r[2] * sc); o.w = f2bu(r[3] * sc);
        *(ushort4*)(hq + obase) = o;
    }
    {
        int kb = base + 64;
        float r[4]; float ss = 0.f;
        #pragma unroll
        for (int j = 0; j < 4; ++j) {
            int d = li * 4 + j;
            float val = (d < 32) ? (row[kb + d] * cs[d] + row[kb + d + 32] * sn[d])
                                 : (-row[kb + d - 32] * sn[d - 32] + row[kb + d] * cs[d - 32]);
            r[j] = val; ss += val * val;
        }
        ss += __shfl_xor(ss, 1); ss += __shfl_xor(ss, 2); ss += __shfl_xor(ss, 4); ss += __shfl_xor(ss, 8);
        float sc = rsqrtf(ss / 64.0f + F32_EPS);
        ushort4 o; o.x = f2bu(r[0] * sc); o.y = f2bu(r[1] * sc); o.z = f2bu(r[2] * sc); o.w = f2bu(r[3] * sc);
        *(ushort4*)(hk + obase) = o;
    }
    {
        ushort4 o;
        o.x = f2bu(row[base + 128 + li * 4 + 0]); o.y = f2bu(row[base + 128 + li * 4 + 1]);
        o.z = f2bu(row[base + 128 + li * 4 + 2]); o.w = f2bu(row[base + 128 + li * 4 + 3]);
        *(ushort4*)(hv + obase) = o;
    }
}

extern "C" void kernel_launch(void* const* d_in, const int* in_sizes, int n_in,
                              void* d_out, int out_size, void* d_ws, size_t ws_size,
                              hipStream_t stream) {
    const float* x_in = (const float*)d_in[0];
    const float* w_in = (const float*)d_in[1];
    const float* cos_in = (const float*)d_in[2];
    const float* sin_in = (const float*)d_in[3];
    float* out = (float*)d_out;
    float* ws = (float*)d_ws;

    long off = 0;
    float* w_cur = ws + off;  off += (long)WR * Ec;
    float* w_tmp = ws + off;  off += (long)WR * Ec;   // also: oa split-K partials (4M floats)
    float* xbuf  = ws + off;  off += BT * Ec;
    float* qkv   = ws + off;  off += BT * 3L * QKVc;  // also: uv fp32 | flash o-partials (10.5M)
    float* oab   = ws + off;  off += (long)Ec * Ec;   // also: flash m/l partials (327K)
    float* red   = ws + off;  off += 1024;
    float* scales= ws + off;  off += 16;
    float* uscale= ws + off;  off += 4096;
    float* chw   = ws + off;  off += 2048L * NCH;
    float* chs   = ws + off;  off += 2048L * NCH;
    float* uv    = qkv;
    float* opart = qkv;
    float* mpart = oab;
    float* lpart = oab + 5120L * 32;

    unsigned short* bp = (unsigned short*)(ws + off);
    long bo = 0;
    unsigned short* wb  = bp + bo; bo += (long)WR * Ec;
    unsigned short* xbn = bp + bo; bo += BT * Ec;
    unsigned short* ybn = bp + bo; bo += BT * Ec;
    unsigned short* gbn = bp + bo; bo += BT * Ec;
    unsigned short* t1  = bp + bo; bo += BT * Ec;            // o^T | hq
    unsigned short* t2  = bp + bo; bo += BT * Ec;            // v^T | hk
    unsigned short* t3  = bp + bo; bo += BT * Ec;            // oa^T | hvS
    unsigned short* t4  = bp + bo; bo += BT * Ec;            // hvT

    hipMemcpyAsync(w_cur, w_in, (size_t)WR * Ec * 4, hipMemcpyDeviceToDevice, stream);
    hipMemcpyAsync(xbuf, x_in, (size_t)BT * Ec * 4, hipMemcpyDeviceToDevice, stream);

    const float rs32 = 0.03125f;
    const float rsWR = 1.0f / sqrtf(6144.0f);
    const long wsw = 3072L * 1024, wout = 5120L * 1024;

    auto stdscale = [&](const float* p, long n, float rs, int slot) {
        k_std_partial<<<256, TPB, 0, stream>>>(p, n, red);
        k_std_final<<<1, TPB, 0, stream>>>(red, (float)n, rs, scales + slot);
    };

    // one-time bf16 copy of w
    k_cast_bf16<<<(int)(((long)WR * Ec / 4) / TPB), TPB, 0, stream>>>(w_cur, wb, (long)WR * Ec / 4);

    for (int layer = 0; layer < 2; ++layer) {
        stdscale(w_cur,        3072L * 1024, rs32, 0);
        stdscale(w_cur + wsw,  2048L * 1024, rs32, 1);
        stdscale(w_cur + wout, 1024L * 1024, rs32, 2);
        k_rms1024b<<<BT, TPB, 0, stream>>>(xbuf, xbn, 1024, 1024);
        k_bgemm<2, 2, 0><<<dim3(24, 32, 1), TPB, 0, stream>>>(
            1024, xbn, 1024, 0, wb, 1024, 0, qkv, 3072, 0, 0, 1, scales + 0, 1.0f, nullptr, 0);
        k_rms1024<<<BT, TPB, 0, stream>>>(qkv, qkv, 3072, 3072);
        k_rms1024<<<BT, TPB, 0, stream>>>(qkv + 1024, qkv + 1024, 3072, 3072);
        k_aft_p1<<<(2048 * NCH) / TPB, TPB, 0, stream>>>(qkv, chw, chs);
        k_aft_p2<<<2048 / TPB, TPB, 0, stream>>>(chw, chs);
        k_aft_p3<<<(2048 * NCH) / TPB, TPB, 0, stream>>>(qkv, chw, chs, ybn);
        k_bgemm<2, 2, 0><<<dim3(16, 32, 1), TPB, 0, stream>>>(
            1024, ybn, 1024, 0, wb + wsw, 1024, 0, uv, 2048, 0, 0, 1, scales + 1, 1.0f, nullptr, 0);
        k_silu_gate<<<(int)((BT * 1024 / 4) / TPB), TPB, 0, stream>>>(uv, gbn, BT * 1024 / 4);
        k_rowrms<<<BT, TPB, 0, stream>>>(uv, 2048, uscale);
        k_tcast<float><<<dim3(16, 64, 1), TPB, 0, stream>>>(uv, 2048, 0, t1, 4096, 0, uscale);
        k_tcast<float><<<dim3(16, 64, 1), TPB, 0, stream>>>(uv + 1024, 2048, 0, t2, 4096, 0, nullptr);
        // oa = softmax(o^T @ a * E^-0.5), split-K x4 into w_tmp partials
        k_bgemm<2, 2, 0><<<dim3(8, 8, 4), TPB, 0, stream>>>(
            1024, t1, 4096, 0, t2, 4096, 0, w_tmp, 1024, 0, 1048576L, 4, nullptr, 1.0f, nullptr, 0);
        k_softmax4<<<1024, TPB, 0, stream>>>(w_tmp, oab, 0.03125f);
        k_tcast<float><<<dim3(16, 16, 1), TPB, 0, stream>>>(oab, 1024, 0, t3, 1024, 0, nullptr);
        k_bgemm<2, 2, 0><<<dim3(8, 32, 1), TPB, 0, stream>>>(
            1024, gbn, 1024, 0, wb + wout, 1024, 0, xbuf, 1024, 0, 0, 1, scales + 2, 1.0f, xbuf, 1024);
        k_bgemm<2, 2, 0><<<dim3(8, 48, 1), TPB, 0, stream>>>(
            1024, wb, 1024, 0, t3, 1024, 0, w_tmp, 1024, 0, 0, 1, nullptr, 1.0f, nullptr, 0);
        stdscale(w_tmp, (long)WR * 1024, rsWR, 3);
        k_wupdate<<<(int)(((long)WR * 1024 / 4) / TPB), TPB, 0, stream>>>(
            w_cur, w_tmp, scales + 3, wb, (long)WR * 1024 / 4);
    }

    // -------- final tea (no w_norm) --------
    k_rms1024b<<<BT, TPB, 0, stream>>>(xbuf, xbn, 1024, 1024);
    k_bgemm<2, 2, 0><<<dim3(24, 32, 1), TPB, 0, stream>>>(
        1024, xbn, 1024, 0, wb, 1024, 0, qkv, 3072, 0, 0, 1, nullptr, 1.0f, nullptr, 0);
    k_rot_split<<<BT, TPB, 0, stream>>>(qkv, cos_in, sin_in, t1, t2, t3);
    k_tcast<unsigned short><<<dim3(1, 32, 32), TPB, 0, stream>>>(
        t3, 64, (long)Tc * 64, t4, 2048, (long)Tc * 64, nullptr);
    // flash-decoding: 5120 split items, then merge (qkv region is dead -> partials)
    k_flash_split<<<dim3(5120), 64, 0, stream>>>(t1, t2, t4, opart, mpart, lpart);
    k_flash_merge<<<dim3(2048), TPB, 0, stream>>>(opart, mpart, lpart, ybn);
    // final swiglu -> d_out
    k_bgemm<2, 2, 0><<<dim3(16, 32, 1), TPB, 0, stream>>>(
        1024, ybn, 1024, 0, wb + wsw, 1024, 0, uv, 2048, 0, 0, 1, nullptr, 1.0f, nullptr, 0);
    k_silu_gate<<<(int)((BT * 1024 / 4) / TPB), TPB, 0, stream>>>(uv, gbn, BT * 1024 / 4);
    k_bgemm<2, 2, 0><<<dim3(8, 32, 1), TPB, 0, stream>>>(
        1024, gbn, 1024, 0, wb + wout, 1024, 0, out, 1024, 0, 0, 1, nullptr, 1.0f, xbuf, 1024);
}

// Round 6
// 879.676 us; speedup vs baseline: 5.2674x; 1.0550x over previous
//
#include <hip/hip_runtime.h>
#include <hip/hip_bf16.h>
#include <math.h>

#define TPB 256

constexpr int Bc = 2, Tc = 2048, Ec = 1024, QKVc = 1024, Hc = 16, DHc = 64;
constexpr long BT = (long)Bc * Tc;     // 4096
constexpr int WR = 5 * QKVc + Ec;      // 6144
constexpr float F32_EPS = 1.1920928955078125e-07f;
constexpr int NCH = 32, CHL = Tc / NCH;

typedef __attribute__((ext_vector_type(8))) short short8;
typedef __attribute__((ext_vector_type(4))) float f32x4;

__device__ __forceinline__ unsigned short f2bu(float f) {
    union { __hip_bfloat16 h; unsigned short u; } c; c.h = __float2bfloat16(f); return c.u;
}
__device__ __forceinline__ float bu2f(unsigned short u) {
    union { __hip_bfloat16 h; unsigned short u; } c; c.u = u; return __bfloat162float(c.h);
}
__device__ __forceinline__ float ldval(const float* p) { return *p; }
__device__ __forceinline__ float ldval(const unsigned short* p) { return bu2f(*p); }

__device__ __forceinline__ void gload_lds16(const void* g, void* l) {
    __builtin_amdgcn_global_load_lds((const __attribute__((address_space(1))) void*)g,
                                     (__attribute__((address_space(3))) void*)l, 16, 0, 0);
}

// ---------------- fused 3-segment global std (ddof=1) for w_qkv/w_sw/w_out ----------------
__global__ void k_std_partial3(const float* __restrict__ w, float* __restrict__ out) {
    __shared__ float ls[TPB], lss[TPB];
    int seg = blockIdx.y;
    long base = (seg == 0) ? 0L : (seg == 1 ? 3072L * 1024 : 5120L * 1024);
    long n    = (seg == 0) ? 3072L * 1024 : (seg == 1 ? 2048L * 1024 : 1024L * 1024);
    const float* p = w + base;
    float s = 0.f, ss = 0.f;
    for (long i = (long)blockIdx.x * TPB + threadIdx.x; i < n; i += 256L * TPB) {
        float v = p[i]; s += v; ss += v * v;
    }
    ls[threadIdx.x] = s; lss[threadIdx.x] = ss; __syncthreads();
    for (int o = 128; o > 0; o >>= 1) {
        if (threadIdx.x < o) { ls[threadIdx.x] += ls[threadIdx.x + o]; lss[threadIdx.x] += lss[threadIdx.x + o]; }
        __syncthreads();
    }
    if (threadIdx.x == 0) { out[seg * 512 + blockIdx.x] = ls[0]; out[seg * 512 + 256 + blockIdx.x] = lss[0]; }
}

__global__ void k_std_final3(const float* __restrict__ part, float* __restrict__ scales) {
    __shared__ float ls[TPB], lss[TPB];
    for (int seg = 0; seg < 3; ++seg) {
        ls[threadIdx.x] = part[seg * 512 + threadIdx.x];
        lss[threadIdx.x] = part[seg * 512 + 256 + threadIdx.x];
        __syncthreads();
        for (int o = 128; o > 0; o >>= 1) {
            if (threadIdx.x < o) { ls[threadIdx.x] += ls[threadIdx.x + o]; lss[threadIdx.x] += lss[threadIdx.x + o]; }
            __syncthreads();
        }
        if (threadIdx.x == 0) {
            float n = (seg == 0) ? 3145728.0f : (seg == 1 ? 2097152.0f : 1048576.0f);
            float var = (lss[0] - ls[0] * ls[0] / n) / (n - 1.0f);
            scales[seg] = 0.03125f / (sqrtf(fmaxf(var, 0.0f)) + 1e-8f);
        }
        __syncthreads();
    }
}

// ---------------- generic global std (for w_tmp) ----------------
__global__ void k_std_partial(const float* __restrict__ p, long n, float* __restrict__ out) {
    __shared__ float ls[TPB], lss[TPB];
    float s = 0.f, ss = 0.f;
    for (long i = (long)blockIdx.x * TPB + threadIdx.x; i < n; i += (long)gridDim.x * TPB) {
        float v = p[i]; s += v; ss += v * v;
    }
    ls[threadIdx.x] = s; lss[threadIdx.x] = ss; __syncthreads();
    for (int o = 128; o > 0; o >>= 1) {
        if (threadIdx.x < o) { ls[threadIdx.x] += ls[threadIdx.x + o]; lss[threadIdx.x] += lss[threadIdx.x + o]; }
        __syncthreads();
    }
    if (threadIdx.x == 0) { out[blockIdx.x] = ls[0]; out[gridDim.x + blockIdx.x] = lss[0]; }
}

__global__ void k_std_final(const float* __restrict__ part, float n, float rs, float* __restrict__ scale) {
    __shared__ float ls[TPB], lss[TPB];
    ls[threadIdx.x] = part[threadIdx.x];
    lss[threadIdx.x] = part[TPB + threadIdx.x];
    __syncthreads();
    for (int o = 128; o > 0; o >>= 1) {
        if (threadIdx.x < o) { ls[threadIdx.x] += ls[threadIdx.x + o]; lss[threadIdx.x] += lss[threadIdx.x + o]; }
        __syncthreads();
    }
    if (threadIdx.x == 0) {
        float var = (lss[0] - ls[0] * ls[0] / n) / (n - 1.0f);
        scale[0] = rs / (sqrtf(fmaxf(var, 0.0f)) + 1e-8f);
    }
}

// ---------------- rmsnorm over 1024 cols, fp32 out ----------------
__global__ void k_rms1024(const float* __restrict__ in, float* __restrict__ out, long ldin, long ldout) {
    __shared__ float red[TPB];
    long row = blockIdx.x;
    float4 v = *(const float4*)(in + row * ldin + threadIdx.x * 4);
    float ss = v.x * v.x + v.y * v.y + v.z * v.z + v.w * v.w;
    red[threadIdx.x] = ss; __syncthreads();
    for (int o = 128; o > 0; o >>= 1) {
        if (threadIdx.x < o) red[threadIdx.x] += red[threadIdx.x + o];
        __syncthreads();
    }
    float sc = rsqrtf(red[0] / 1024.0f + F32_EPS);
    float4 o4; o4.x = v.x * sc; o4.y = v.y * sc; o4.z = v.z * sc; o4.w = v.w * sc;
    *(float4*)(out + row * ldout + threadIdx.x * 4) = o4;
}

// ---------------- in-place rmsnorm of q and k halves of qkv (grid 8192) ----------------
__global__ void k_rms_qk(float* __restrict__ qkv) {
    __shared__ float red[TPB];
    int bid = blockIdx.x;
    long row = bid >> 1; int half = bid & 1;
    float* p = qkv + row * 3072 + half * 1024;
    float4 v = *(const float4*)(p + threadIdx.x * 4);
    float ss = v.x * v.x + v.y * v.y + v.z * v.z + v.w * v.w;
    red[threadIdx.x] = ss; __syncthreads();
    for (int o = 128; o > 0; o >>= 1) {
        if (threadIdx.x < o) red[threadIdx.x] += red[threadIdx.x + o];
        __syncthreads();
    }
    float sc = rsqrtf(red[0] / 1024.0f + F32_EPS);
    float4 o4; o4.x = v.x * sc; o4.y = v.y * sc; o4.z = v.z * sc; o4.w = v.w * sc;
    *(float4*)(p + threadIdx.x * 4) = o4;
}

// ---------------- rmsnorm over 1024 cols, bf16 out ----------------
__global__ void k_rms1024b(const float* __restrict__ in, unsigned short* __restrict__ out, long ldin, long ldout) {
    __shared__ float red[TPB];
    long row = blockIdx.x;
    float4 v = *(const float4*)(in + row * ldin + threadIdx.x * 4);
    float ss = v.x * v.x + v.y * v.y + v.z * v.z + v.w * v.w;
    red[threadIdx.x] = ss; __syncthreads();
    for (int o = 128; o > 0; o >>= 1) {
        if (threadIdx.x < o) red[threadIdx.x] += red[threadIdx.x + o];
        __syncthreads();
    }
    float sc = rsqrtf(red[0] / 1024.0f + F32_EPS);
    ushort4 o4; o4.x = f2bu(v.x * sc); o4.y = f2bu(v.y * sc); o4.z = f2bu(v.z * sc); o4.w = f2bu(v.w * sc);
    *(ushort4*)(out + row * ldout + threadIdx.x * 4) = o4;
}

// ---------------- fp32 -> bf16 cast ----------------
__global__ void k_cast_bf16(const float* __restrict__ in, unsigned short* __restrict__ out, long n4) {
    long i = (long)blockIdx.x * TPB + threadIdx.x;
    if (i >= n4) return;
    float4 v = *(const float4*)(in + i * 4);
    ushort4 o; o.x = f2bu(v.x); o.y = f2bu(v.y); o.z = f2bu(v.z); o.w = f2bu(v.w);
    *(ushort4*)(out + i * 4) = o;
}

// ---------------- transpose-cast: in[R][C] (ld, opt rowscale) -> bf16 out[C][R] ----------------
template<typename TI>
__global__ void k_tcast(const TI* __restrict__ in, long ldi, long sIn,
                        unsigned short* __restrict__ out, long ldo, long sOut,
                        const float* __restrict__ rowscale) {
    __shared__ float tile[64][65];
    const TI* ip = in + (long)blockIdx.z * sIn;
    unsigned short* op = out + (long)blockIdx.z * sOut;
    int r0 = blockIdx.y * 64, c0 = blockIdx.x * 64;
    int tid = threadIdx.x;
    int rr = tid >> 4, cc = (tid & 15) * 4;
    #pragma unroll
    for (int u = 0; u < 4; ++u) {
        int r = rr + u * 16;
        float sc = rowscale ? rowscale[r0 + r] : 1.0f;
        #pragma unroll
        for (int j = 0; j < 4; ++j)
            tile[r][cc + j] = ldval(ip + (long)(r0 + r) * ldi + c0 + cc + j) * sc;
    }
    __syncthreads();
    #pragma unroll
    for (int u = 0; u < 4; ++u) {
        int c = rr + u * 16;
        ushort4 o;
        o.x = f2bu(tile[cc + 0][c]); o.y = f2bu(tile[cc + 1][c]);
        o.z = f2bu(tile[cc + 2][c]); o.w = f2bu(tile[cc + 3][c]);
        *(ushort4*)(op + (long)(c0 + c) * ldo + r0 + cc) = o;
    }
}

// ---------------- fused transpose of o (rowscaled) and a from packed uv ----------------
__global__ void k_tcast2(const float* __restrict__ uv, const float* __restrict__ uscale,
                         unsigned short* __restrict__ t1, unsigned short* __restrict__ t2) {
    __shared__ float tile[64][65];
    int z = blockIdx.z;
    const float* ip = uv + (z ? 1024 : 0);
    unsigned short* op = z ? t2 : t1;
    int r0 = blockIdx.y * 64, c0 = blockIdx.x * 64;
    int tid = threadIdx.x;
    int rr = tid >> 4, cc = (tid & 15) * 4;
    #pragma unroll
    for (int u = 0; u < 4; ++u) {
        int r = rr + u * 16;
        float sc = z ? 1.0f : uscale[r0 + r];
        #pragma unroll
        for (int j = 0; j < 4; ++j)
            tile[r][cc + j] = ip[(long)(r0 + r) * 2048 + c0 + cc + j] * sc;
    }
    __syncthreads();
    #pragma unroll
    for (int u = 0; u < 4; ++u) {
        int c = rr + u * 16;
        ushort4 o;
        o.x = f2bu(tile[cc + 0][c]); o.y = f2bu(tile[cc + 1][c]);
        o.z = f2bu(tile[cc + 2][c]); o.w = f2bu(tile[cc + 3][c]);
        *(ushort4*)(op + (long)(c0 + c) * 4096 + r0 + cc) = o;
    }
}

// ---------------- bf16 MFMA GEMM, NT: C[M,N] = s * A[M,K] @ B[N,K]^T (+add), opt split-K ----------------
template<int WGM, int WGN, int WRITE_BF16>
__global__ __launch_bounds__(256)
void k_bgemm(int K,
             const unsigned short* __restrict__ A, int lda, long sA,
             const unsigned short* __restrict__ B, int ldb, long sB,
             void* __restrict__ C, int ldc, long sCi, long sSplit, int nsplit,
             const float* __restrict__ scale_ptr, float fscale,
             const float* __restrict__ addp, int ldadd) {
    constexpr int TM = WGM * 64, TN = WGN * 64;
    __shared__ unsigned short Asl[TM * 32];
    __shared__ unsigned short Bsl[TN * 32];
    int bz = blockIdx.z;
    int batch = bz, sp = 0;
    if (nsplit > 1) { batch = bz / nsplit; sp = bz - batch * nsplit; }
    int m0 = blockIdx.y * TM, n0 = blockIdx.x * TN;
    const unsigned short* Ap = A + (long)batch * sA + (long)sp * K;
    const unsigned short* Bp = B + (long)batch * sB + (long)sp * K;
    int tid = threadIdx.x, lane = tid & 63, wave = tid >> 6;
    int wr = wave / WGN, wc = wave % WGN;
    f32x4 acc[4][4] = {};
    constexpr int CAW = TM / 64;
    constexpr int CBW = TN / 64;
    for (int k0 = 0; k0 < K; k0 += 32) {
        #pragma unroll
        for (int c = 0; c < CAW; ++c) {
            int bu = (wave * CAW + c) * 64;
            int uidx = bu + lane;
            int r = uidx >> 2, slot = uidx & 3;
            int gu = slot ^ ((r >> 1) & 3);
            gload_lds16(Ap + (long)(m0 + r) * lda + k0 + gu * 8, Asl + bu * 8);
        }
        #pragma unroll
        for (int c = 0; c < CBW; ++c) {
            int bu = (wave * CBW + c) * 64;
            int uidx = bu + lane;
            int r = uidx >> 2, slot = uidx & 3;
            int gu = slot ^ ((r >> 1) & 3);
            gload_lds16(Bp + (long)(n0 + r) * ldb + k0 + gu * 8, Bsl + bu * 8);
        }
        __syncthreads();
        short8 av[4], bv[4];
        #pragma unroll
        for (int m = 0; m < 4; ++m) {
            int r = wr * 64 + m * 16 + (lane & 15);
            int slot = (lane >> 4) ^ ((r >> 1) & 3);
            av[m] = *(const short8*)(Asl + r * 32 + slot * 8);
        }
        #pragma unroll
        for (int n = 0; n < 4; ++n) {
            int r = wc * 64 + n * 16 + (lane & 15);
            int slot = (lane >> 4) ^ ((r >> 1) & 3);
            bv[n] = *(const short8*)(Bsl + r * 32 + slot * 8);
        }
        #pragma unroll
        for (int m = 0; m < 4; ++m)
            #pragma unroll
            for (int n = 0; n < 4; ++n)
                acc[m][n] = __builtin_amdgcn_mfma_f32_16x16x32_bf16(av[m], bv[n], acc[m][n], 0, 0, 0);
        __syncthreads();
    }
    float s = fscale * (scale_ptr ? scale_ptr[0] : 1.0f);
    long cbase = (long)batch * sCi + (long)sp * sSplit;
    int row0 = m0 + wr * 64, col0 = n0 + wc * 64 + (lane & 15);
    int rbase = (lane >> 4) * 4;
    #pragma unroll
    for (int m = 0; m < 4; ++m)
        #pragma unroll
        for (int i = 0; i < 4; ++i) {
            long row = row0 + m * 16 + rbase + i;
            #pragma unroll
            for (int n = 0; n < 4; ++n) {
                long col = col0 + n * 16;
                float v = acc[m][n][i] * s;
                if (addp) v += addp[row * (long)ldadd + col];
                long idx = cbase + row * ldc + col;
                if (WRITE_BF16) ((unsigned short*)C)[idx] = f2bu(v);
                else ((float*)C)[idx] = v;
            }
        }
}

// ---------------- flash-decoding split with pipelined softmax ----------------
// item = (bh, strip32, K-chunk of <=8 tiles); 160 items/bh, 5120 waves.
__global__ __launch_bounds__(64)
void k_flash_split(const unsigned short* __restrict__ hq, const unsigned short* __restrict__ hk,
                   const unsigned short* __restrict__ hvT,
                   float* __restrict__ opart, float* __restrict__ mpart, float* __restrict__ lpart) {
    __shared__ unsigned short P[32 * 72];
    int lane = threadIdx.x;
    int g = lane >> 4, c = lane & 15;
    unsigned bid = blockIdx.x;
    unsigned swz = (bid & 7) * 640 + (bid >> 3);        // XCD-bijective: 4 bh per XCD
    unsigned bh = swz / 160, itr = swz % 160;
    int item = 159 - (int)itr;                           // longest chunks first
    int strip, chunk;
    if (item < 16)      { strip = item;                 chunk = 0; }
    else if (item < 48) { strip = 16 + (item - 16) / 2; chunk = (item - 16) & 1; }
    else if (item < 96) { strip = 32 + (item - 48) / 3; chunk = (item - 48) % 3; }
    else                { strip = 48 + (item - 96) / 4; chunk = (item - 96) & 3; }
    int q0 = strip * 32;
    int nt = (q0 + 32 + 63) >> 6;
    int ti0 = chunk * 8;
    int ti1 = ti0 + 8 < nt ? ti0 + 8 : nt;
    const unsigned short* qb = hq + (long)bh * Tc * 64;
    const unsigned short* kb = hk + (long)bh * Tc * 64;
    const unsigned short* vtb = hvT + (long)bh * 64 * Tc;

    short8 qf[2][2];
    #pragma unroll
    for (int mf = 0; mf < 2; ++mf)
        #pragma unroll
        for (int ks = 0; ks < 2; ++ks)
            qf[mf][ks] = *(const short8*)(qb + (long)(q0 + mf * 16 + c) * 64 + ks * 32 + g * 8);

    f32x4 o_acc[2][4] = {};
    float m_run[2][4], l_run[2][4];
    #pragma unroll
    for (int mf = 0; mf < 2; ++mf)
        #pragma unroll
        for (int i = 0; i < 4; ++i) { m_run[mf][i] = -3.0e38f; l_run[mf][i] = 0.f; }

    for (int ti = ti0; ti < ti1; ++ti) {
        int kt = ti * 64;
        // issue V loads early: latency hides under QK^T + softmax
        short8 vf[2][4];
        #pragma unroll
        for (int ks = 0; ks < 2; ++ks)
            #pragma unroll
            for (int df = 0; df < 4; ++df)
                vf[ks][df] = *(const short8*)(vtb + (long)(df * 16 + c) * Tc + kt + ks * 32 + g * 8);
        f32x4 s_acc[2][4] = {};
        #pragma unroll
        for (int ks = 0; ks < 2; ++ks) {
            short8 kf[4];
            #pragma unroll
            for (int nf = 0; nf < 4; ++nf)
                kf[nf] = *(const short8*)(kb + (long)(kt + nf * 16 + c) * 64 + ks * 32 + g * 8);
            #pragma unroll
            for (int mf = 0; mf < 2; ++mf)
                #pragma unroll
                for (int nf = 0; nf < 4; ++nf)
                    s_acc[mf][nf] = __builtin_amdgcn_mfma_f32_16x16x32_bf16(qf[mf][ks], kf[nf], s_acc[mf][nf], 0, 0, 0);
        }
        bool diag = (kt + 64 > q0);
        // scale + causal mask in place
        #pragma unroll
        for (int mf = 0; mf < 2; ++mf)
            #pragma unroll
            for (int nf = 0; nf < 4; ++nf)
                #pragma unroll
                for (int i = 0; i < 4; ++i) {
                    float v = s_acc[mf][nf][i] * 0.125f;
                    if (diag && (kt + nf * 16 + c) > (q0 + mf * 16 + g * 4 + i)) v = -3.0e38f;
                    s_acc[mf][nf][i] = v;
                }
        // in-register max over nf, then level-hoisted shfl trees (8 independent chains/level)
        float pm[2][4];
        #pragma unroll
        for (int mf = 0; mf < 2; ++mf)
            #pragma unroll
            for (int i = 0; i < 4; ++i)
                pm[mf][i] = fmaxf(fmaxf(s_acc[mf][0][i], s_acc[mf][1][i]),
                                  fmaxf(s_acc[mf][2][i], s_acc[mf][3][i]));
        #pragma unroll
        for (int lvl = 1; lvl <= 8; lvl <<= 1)
            #pragma unroll
            for (int mf = 0; mf < 2; ++mf)
                #pragma unroll
                for (int i = 0; i < 4; ++i)
                    pm[mf][i] = fmaxf(pm[mf][i], __shfl_xor(pm[mf][i], lvl));
        float corr[2][4], ls[2][4];
        #pragma unroll
        for (int mf = 0; mf < 2; ++mf)
            #pragma unroll
            for (int i = 0; i < 4; ++i) {
                float mn = fmaxf(m_run[mf][i], pm[mf][i]);
                corr[mf][i] = __expf(m_run[mf][i] - mn);
                m_run[mf][i] = mn;
                ls[mf][i] = 0.f;
            }
        // independent exps + P stores
        #pragma unroll
        for (int mf = 0; mf < 2; ++mf)
            #pragma unroll
            for (int nf = 0; nf < 4; ++nf)
                #pragma unroll
                for (int i = 0; i < 4; ++i) {
                    float p = __expf(s_acc[mf][nf][i] - m_run[mf][i]);
                    unsigned short pb = f2bu(p);
                    P[(mf * 16 + g * 4 + i) * 72 + nf * 16 + c] = pb;
                    ls[mf][i] += bu2f(pb);
                }
        #pragma unroll
        for (int lvl = 1; lvl <= 8; lvl <<= 1)
            #pragma unroll
            for (int mf = 0; mf < 2; ++mf)
                #pragma unroll
                for (int i = 0; i < 4; ++i)
                    ls[mf][i] += __shfl_xor(ls[mf][i], lvl);
        #pragma unroll
        for (int mf = 0; mf < 2; ++mf)
            #pragma unroll
            for (int i = 0; i < 4; ++i) {
                l_run[mf][i] = l_run[mf][i] * corr[mf][i] + ls[mf][i];
                #pragma unroll
                for (int df = 0; df < 4; ++df) o_acc[mf][df][i] *= corr[mf][i];
            }
        // PV
        #pragma unroll
        for (int ks = 0; ks < 2; ++ks) {
            short8 pa[2];
            #pragma unroll
            for (int mf = 0; mf < 2; ++mf)
                pa[mf] = *(const short8*)(P + (mf * 16 + c) * 72 + ks * 32 + g * 8);
            #pragma unroll
            for (int mf = 0; mf < 2; ++mf)
                #pragma unroll
                for (int df = 0; df < 4; ++df)
                    o_acc[mf][df] = __builtin_amdgcn_mfma_f32_16x16x32_bf16(pa[mf], vf[ks][df], o_acc[mf][df], 0, 0, 0);
        }
    }
    long pbase = (long)(bh * 160 + item);
    #pragma unroll
    for (int mf = 0; mf < 2; ++mf)
        #pragma unroll
        for (int i = 0; i < 4; ++i) {
            int row_l = mf * 16 + g * 4 + i;
            #pragma unroll
            for (int df = 0; df < 4; ++df)
                opart[pbase * 2048 + row_l * 64 + df * 16 + c] = o_acc[mf][df][i];
            if (c == 0) {
                mpart[pbase * 32 + row_l] = m_run[mf][i];
                lpart[pbase * 32 + row_l] = l_run[mf][i];
            }
        }
}

// ---------------- flash merge: combine <=4 partials per (bh,strip) -> bf16 y ----------------
__global__ __launch_bounds__(256)
void k_flash_merge(const float* __restrict__ opart, const float* __restrict__ mpart,
                   const float* __restrict__ lpart, unsigned short* __restrict__ yout) {
    int bs = blockIdx.x;
    int bh = bs >> 6, strip = bs & 63;
    int b = bh >> 4, h = bh & 15;
    int np, base;
    if (strip < 16)      { np = 1; base = strip; }
    else if (strip < 32) { np = 2; base = 16 + (strip - 16) * 2; }
    else if (strip < 48) { np = 3; base = 48 + (strip - 32) * 3; }
    else                 { np = 4; base = 96 + (strip - 48) * 4; }
    long p0 = (long)(bh * 160 + base);
    int tid = threadIdx.x;
    int r = tid >> 3, c0 = (tid & 7) * 8;
    float M = -3.0e38f;
    for (int p = 0; p < np; ++p) M = fmaxf(M, mpart[(p0 + p) * 32 + r]);
    float L = 0.f;
    float acc[8] = {};
    for (int p = 0; p < np; ++p) {
        float sc = __expf(mpart[(p0 + p) * 32 + r] - M);
        L += lpart[(p0 + p) * 32 + r] * sc;
        const float* op = opart + (p0 + p) * 2048 + r * 64 + c0;
        #pragma unroll
        for (int j = 0; j < 8; ++j) acc[j] += op[j] * sc;
    }
    float inv = 1.0f / L;
    long row = (long)b * Tc + strip * 32 + r;
    unsigned short* yp = yout + row * 1024 + h * 64 + c0;
    ushort4 o1, o2;
    o1.x = f2bu(acc[0] * inv); o1.y = f2bu(acc[1] * inv); o1.z = f2bu(acc[2] * inv); o1.w = f2bu(acc[3] * inv);
    o2.x = f2bu(acc[4] * inv); o2.y = f2bu(acc[5] * inv); o2.z = f2bu(acc[6] * inv); o2.w = f2bu(acc[7] * inv);
    *(ushort4*)yp = o1;
    *(ushort4*)(yp + 4) = o2;
}

// ---------------- AFT gated cumsum: chunk totals, then p3 with inline prefix ----------------
__global__ void k_aft_p1(const float* __restrict__ qkv, float* __restrict__ cw, float* __restrict__ cs) {
    int id = blockIdx.x * TPB + threadIdx.x;
    int bc = id & 2047, ch = id >> 11;
    int b = bc >> 10, c = bc & 1023;
    const float* base = qkv + ((long)(b * Tc + ch * CHL)) * 3072 + c;
    float sw = 0.f, sv = 0.f;
    for (int i = 0; i < CHL; ++i) {
        float k = base[1024], v = base[2048];
        float e = __expf(k);
        sw += e; sv += e * v;
        base += 3072;
    }
    cw[ch * 2048 + bc] = sw; cs[ch * 2048 + bc] = sv;
}

__global__ void k_aft_p3(const float* __restrict__ qkv, const float* __restrict__ cw,
                         const float* __restrict__ cs, unsigned short* __restrict__ y) {
    int id = blockIdx.x * TPB + threadIdx.x;
    int bc = id & 2047, ch = id >> 11;
    int b = bc >> 10, c = bc & 1023;
    float aw = 0.f, av = 0.f;
    for (int cc = 0; cc < ch; ++cc) { aw += cw[cc * 2048 + bc]; av += cs[cc * 2048 + bc]; }
    long t0 = (long)b * Tc + ch * CHL;
    const float* base = qkv + t0 * 3072 + c;
    unsigned short* yp = y + t0 * 1024 + c;
    for (int i = 0; i < CHL; ++i) {
        float q = base[0], k = base[1024], v = base[2048];
        float e = __expf(k);
        av += e * v; aw += e;
        float sig = 1.0f / (1.0f + __expf(-q));
        yp[0] = f2bu(sig * av / (aw + 1e-6f));
        base += 3072; yp += 1024;
    }
}

// ---------------- fused u*silu(v) -> bf16 + rowrms(u) (block per row) ----------------
__global__ void k_silu_rms(const float* __restrict__ uv, unsigned short* __restrict__ g,
                           float* __restrict__ rs) {
    __shared__ float red[TPB];
    long row = blockIdx.x;
    const float* up = uv + row * 2048;
    float4 u = *(const float4*)(up + threadIdx.x * 4);
    float4 v = *(const float4*)(up + 1024 + threadIdx.x * 4);
    ushort4 o;
    o.x = f2bu(u.x * v.x / (1.f + __expf(-v.x)));
    o.y = f2bu(u.y * v.y / (1.f + __expf(-v.y)));
    o.z = f2bu(u.z * v.z / (1.f + __expf(-v.z)));
    o.w = f2bu(u.w * v.w / (1.f + __expf(-v.w)));
    *(ushort4*)(g + row * 1024 + threadIdx.x * 4) = o;
    red[threadIdx.x] = u.x * u.x + u.y * u.y + u.z * u.z + u.w * u.w;
    __syncthreads();
    for (int off = 128; off > 0; off >>= 1) {
        if (threadIdx.x < off) red[threadIdx.x] += red[threadIdx.x + off];
        __syncthreads();
    }
    if (threadIdx.x == 0) rs[row] = rsqrtf(red[0] / 1024.0f + F32_EPS);
}

// ---------------- u * silu(v) -> bf16 (final swiglu, no rms needed) ----------------
__global__ void k_silu_gate(const float* __restrict__ uv, unsigned short* __restrict__ g, long n4) {
    long i = (long)blockIdx.x * TPB + threadIdx.x;
    if (i >= n4) return;
    long r = i >> 8, c4 = i & 255;
    float4 u = *(const float4*)(uv + r * 2048 + c4 * 4);
    float4 v = *(const float4*)(uv + r * 2048 + 1024 + c4 * 4);
    ushort4 o;
    o.x = f2bu(u.x * v.x / (1.f + __expf(-v.x)));
    o.y = f2bu(u.y * v.y / (1.f + __expf(-v.y)));
    o.z = f2bu(u.z * v.z / (1.f + __expf(-v.z)));
    o.w = f2bu(u.w * v.w / (1.f + __expf(-v.w)));
    *(ushort4*)(g + r * 1024 + c4 * 4) = o;
}

// ---------------- w = wT*s*silu(w) + w  (also emits bf16 copy) ----------------
__global__ void k_wupdate(float* __restrict__ w, const float* __restrict__ p,
                          const float* __restrict__ scale, unsigned short* __restrict__ wb, long n4) {
    long i = (long)blockIdx.x * TPB + threadIdx.x;
    if (i >= n4) return;
    float s = scale[0];
    float4 wv = *(const float4*)(w + i * 4);
    float4 pv = *(const float4*)(p + i * 4);
    float4 o;
    o.x = pv.x * s * (wv.x / (1.f + __expf(-wv.x))) + wv.x;
    o.y = pv.y * s * (wv.y / (1.f + __expf(-wv.y))) + wv.y;
    o.z = pv.z * s * (wv.z / (1.f + __expf(-wv.z))) + wv.z;
    o.w = pv.w * s * (wv.w / (1.f + __expf(-wv.w))) + wv.w;
    *(float4*)(w + i * 4) = o;
    ushort4 ob; ob.x = f2bu(o.x); ob.y = f2bu(o.y); ob.z = f2bu(o.z); ob.w = f2bu(o.w);
    *(ushort4*)(wb + i * 4) = ob;
}

// ---------------- 4-slab reduce + scale + row softmax -> fp32 out ----------------
__global__ void k_softmax4(const float* __restrict__ parts, float* __restrict__ outb, float fscale) {
    __shared__ float red[TPB];
    __shared__ float rowbuf[1024];
    long row = blockIdx.x;
    const float* p0 = parts + row * 1024;
    for (int c = threadIdx.x; c < 1024; c += TPB) {
        float v = p0[c] + p0[c + 1048576] + p0[c + 2097152] + p0[c + 3145728];
        rowbuf[c] = v * fscale;
    }
    __syncthreads();
    float m = -3.0e38f;
    for (int c = threadIdx.x; c < 1024; c += TPB) m = fmaxf(m, rowbuf[c]);
    red[threadIdx.x] = m; __syncthreads();
    for (int o = 128; o > 0; o >>= 1) {
        if (threadIdx.x < o) red[threadIdx.x] = fmaxf(red[threadIdx.x], red[threadIdx.x + o]);
        __syncthreads();
    }
    m = red[0]; __syncthreads();
    float sum = 0.f;
    for (int c = threadIdx.x; c < 1024; c += TPB) sum += __expf(rowbuf[c] - m);
    red[threadIdx.x] = sum; __syncthreads();
    for (int o = 128; o > 0; o >>= 1) {
        if (threadIdx.x < o) red[threadIdx.x] += red[threadIdx.x + o];
        __syncthreads();
    }
    float inv = 1.0f / red[0];
    for (int c = threadIdx.x; c < 1024; c += TPB)
        outb[row * 1024 + c] = __expf(rowbuf[c] - m) * inv;
}

// ---------------- tea: rotary + per-head rmsnorm + split, bf16 out ----------------
__global__ void k_rot_split(const float* __restrict__ qkvp, const float* __restrict__ cosp,
                            const float* __restrict__ sinp, unsigned short* __restrict__ hq,
                            unsigned short* __restrict__ hk, unsigned short* __restrict__ hv) {
    __shared__ float row[3072];
    __shared__ float cs[32], sn[32];
    int bt = blockIdx.x;
    int b = bt >> 11, t = bt & 2047;
    const float* src = qkvp + (long)bt * 3072;
    #pragma unroll
    for (int u = 0; u < 3; ++u) {
        int idx = threadIdx.x + u * 256;
        *(float4*)&row[idx * 4] = *(const float4*)(src + idx * 4);
    }
    if (threadIdx.x < 32) { cs[threadIdx.x] = cosp[t * 32 + threadIdx.x]; sn[threadIdx.x] = sinp[t * 32 + threadIdx.x]; }
    __syncthreads();
    int h = threadIdx.x >> 4, li = threadIdx.x & 15;
    int base = h * 192;
    long obase = ((long)(b * Hc + h) * Tc + t) * 64 + li * 4;
    {
        float r[4]; float ss = 0.f;
        #pragma unroll
        for (int j = 0; j < 4; ++j) {
            int d = li * 4 + j;
            float val = (d < 32) ? (row[base + d] * cs[d] + row[base + d + 32] * sn[d])
                                 : (-row[base + d - 32] * sn[d - 32] + row[base + d] * cs[d - 32]);
            r[j] = val; ss += val * val;
        }
        ss += __shfl_xor(ss, 1); ss += __shfl_xor(ss, 2); ss += __shfl_xor(ss, 4); ss += __shfl_xor(ss, 8);
        float sc = rsqrtf(ss / 64.0f + F32_EPS);
        ushort4 o; o.x = f2bu(r[0] * sc); o.y = f2bu(r[1] * sc); o.z = f2bu(r[2] * sc); o.w = f2bu(r[3] * sc);
        *(ushort4*)(hq + obase) = o;
    }
    {
        int kb = base + 64;
        float r[4]; float ss = 0.f;
        #pragma unroll
        for (int j = 0; j < 4; ++j) {
            int d = li * 4 + j;
            float val = (d < 32) ? (row[kb + d] * cs[d] + row[kb + d + 32] * sn[d])
                                 : (-row[kb + d - 32] * sn[d - 32] + row[kb + d] * cs[d - 32]);
            r[j] = val; ss += val * val;
        }
        ss += __shfl_xor(ss, 1); ss += __shfl_xor(ss, 2); ss += __shfl_xor(ss, 4); ss += __shfl_xor(ss, 8);
        float sc = rsqrtf(ss / 64.0f + F32_EPS);
        ushort4 o; o.x = f2bu(r[0] * sc); o.y = f2bu(r[1] * sc); o.z = f2bu(r[2] * sc); o.w = f2bu(r[3] * sc);
        *(ushort4*)(hk + obase) = o;
    }
    {
        ushort4 o;
        o.x = f2bu(row[base + 128 + li * 4 + 0]); o.y = f2bu(row[base + 128 + li * 4 + 1]);
        o.z = f2bu(row[base + 128 + li * 4 + 2]); o.w = f2bu(row[base + 128 + li * 4 + 3]);
        *(ushort4*)(hv + obase) = o;
    }
}

extern "C" void kernel_launch(void* const* d_in, const int* in_sizes, int n_in,
                              void* d_out, int out_size, void* d_ws, size_t ws_size,
                              hipStream_t stream) {
    const float* x_in = (const float*)d_in[0];
    const float* w_in = (const float*)d_in[1];
    const float* cos_in = (const float*)d_in[2];
    const float* sin_in = (const float*)d_in[3];
    float* out = (float*)d_out;
    float* ws = (float*)d_ws;

    long off = 0;
    float* w_cur = ws + off;  off += (long)WR * Ec;
    float* w_tmp = ws + off;  off += (long)WR * Ec;   // also: oa split-K partials (4M floats)
    float* xbuf  = ws + off;  off += BT * Ec;
    float* qkv   = ws + off;  off += BT * 3L * QKVc;  // also: uv fp32 | flash o-partials (10.5M)
    float* oab   = ws + off;  off += (long)Ec * Ec;   // also: flash m/l partials (327K)
    float* red   = ws + off;  off += 2048;
    float* scales= ws + off;  off += 16;
    float* uscale= ws + off;  off += 4096;
    float* chw   = ws + off;  off += 2048L * NCH;
    float* chs   = ws + off;  off += 2048L * NCH;
    float* uv    = qkv;
    float* opart = qkv;
    float* mpart = oab;
    float* lpart = oab + 5120L * 32;

    unsigned short* bp = (unsigned short*)(ws + off);
    long bo = 0;
    unsigned short* wb  = bp + bo; bo += (long)WR * Ec;
    unsigned short* xbn = bp + bo; bo += BT * Ec;
    unsigned short* ybn = bp + bo; bo += BT * Ec;
    unsigned short* gbn = bp + bo; bo += BT * Ec;
    unsigned short* t1  = bp + bo; bo += BT * Ec;            // o^T | hq
    unsigned short* t2  = bp + bo; bo += BT * Ec;            // v^T | hk
    unsigned short* t3  = bp + bo; bo += BT * Ec;            // oa^T | hvS
    unsigned short* t4  = bp + bo; bo += BT * Ec;            // hvT

    hipMemcpyAsync(w_cur, w_in, (size_t)WR * Ec * 4, hipMemcpyDeviceToDevice, stream);
    hipMemcpyAsync(xbuf, x_in, (size_t)BT * Ec * 4, hipMemcpyDeviceToDevice, stream);

    const float rsWR = 1.0f / sqrtf(6144.0f);
    const long wsw = 3072L * 1024, wout = 5120L * 1024;

    // one-time bf16 copy of w
    k_cast_bf16<<<(int)(((long)WR * Ec / 4) / TPB), TPB, 0, stream>>>(w_cur, wb, (long)WR * Ec / 4);

    for (int layer = 0; layer < 2; ++layer) {
        k_std_partial3<<<dim3(256, 3), TPB, 0, stream>>>(w_cur, red);
        k_std_final3<<<1, TPB, 0, stream>>>(red, scales);
        k_rms1024b<<<BT, TPB, 0, stream>>>(xbuf, xbn, 1024, 1024);
        k_bgemm<2, 2, 0><<<dim3(24, 32, 1), TPB, 0, stream>>>(
            1024, xbn, 1024, 0, wb, 1024, 0, qkv, 3072, 0, 0, 1, scales + 0, 1.0f, nullptr, 0);
        k_rms_qk<<<8192, TPB, 0, stream>>>(qkv);
        k_aft_p1<<<(2048 * NCH) / TPB, TPB, 0, stream>>>(qkv, chw, chs);
        k_aft_p3<<<(2048 * NCH) / TPB, TPB, 0, stream>>>(qkv, chw, chs, ybn);
        k_bgemm<2, 2, 0><<<dim3(16, 32, 1), TPB, 0, stream>>>(
            1024, ybn, 1024, 0, wb + wsw, 1024, 0, uv, 2048, 0, 0, 1, scales + 1, 1.0f, nullptr, 0);
        k_silu_rms<<<BT, TPB, 0, stream>>>(uv, gbn, uscale);
        k_tcast2<<<dim3(16, 64, 2), TPB, 0, stream>>>(uv, uscale, t1, t2);
        // oa = softmax(o^T @ a * E^-0.5), split-K x4 into w_tmp partials
        k_bgemm<2, 2, 0><<<dim3(8, 8, 4), TPB, 0, stream>>>(
            1024, t1, 4096, 0, t2, 4096, 0, w_tmp, 1024, 0, 1048576L, 4, nullptr, 1.0f, nullptr, 0);
        k_softmax4<<<1024, TPB, 0, stream>>>(w_tmp, oab, 0.03125f);
        k_tcast<float><<<dim3(16, 16, 1), TPB, 0, stream>>>(oab, 1024, 0, t3, 1024, 0, nullptr);
        k_bgemm<2, 2, 0><<<dim3(8, 32, 1), TPB, 0, stream>>>(
            1024, gbn, 1024, 0, wb + wout, 1024, 0, xbuf, 1024, 0, 0, 1, scales + 2, 1.0f, xbuf, 1024);
        k_bgemm<2, 2, 0><<<dim3(8, 48, 1), TPB, 0, stream>>>(
            1024, wb, 1024, 0, t3, 1024, 0, w_tmp, 1024, 0, 0, 1, nullptr, 1.0f, nullptr, 0);
        k_std_partial<<<256, TPB, 0, stream>>>(w_tmp, (long)WR * 1024, red);
        k_std_final<<<1, TPB, 0, stream>>>(red, (float)((long)WR * 1024), rsWR, scales + 3);
        k_wupdate<<<(int)(((long)WR * 1024 / 4) / TPB), TPB, 0, stream>>>(
            w_cur, w_tmp, scales + 3, wb, (long)WR * 1024 / 4);
    }

    // -------- final tea (no w_norm) --------
    k_rms1024b<<<BT, TPB, 0, stream>>>(xbuf, xbn, 1024, 1024);
    k_bgemm<2, 2, 0><<<dim3(24, 32, 1), TPB, 0, stream>>>(
        1024, xbn, 1024, 0, wb, 1024, 0, qkv, 3072, 0, 0, 1, nullptr, 1.0f, nullptr, 0);
    k_rot_split<<<BT, TPB, 0, stream>>>(qkv, cos_in, sin_in, t1, t2, t3);
    k_tcast<unsigned short><<<dim3(1, 32, 32), TPB, 0, stream>>>(
        t3, 64, (long)Tc * 64, t4, 2048, (long)Tc * 64, nullptr);
    // flash-decoding: 5120 split items, then merge (qkv region is dead -> partials)
    k_flash_split<<<dim3(5120), 64, 0, stream>>>(t1, t2, t4, opart, mpart, lpart);
    k_flash_merge<<<dim3(2048), TPB, 0, stream>>>(opart, mpart, lpart, ybn);
    // final swiglu -> d_out
    k_bgemm<2, 2, 0><<<dim3(16, 32, 1), TPB, 0, stream>>>(
        1024, ybn, 1024, 0, wb + wsw, 1024, 0, uv, 2048, 0, 0, 1, nullptr, 1.0f, nullptr, 0);
    k_silu_gate<<<(int)((BT * 1024 / 4) / TPB), TPB, 0, stream>>>(uv, gbn, BT * 1024 / 4);
    k_bgemm<2, 2, 0><<<dim3(8, 32, 1), TPB, 0, stream>>>(
        1024, gbn, 1024, 0, wb + wout, 1024, 0, out, 1024, 0, 0, 1, nullptr, 1.0f, xbuf, 1024);
}

// Round 7
// 866.424 us; speedup vs baseline: 5.3480x; 1.0153x over previous
//
#include <hip/hip_runtime.h>
#include <hip/hip_bf16.h>
#include <math.h>

#define TPB 256

constexpr int Bc = 2, Tc = 2048, Ec = 1024, QKVc = 1024, Hc = 16, DHc = 64;
constexpr long BT = (long)Bc * Tc;     // 4096
constexpr int WR = 5 * QKVc + Ec;      // 6144
constexpr float F32_EPS = 1.1920928955078125e-07f;
constexpr int NCH = 64, CHL = Tc / NCH;

typedef __attribute__((ext_vector_type(8))) short short8;
typedef __attribute__((ext_vector_type(4))) float f32x4;

__device__ __forceinline__ unsigned short f2bu(float f) {
    union { __hip_bfloat16 h; unsigned short u; } c; c.h = __float2bfloat16(f); return c.u;
}
__device__ __forceinline__ float bu2f(unsigned short u) {
    union { __hip_bfloat16 h; unsigned short u; } c; c.u = u; return __bfloat162float(c.h);
}
__device__ __forceinline__ float ldval(const float* p) { return *p; }
__device__ __forceinline__ float ldval(const unsigned short* p) { return bu2f(*p); }

__device__ __forceinline__ void gload_lds16(const void* g, void* l) {
    __builtin_amdgcn_global_load_lds((const __attribute__((address_space(1))) void*)g,
                                     (__attribute__((address_space(3))) void*)l, 16, 0, 0);
}

// ---------------- fused 3-segment global std (ddof=1) for w_qkv/w_sw/w_out ----------------
__global__ void k_std_partial3(const float* __restrict__ w, float* __restrict__ out) {
    __shared__ float ls[TPB], lss[TPB];
    int seg = blockIdx.y;
    long base = (seg == 0) ? 0L : (seg == 1 ? 3072L * 1024 : 5120L * 1024);
    long n    = (seg == 0) ? 3072L * 1024 : (seg == 1 ? 2048L * 1024 : 1024L * 1024);
    const float* p = w + base;
    float s = 0.f, ss = 0.f;
    for (long i = (long)blockIdx.x * TPB + threadIdx.x; i < n; i += 256L * TPB) {
        float v = p[i]; s += v; ss += v * v;
    }
    ls[threadIdx.x] = s; lss[threadIdx.x] = ss; __syncthreads();
    for (int o = 128; o > 0; o >>= 1) {
        if (threadIdx.x < o) { ls[threadIdx.x] += ls[threadIdx.x + o]; lss[threadIdx.x] += lss[threadIdx.x + o]; }
        __syncthreads();
    }
    if (threadIdx.x == 0) { out[seg * 512 + blockIdx.x] = ls[0]; out[seg * 512 + 256 + blockIdx.x] = lss[0]; }
}

__global__ void k_std_final3(const float* __restrict__ part, float* __restrict__ scales) {
    __shared__ float ls[TPB], lss[TPB];
    for (int seg = 0; seg < 3; ++seg) {
        ls[threadIdx.x] = part[seg * 512 + threadIdx.x];
        lss[threadIdx.x] = part[seg * 512 + 256 + threadIdx.x];
        __syncthreads();
        for (int o = 128; o > 0; o >>= 1) {
            if (threadIdx.x < o) { ls[threadIdx.x] += ls[threadIdx.x + o]; lss[threadIdx.x] += lss[threadIdx.x + o]; }
            __syncthreads();
        }
        if (threadIdx.x == 0) {
            float n = (seg == 0) ? 3145728.0f : (seg == 1 ? 2097152.0f : 1048576.0f);
            float var = (lss[0] - ls[0] * ls[0] / n) / (n - 1.0f);
            scales[seg] = 0.03125f / (sqrtf(fmaxf(var, 0.0f)) + 1e-8f);
        }
        __syncthreads();
    }
}

// ---------------- generic global std (for w_tmp) ----------------
__global__ void k_std_partial(const float* __restrict__ p, long n, float* __restrict__ out) {
    __shared__ float ls[TPB], lss[TPB];
    float s = 0.f, ss = 0.f;
    for (long i = (long)blockIdx.x * TPB + threadIdx.x; i < n; i += (long)gridDim.x * TPB) {
        float v = p[i]; s += v; ss += v * v;
    }
    ls[threadIdx.x] = s; lss[threadIdx.x] = ss; __syncthreads();
    for (int o = 128; o > 0; o >>= 1) {
        if (threadIdx.x < o) { ls[threadIdx.x] += ls[threadIdx.x + o]; lss[threadIdx.x] += lss[threadIdx.x + o]; }
        __syncthreads();
    }
    if (threadIdx.x == 0) { out[blockIdx.x] = ls[0]; out[gridDim.x + blockIdx.x] = lss[0]; }
}

__global__ void k_std_final(const float* __restrict__ part, float n, float rs, float* __restrict__ scale) {
    __shared__ float ls[TPB], lss[TPB];
    ls[threadIdx.x] = part[threadIdx.x];
    lss[threadIdx.x] = part[TPB + threadIdx.x];
    __syncthreads();
    for (int o = 128; o > 0; o >>= 1) {
        if (threadIdx.x < o) { ls[threadIdx.x] += ls[threadIdx.x + o]; lss[threadIdx.x] += lss[threadIdx.x + o]; }
        __syncthreads();
    }
    if (threadIdx.x == 0) {
        float var = (lss[0] - ls[0] * ls[0] / n) / (n - 1.0f);
        scale[0] = rs / (sqrtf(fmaxf(var, 0.0f)) + 1e-8f);
    }
}

// ---------------- in-place rmsnorm of q and k halves of qkv (grid 8192) ----------------
__global__ void k_rms_qk(float* __restrict__ qkv) {
    __shared__ float red[TPB];
    int bid = blockIdx.x;
    long row = bid >> 1; int half = bid & 1;
    float* p = qkv + row * 3072 + half * 1024;
    float4 v = *(const float4*)(p + threadIdx.x * 4);
    float ss = v.x * v.x + v.y * v.y + v.z * v.z + v.w * v.w;
    red[threadIdx.x] = ss; __syncthreads();
    for (int o = 128; o > 0; o >>= 1) {
        if (threadIdx.x < o) red[threadIdx.x] += red[threadIdx.x + o];
        __syncthreads();
    }
    float sc = rsqrtf(red[0] / 1024.0f + F32_EPS);
    float4 o4; o4.x = v.x * sc; o4.y = v.y * sc; o4.z = v.z * sc; o4.w = v.w * sc;
    *(float4*)(p + threadIdx.x * 4) = o4;
}

// ---------------- rmsnorm over 1024 cols, bf16 out ----------------
__global__ void k_rms1024b(const float* __restrict__ in, unsigned short* __restrict__ out, long ldin, long ldout) {
    __shared__ float red[TPB];
    long row = blockIdx.x;
    float4 v = *(const float4*)(in + row * ldin + threadIdx.x * 4);
    float ss = v.x * v.x + v.y * v.y + v.z * v.z + v.w * v.w;
    red[threadIdx.x] = ss; __syncthreads();
    for (int o = 128; o > 0; o >>= 1) {
        if (threadIdx.x < o) red[threadIdx.x] += red[threadIdx.x + o];
        __syncthreads();
    }
    float sc = rsqrtf(red[0] / 1024.0f + F32_EPS);
    ushort4 o4; o4.x = f2bu(v.x * sc); o4.y = f2bu(v.y * sc); o4.z = f2bu(v.z * sc); o4.w = f2bu(v.w * sc);
    *(ushort4*)(out + row * ldout + threadIdx.x * 4) = o4;
}

// ---------------- fp32 -> bf16 cast ----------------
__global__ void k_cast_bf16(const float* __restrict__ in, unsigned short* __restrict__ out, long n4) {
    long i = (long)blockIdx.x * TPB + threadIdx.x;
    if (i >= n4) return;
    float4 v = *(const float4*)(in + i * 4);
    ushort4 o; o.x = f2bu(v.x); o.y = f2bu(v.y); o.z = f2bu(v.z); o.w = f2bu(v.w);
    *(ushort4*)(out + i * 4) = o;
}

// ---------------- transpose-cast: in[R][C] (ld, opt rowscale) -> bf16 out[C][R] ----------------
template<typename TI>
__global__ void k_tcast(const TI* __restrict__ in, long ldi, long sIn,
                        unsigned short* __restrict__ out, long ldo, long sOut,
                        const float* __restrict__ rowscale) {
    __shared__ float tile[64][65];
    const TI* ip = in + (long)blockIdx.z * sIn;
    unsigned short* op = out + (long)blockIdx.z * sOut;
    int r0 = blockIdx.y * 64, c0 = blockIdx.x * 64;
    int tid = threadIdx.x;
    int rr = tid >> 4, cc = (tid & 15) * 4;
    #pragma unroll
    for (int u = 0; u < 4; ++u) {
        int r = rr + u * 16;
        float sc = rowscale ? rowscale[r0 + r] : 1.0f;
        #pragma unroll
        for (int j = 0; j < 4; ++j)
            tile[r][cc + j] = ldval(ip + (long)(r0 + r) * ldi + c0 + cc + j) * sc;
    }
    __syncthreads();
    #pragma unroll
    for (int u = 0; u < 4; ++u) {
        int c = rr + u * 16;
        ushort4 o;
        o.x = f2bu(tile[cc + 0][c]); o.y = f2bu(tile[cc + 1][c]);
        o.z = f2bu(tile[cc + 2][c]); o.w = f2bu(tile[cc + 3][c]);
        *(ushort4*)(op + (long)(c0 + c) * ldo + r0 + cc) = o;
    }
}

// ---------------- fused transpose of o (rowscaled) and a from packed uv ----------------
__global__ void k_tcast2(const float* __restrict__ uv, const float* __restrict__ uscale,
                         unsigned short* __restrict__ t1, unsigned short* __restrict__ t2) {
    __shared__ float tile[64][65];
    int z = blockIdx.z;
    const float* ip = uv + (z ? 1024 : 0);
    unsigned short* op = z ? t2 : t1;
    int r0 = blockIdx.y * 64, c0 = blockIdx.x * 64;
    int tid = threadIdx.x;
    int rr = tid >> 4, cc = (tid & 15) * 4;
    #pragma unroll
    for (int u = 0; u < 4; ++u) {
        int r = rr + u * 16;
        float sc = z ? 1.0f : uscale[r0 + r];
        #pragma unroll
        for (int j = 0; j < 4; ++j)
            tile[r][cc + j] = ip[(long)(r0 + r) * 2048 + c0 + cc + j] * sc;
    }
    __syncthreads();
    #pragma unroll
    for (int u = 0; u < 4; ++u) {
        int c = rr + u * 16;
        ushort4 o;
        o.x = f2bu(tile[cc + 0][c]); o.y = f2bu(tile[cc + 1][c]);
        o.z = f2bu(tile[cc + 2][c]); o.w = f2bu(tile[cc + 3][c]);
        *(ushort4*)(op + (long)(c0 + c) * 4096 + r0 + cc) = o;
    }
}

// ---------------- bf16 MFMA GEMM, NT: C[M,N] = s * A[M,K] @ B[N,K]^T (+add), opt split-K ----------------
template<int WGM, int WGN, int WRITE_BF16>
__global__ __launch_bounds__(256)
void k_bgemm(int K,
             const unsigned short* __restrict__ A, int lda, long sA,
             const unsigned short* __restrict__ B, int ldb, long sB,
             void* __restrict__ C, int ldc, long sCi, long sSplit, int nsplit,
             const float* __restrict__ scale_ptr, float fscale,
             const float* __restrict__ addp, int ldadd) {
    constexpr int TM = WGM * 64, TN = WGN * 64;
    __shared__ unsigned short Asl[TM * 32];
    __shared__ unsigned short Bsl[TN * 32];
    int bz = blockIdx.z;
    int batch = bz, sp = 0;
    if (nsplit > 1) { batch = bz / nsplit; sp = bz - batch * nsplit; }
    int m0 = blockIdx.y * TM, n0 = blockIdx.x * TN;
    const unsigned short* Ap = A + (long)batch * sA + (long)sp * K;
    const unsigned short* Bp = B + (long)batch * sB + (long)sp * K;
    int tid = threadIdx.x, lane = tid & 63, wave = tid >> 6;
    int wr = wave / WGN, wc = wave % WGN;
    f32x4 acc[4][4] = {};
    constexpr int CAW = TM / 64;
    constexpr int CBW = TN / 64;
    for (int k0 = 0; k0 < K; k0 += 32) {
        #pragma unroll
        for (int c = 0; c < CAW; ++c) {
            int bu = (wave * CAW + c) * 64;
            int uidx = bu + lane;
            int r = uidx >> 2, slot = uidx & 3;
            int gu = slot ^ ((r >> 1) & 3);
            gload_lds16(Ap + (long)(m0 + r) * lda + k0 + gu * 8, Asl + bu * 8);
        }
        #pragma unroll
        for (int c = 0; c < CBW; ++c) {
            int bu = (wave * CBW + c) * 64;
            int uidx = bu + lane;
            int r = uidx >> 2, slot = uidx & 3;
            int gu = slot ^ ((r >> 1) & 3);
            gload_lds16(Bp + (long)(n0 + r) * ldb + k0 + gu * 8, Bsl + bu * 8);
        }
        __syncthreads();
        short8 av[4], bv[4];
        #pragma unroll
        for (int m = 0; m < 4; ++m) {
            int r = wr * 64 + m * 16 + (lane & 15);
            int slot = (lane >> 4) ^ ((r >> 1) & 3);
            av[m] = *(const short8*)(Asl + r * 32 + slot * 8);
        }
        #pragma unroll
        for (int n = 0; n < 4; ++n) {
            int r = wc * 64 + n * 16 + (lane & 15);
            int slot = (lane >> 4) ^ ((r >> 1) & 3);
            bv[n] = *(const short8*)(Bsl + r * 32 + slot * 8);
        }
        #pragma unroll
        for (int m = 0; m < 4; ++m)
            #pragma unroll
            for (int n = 0; n < 4; ++n)
                acc[m][n] = __builtin_amdgcn_mfma_f32_16x16x32_bf16(av[m], bv[n], acc[m][n], 0, 0, 0);
        __syncthreads();
    }
    float s = fscale * (scale_ptr ? scale_ptr[0] : 1.0f);
    long cbase = (long)batch * sCi + (long)sp * sSplit;
    int row0 = m0 + wr * 64, col0 = n0 + wc * 64 + (lane & 15);
    int rbase = (lane >> 4) * 4;
    #pragma unroll
    for (int m = 0; m < 4; ++m)
        #pragma unroll
        for (int i = 0; i < 4; ++i) {
            long row = row0 + m * 16 + rbase + i;
            #pragma unroll
            for (int n = 0; n < 4; ++n) {
                long col = col0 + n * 16;
                float v = acc[m][n][i] * s;
                if (addp) v += addp[row * (long)ldadd + col];
                long idx = cbase + row * ldc + col;
                if (WRITE_BF16) ((unsigned short*)C)[idx] = f2bu(v);
                else ((float*)C)[idx] = v;
            }
        }
}

// ---------------- flash-decoding split: lean per-tile softmax ----------------
// item = (bh, strip32, K-chunk of <=8 tiles); 160 items/bh, 5120 waves.
// Per tile: QK mfma -> raw-domain max (one 4-lvl tree) -> defer-max rescale ->
// exp via fma(s,0.125,-m) -> P lds -> PV mfma. Row-sum l deferred to chunk end.
__global__ __launch_bounds__(64)
void k_flash_split(const unsigned short* __restrict__ hq, const unsigned short* __restrict__ hk,
                   const unsigned short* __restrict__ hvT,
                   float* __restrict__ opart, float* __restrict__ mpart, float* __restrict__ lpart) {
    __shared__ unsigned short P[32 * 72];
    int lane = threadIdx.x;
    int g = lane >> 4, c = lane & 15;
    unsigned bid = blockIdx.x;
    unsigned swz = (bid & 7) * 640 + (bid >> 3);        // XCD-bijective: 4 bh per XCD
    unsigned bh = swz / 160, itr = swz % 160;
    int item = 159 - (int)itr;                           // longest chunks first
    int strip, chunk;
    if (item < 16)      { strip = item;                 chunk = 0; }
    else if (item < 48) { strip = 16 + (item - 16) / 2; chunk = (item - 16) & 1; }
    else if (item < 96) { strip = 32 + (item - 48) / 3; chunk = (item - 48) % 3; }
    else                { strip = 48 + (item - 96) / 4; chunk = (item - 96) & 3; }
    int q0 = strip * 32;
    int nt = (q0 + 32 + 63) >> 6;
    int ti0 = chunk * 8;
    int ti1 = ti0 + 8 < nt ? ti0 + 8 : nt;
    const unsigned short* qb = hq + (long)bh * Tc * 64;
    const unsigned short* kb = hk + (long)bh * Tc * 64;
    const unsigned short* vtb = hvT + (long)bh * 64 * Tc;

    short8 qf[2][2];
    #pragma unroll
    for (int mf = 0; mf < 2; ++mf)
        #pragma unroll
        for (int ks = 0; ks < 2; ++ks)
            qf[mf][ks] = *(const short8*)(qb + (long)(q0 + mf * 16 + c) * 64 + ks * 32 + g * 8);

    f32x4 o_acc[2][4] = {};
    float m_run[2][4], lpp[2][4];
    #pragma unroll
    for (int mf = 0; mf < 2; ++mf)
        #pragma unroll
        for (int i = 0; i < 4; ++i) { m_run[mf][i] = -3.0e38f; lpp[mf][i] = 0.f; }

    for (int ti = ti0; ti < ti1; ++ti) {
        int kt = ti * 64;
        // V loads issued early; latency hides under QK + softmax
        short8 vf[2][4];
        #pragma unroll
        for (int ks = 0; ks < 2; ++ks)
            #pragma unroll
            for (int df = 0; df < 4; ++df)
                vf[ks][df] = *(const short8*)(vtb + (long)(df * 16 + c) * Tc + kt + ks * 32 + g * 8);
        f32x4 s_acc[2][4] = {};
        #pragma unroll
        for (int ks = 0; ks < 2; ++ks) {
            short8 kf[4];
            #pragma unroll
            for (int nf = 0; nf < 4; ++nf)
                kf[nf] = *(const short8*)(kb + (long)(kt + nf * 16 + c) * 64 + ks * 32 + g * 8);
            #pragma unroll
            for (int mf = 0; mf < 2; ++mf)
                #pragma unroll
                for (int nf = 0; nf < 4; ++nf)
                    s_acc[mf][nf] = __builtin_amdgcn_mfma_f32_16x16x32_bf16(qf[mf][ks], kf[nf], s_acc[mf][nf], 0, 0, 0);
        }
        // causal mask: only the diagonal tile (global last tile) needs it
        if (ti == nt - 1) {
            #pragma unroll
            for (int mf = 0; mf < 2; ++mf)
                #pragma unroll
                for (int nf = 0; nf < 4; ++nf)
                    #pragma unroll
                    for (int i = 0; i < 4; ++i)
                        if ((kt + nf * 16 + c) > (q0 + mf * 16 + g * 4 + i)) s_acc[mf][nf][i] = -1.0e30f;
        }
        // raw-domain row max: in-lane over nf, then one 4-level tree over 16 lanes
        float pm[2][4];
        #pragma unroll
        for (int mf = 0; mf < 2; ++mf)
            #pragma unroll
            for (int i = 0; i < 4; ++i)
                pm[mf][i] = fmaxf(fmaxf(s_acc[mf][0][i], s_acc[mf][1][i]),
                                  fmaxf(s_acc[mf][2][i], s_acc[mf][3][i]));
        #pragma unroll
        for (int lvl = 1; lvl <= 8; lvl <<= 1)
            #pragma unroll
            for (int mf = 0; mf < 2; ++mf)
                #pragma unroll
                for (int i = 0; i < 4; ++i)
                    pm[mf][i] = fmaxf(pm[mf][i], __shfl_xor(pm[mf][i], lvl));
        // defer-max: rescale only if any row's scaled max grew beyond m_run + 8
        float mg = 0.f;
        #pragma unroll
        for (int mf = 0; mf < 2; ++mf)
            #pragma unroll
            for (int i = 0; i < 4; ++i) {
                pm[mf][i] *= 0.125f;
                mg = fmaxf(mg, pm[mf][i] - m_run[mf][i]);
            }
        if (__any(mg > 8.0f)) {
            #pragma unroll
            for (int mf = 0; mf < 2; ++mf)
                #pragma unroll
                for (int i = 0; i < 4; ++i) {
                    float mn = fmaxf(m_run[mf][i], pm[mf][i]);
                    float corr = __expf(m_run[mf][i] - mn);
                    m_run[mf][i] = mn;
                    lpp[mf][i] *= corr;
                    #pragma unroll
                    for (int df = 0; df < 4; ++df) o_acc[mf][df][i] *= corr;
                }
        }
        // exp (scale folded into fma) + P store + per-lane l accumulate (no tree here)
        #pragma unroll
        for (int mf = 0; mf < 2; ++mf)
            #pragma unroll
            for (int nf = 0; nf < 4; ++nf)
                #pragma unroll
                for (int i = 0; i < 4; ++i) {
                    float p = __expf(fmaf(s_acc[mf][nf][i], 0.125f, -m_run[mf][i]));
                    P[(mf * 16 + g * 4 + i) * 72 + nf * 16 + c] = f2bu(p);
                    lpp[mf][i] += p;
                }
        // PV
        #pragma unroll
        for (int ks = 0; ks < 2; ++ks) {
            short8 pa[2];
            #pragma unroll
            for (int mf = 0; mf < 2; ++mf)
                pa[mf] = *(const short8*)(P + (mf * 16 + c) * 72 + ks * 32 + g * 8);
            #pragma unroll
            for (int mf = 0; mf < 2; ++mf)
                #pragma unroll
                for (int df = 0; df < 4; ++df)
                    o_acc[mf][df] = __builtin_amdgcn_mfma_f32_16x16x32_bf16(pa[mf], vf[ks][df], o_acc[mf][df], 0, 0, 0);
        }
    }
    // one l-sum tree for the whole chunk
    #pragma unroll
    for (int lvl = 1; lvl <= 8; lvl <<= 1)
        #pragma unroll
        for (int mf = 0; mf < 2; ++mf)
            #pragma unroll
            for (int i = 0; i < 4; ++i)
                lpp[mf][i] += __shfl_xor(lpp[mf][i], lvl);
    long pbase = (long)(bh * 160 + item);
    #pragma unroll
    for (int mf = 0; mf < 2; ++mf)
        #pragma unroll
        for (int i = 0; i < 4; ++i) {
            int row_l = mf * 16 + g * 4 + i;
            #pragma unroll
            for (int df = 0; df < 4; ++df)
                opart[pbase * 2048 + row_l * 64 + df * 16 + c] = o_acc[mf][df][i];
            if (c == 0) {
                mpart[pbase * 32 + row_l] = m_run[mf][i];
                lpart[pbase * 32 + row_l] = lpp[mf][i];
            }
        }
}

// ---------------- flash merge: combine <=4 partials per (bh,strip) -> bf16 y ----------------
__global__ __launch_bounds__(256)
void k_flash_merge(const float* __restrict__ opart, const float* __restrict__ mpart,
                   const float* __restrict__ lpart, unsigned short* __restrict__ yout) {
    int bs = blockIdx.x;
    int bh = bs >> 6, strip = bs & 63;
    int b = bh >> 4, h = bh & 15;
    int np, base;
    if (strip < 16)      { np = 1; base = strip; }
    else if (strip < 32) { np = 2; base = 16 + (strip - 16) * 2; }
    else if (strip < 48) { np = 3; base = 48 + (strip - 32) * 3; }
    else                 { np = 4; base = 96 + (strip - 48) * 4; }
    long p0 = (long)(bh * 160 + base);
    int tid = threadIdx.x;
    int r = tid >> 3, c0 = (tid & 7) * 8;
    float M = -3.0e38f;
    for (int p = 0; p < np; ++p) M = fmaxf(M, mpart[(p0 + p) * 32 + r]);
    float L = 0.f;
    float acc[8] = {};
    for (int p = 0; p < np; ++p) {
        float sc = __expf(mpart[(p0 + p) * 32 + r] - M);
        L += lpart[(p0 + p) * 32 + r] * sc;
        const float* op = opart + (p0 + p) * 2048 + r * 64 + c0;
        #pragma unroll
        for (int j = 0; j < 8; ++j) acc[j] += op[j] * sc;
    }
    float inv = 1.0f / L;
    long row = (long)b * Tc + strip * 32 + r;
    unsigned short* yp = yout + row * 1024 + h * 64 + c0;
    ushort4 o1, o2;
    o1.x = f2bu(acc[0] * inv); o1.y = f2bu(acc[1] * inv); o1.z = f2bu(acc[2] * inv); o1.w = f2bu(acc[3] * inv);
    o2.x = f2bu(acc[4] * inv); o2.y = f2bu(acc[5] * inv); o2.z = f2bu(acc[6] * inv); o2.w = f2bu(acc[7] * inv);
    *(ushort4*)yp = o1;
    *(ushort4*)(yp + 4) = o2;
}

// ---------------- AFT gated cumsum: chunk totals, then p3 with inline prefix ----------------
__global__ void k_aft_p1(const float* __restrict__ qkv, float* __restrict__ cw, float* __restrict__ cs) {
    int id = blockIdx.x * TPB + threadIdx.x;
    int bc = id & 2047, ch = id >> 11;
    int b = bc >> 10, c = bc & 1023;
    const float* base = qkv + ((long)(b * Tc + ch * CHL)) * 3072 + c;
    float sw = 0.f, sv = 0.f;
    for (int i = 0; i < CHL; ++i) {
        float k = base[1024], v = base[2048];
        float e = __expf(k);
        sw += e; sv += e * v;
        base += 3072;
    }
    cw[ch * 2048 + bc] = sw; cs[ch * 2048 + bc] = sv;
}

__global__ void k_aft_p3(const float* __restrict__ qkv, const float* __restrict__ cw,
                         const float* __restrict__ cs, unsigned short* __restrict__ y) {
    int id = blockIdx.x * TPB + threadIdx.x;
    int bc = id & 2047, ch = id >> 11;
    int b = bc >> 10, c = bc & 1023;
    float aw = 0.f, av = 0.f;
    for (int cc = 0; cc < ch; ++cc) { aw += cw[cc * 2048 + bc]; av += cs[cc * 2048 + bc]; }
    long t0 = (long)b * Tc + ch * CHL;
    const float* base = qkv + t0 * 3072 + c;
    unsigned short* yp = y + t0 * 1024 + c;
    for (int i = 0; i < CHL; ++i) {
        float q = base[0], k = base[1024], v = base[2048];
        float e = __expf(k);
        av += e * v; aw += e;
        float sig = 1.0f / (1.0f + __expf(-q));
        yp[0] = f2bu(sig * av / (aw + 1e-6f));
        base += 3072; yp += 1024;
    }
}

// ---------------- fused u*silu(v) -> bf16 + rowrms(u) (block per row) ----------------
__global__ void k_silu_rms(const float* __restrict__ uv, unsigned short* __restrict__ g,
                           float* __restrict__ rs) {
    __shared__ float red[TPB];
    long row = blockIdx.x;
    const float* up = uv + row * 2048;
    float4 u = *(const float4*)(up + threadIdx.x * 4);
    float4 v = *(const float4*)(up + 1024 + threadIdx.x * 4);
    ushort4 o;
    o.x = f2bu(u.x * v.x / (1.f + __expf(-v.x)));
    o.y = f2bu(u.y * v.y / (1.f + __expf(-v.y)));
    o.z = f2bu(u.z * v.z / (1.f + __expf(-v.z)));
    o.w = f2bu(u.w * v.w / (1.f + __expf(-v.w)));
    *(ushort4*)(g + row * 1024 + threadIdx.x * 4) = o;
    red[threadIdx.x] = u.x * u.x + u.y * u.y + u.z * u.z + u.w * u.w;
    __syncthreads();
    for (int off = 128; off > 0; off >>= 1) {
        if (threadIdx.x < off) red[threadIdx.x] += red[threadIdx.x + off];
        __syncthreads();
    }
    if (threadIdx.x == 0) rs[row] = rsqrtf(red[0] / 1024.0f + F32_EPS);
}

// ---------------- u * silu(v) -> bf16 (final swiglu) ----------------
__global__ void k_silu_gate(const float* __restrict__ uv, unsigned short* __restrict__ g, long n4) {
    long i = (long)blockIdx.x * TPB + threadIdx.x;
    if (i >= n4) return;
    long r = i >> 8, c4 = i & 255;
    float4 u = *(const float4*)(uv + r * 2048 + c4 * 4);
    float4 v = *(const float4*)(uv + r * 2048 + 1024 + c4 * 4);
    ushort4 o;
    o.x = f2bu(u.x * v.x / (1.f + __expf(-v.x)));
    o.y = f2bu(u.y * v.y / (1.f + __expf(-v.y)));
    o.z = f2bu(u.z * v.z / (1.f + __expf(-v.z)));
    o.w = f2bu(u.w * v.w / (1.f + __expf(-v.w)));
    *(ushort4*)(g + r * 1024 + c4 * 4) = o;
}

// ---------------- w_out = p*s*silu(w_in) + w_in  (also emits bf16 copy) ----------------
__global__ void k_wupdate(float* __restrict__ wout, const float* __restrict__ win,
                          const float* __restrict__ p, const float* __restrict__ scale,
                          unsigned short* __restrict__ wb, long n4) {
    long i = (long)blockIdx.x * TPB + threadIdx.x;
    if (i >= n4) return;
    float s = scale[0];
    float4 wv = *(const float4*)(win + i * 4);
    float4 pv = *(const float4*)(p + i * 4);
    float4 o;
    o.x = pv.x * s * (wv.x / (1.f + __expf(-wv.x))) + wv.x;
    o.y = pv.y * s * (wv.y / (1.f + __expf(-wv.y))) + wv.y;
    o.z = pv.z * s * (wv.z / (1.f + __expf(-wv.z))) + wv.z;
    o.w = pv.w * s * (wv.w / (1.f + __expf(-wv.w))) + wv.w;
    *(float4*)(wout + i * 4) = o;
    ushort4 ob; ob.x = f2bu(o.x); ob.y = f2bu(o.y); ob.z = f2bu(o.z); ob.w = f2bu(o.w);
    *(ushort4*)(wb + i * 4) = ob;
}

// ---------------- 4-slab reduce + scale + row softmax -> fp32 out ----------------
__global__ void k_softmax4(const float* __restrict__ parts, float* __restrict__ outb, float fscale) {
    __shared__ float red[TPB];
    __shared__ float rowbuf[1024];
    long row = blockIdx.x;
    const float* p0 = parts + row * 1024;
    for (int c = threadIdx.x; c < 1024; c += TPB) {
        float v = p0[c] + p0[c + 1048576] + p0[c + 2097152] + p0[c + 3145728];
        rowbuf[c] = v * fscale;
    }
    __syncthreads();
    float m = -3.0e38f;
    for (int c = threadIdx.x; c < 1024; c += TPB) m = fmaxf(m, rowbuf[c]);
    red[threadIdx.x] = m; __syncthreads();
    for (int o = 128; o > 0; o >>= 1) {
        if (threadIdx.x < o) red[threadIdx.x] = fmaxf(red[threadIdx.x], red[threadIdx.x + o]);
        __syncthreads();
    }
    m = red[0]; __syncthreads();
    float sum = 0.f;
    for (int c = threadIdx.x; c < 1024; c += TPB) sum += __expf(rowbuf[c] - m);
    red[threadIdx.x] = sum; __syncthreads();
    for (int o = 128; o > 0; o >>= 1) {
        if (threadIdx.x < o) red[threadIdx.x] += red[threadIdx.x + o];
        __syncthreads();
    }
    float inv = 1.0f / red[0];
    for (int c = threadIdx.x; c < 1024; c += TPB)
        outb[row * 1024 + c] = __expf(rowbuf[c] - m) * inv;
}

// ---------------- tea: rotary + per-head rmsnorm + split, bf16 out ----------------
__global__ void k_rot_split(const float* __restrict__ qkvp, const float* __restrict__ cosp,
                            const float* __restrict__ sinp, unsigned short* __restrict__ hq,
                            unsigned short* __restrict__ hk, unsigned short* __restrict__ hv) {
    __shared__ float row[3072];
    __shared__ float cs[32], sn[32];
    int bt = blockIdx.x;
    int b = bt >> 11, t = bt & 2047;
    const float* src = qkvp + (long)bt * 3072;
    #pragma unroll
    for (int u = 0; u < 3; ++u) {
        int idx = threadIdx.x + u * 256;
        *(float4*)&row[idx * 4] = *(const float4*)(src + idx * 4);
    }
    if (threadIdx.x < 32) { cs[threadIdx.x] = cosp[t * 32 + threadIdx.x]; sn[threadIdx.x] = sinp[t * 32 + threadIdx.x]; }
    __syncthreads();
    int h = threadIdx.x >> 4, li = threadIdx.x & 15;
    int base = h * 192;
    long obase = ((long)(b * Hc + h) * Tc + t) * 64 + li * 4;
    {
        float r[4]; float ss = 0.f;
        #pragma unroll
        for (int j = 0; j < 4; ++j) {
            int d = li * 4 + j;
            float val = (d < 32) ? (row[base + d] * cs[d] + row[base + d + 32] * sn[d])
                                 : (-row[base + d - 32] * sn[d - 32] + row[base + d] * cs[d - 32]);
            r[j] = val; ss += val * val;
        }
        ss += __shfl_xor(ss, 1); ss += __shfl_xor(ss, 2); ss += __shfl_xor(ss, 4); ss += __shfl_xor(ss, 8);
        float sc = rsqrtf(ss / 64.0f + F32_EPS);
        ushort4 o; o.x = f2bu(r[0] * sc); o.y = f2bu(r[1] * sc); o.z = f2bu(r[2] * sc); o.w = f2bu(r[3] * sc);
        *(ushort4*)(hq + obase) = o;
    }
    {
        int kb = base + 64;
        float r[4]; float ss = 0.f;
        #pragma unroll
        for (int j = 0; j < 4; ++j) {
            int d = li * 4 + j;
            float val = (d < 32) ? (row[kb + d] * cs[d] + row[kb + d + 32] * sn[d])
                                 : (-row[kb + d - 32] * sn[d - 32] + row[kb + d] * cs[d - 32]);
            r[j] = val; ss += val * val;
        }
        ss += __shfl_xor(ss, 1); ss += __shfl_xor(ss, 2); ss += __shfl_xor(ss, 4); ss += __shfl_xor(ss, 8);
        float sc = rsqrtf(ss / 64.0f + F32_EPS);
        ushort4 o; o.x = f2bu(r[0] * sc); o.y = f2bu(r[1] * sc); o.z = f2bu(r[2] * sc); o.w = f2bu(r[3] * sc);
        *(ushort4*)(hk + obase) = o;
    }
    {
        ushort4 o;
        o.x = f2bu(row[base + 128 + li * 4 + 0]); o.y = f2bu(row[base + 128 + li * 4 + 1]);
        o.z = f2bu(row[base + 128 + li * 4 + 2]); o.w = f2bu(row[base + 128 + li * 4 + 3]);
        *(ushort4*)(hv + obase) = o;
    }
}

extern "C" void kernel_launch(void* const* d_in, const int* in_sizes, int n_in,
                              void* d_out, int out_size, void* d_ws, size_t ws_size,
                              hipStream_t stream) {
    const float* x_in = (const float*)d_in[0];
    const float* w_in = (const float*)d_in[1];
    const float* cos_in = (const float*)d_in[2];
    const float* sin_in = (const float*)d_in[3];
    float* out = (float*)d_out;
    float* ws = (float*)d_ws;

    long off = 0;
    float* w_cur = ws + off;  off += (long)WR * Ec;
    float* w_tmp = ws + off;  off += (long)WR * Ec;   // also: oa split-K partials (4M floats)
    float* xbuf  = ws + off;  off += BT * Ec;
    float* qkv   = ws + off;  off += BT * 3L * QKVc;  // also: uv fp32 | flash o-partials (10.5M)
    float* oab   = ws + off;  off += (long)Ec * Ec;   // also: flash m/l partials (327K)
    float* red   = ws + off;  off += 2048;
    float* scales= ws + off;  off += 16;
    float* uscale= ws + off;  off += 4096;
    float* chw   = ws + off;  off += 2048L * NCH;
    float* chs   = ws + off;  off += 2048L * NCH;
    float* uv    = qkv;
    float* opart = qkv;
    float* mpart = oab;
    float* lpart = oab + 5120L * 32;

    unsigned short* bp = (unsigned short*)(ws + off);
    long bo = 0;
    unsigned short* wb  = bp + bo; bo += (long)WR * Ec;
    unsigned short* xbn = bp + bo; bo += BT * Ec;
    unsigned short* ybn = bp + bo; bo += BT * Ec;
    unsigned short* gbn = bp + bo; bo += BT * Ec;
    unsigned short* t1  = bp + bo; bo += BT * Ec;            // o^T | hq
    unsigned short* t2  = bp + bo; bo += BT * Ec;            // v^T | hk
    unsigned short* t3  = bp + bo; bo += BT * Ec;            // oa^T | hvS
    unsigned short* t4  = bp + bo; bo += BT * Ec;            // hvT

    const float rsWR = 1.0f / sqrtf(6144.0f);
    const long wsw = 3072L * 1024, wout = 5120L * 1024;

    // one-time bf16 copy of w (from input)
    k_cast_bf16<<<(int)(((long)WR * Ec / 4) / TPB), TPB, 0, stream>>>(w_in, wb, (long)WR * Ec / 4);

    for (int layer = 0; layer < 2; ++layer) {
        const float* wsrc = layer == 0 ? w_in : w_cur;   // fp32 weights
        const float* xsrc = layer == 0 ? x_in : xbuf;    // fp32 activations
        k_std_partial3<<<dim3(256, 3), TPB, 0, stream>>>(wsrc, red);
        k_std_final3<<<1, TPB, 0, stream>>>(red, scales);
        k_rms1024b<<<BT, TPB, 0, stream>>>(xsrc, xbn, 1024, 1024);
        k_bgemm<2, 2, 0><<<dim3(24, 32, 1), TPB, 0, stream>>>(
            1024, xbn, 1024, 0, wb, 1024, 0, qkv, 3072, 0, 0, 1, scales + 0, 1.0f, nullptr, 0);
        k_rms_qk<<<8192, TPB, 0, stream>>>(qkv);
        k_aft_p1<<<(2048 * NCH) / TPB, TPB, 0, stream>>>(qkv, chw, chs);
        k_aft_p3<<<(2048 * NCH) / TPB, TPB, 0, stream>>>(qkv, chw, chs, ybn);
        k_bgemm<2, 2, 0><<<dim3(16, 32, 1), TPB, 0, stream>>>(
            1024, ybn, 1024, 0, wb + wsw, 1024, 0, uv, 2048, 0, 0, 1, scales + 1, 1.0f, nullptr, 0);
        k_silu_rms<<<BT, TPB, 0, stream>>>(uv, gbn, uscale);
        k_tcast2<<<dim3(16, 64, 2), TPB, 0, stream>>>(uv, uscale, t1, t2);
        // oa = softmax(o^T @ a * E^-0.5), split-K x4 into w_tmp partials
        k_bgemm<2, 2, 0><<<dim3(8, 8, 4), TPB, 0, stream>>>(
            1024, t1, 4096, 0, t2, 4096, 0, w_tmp, 1024, 0, 1048576L, 4, nullptr, 1.0f, nullptr, 0);
        k_softmax4<<<1024, TPB, 0, stream>>>(w_tmp, oab, 0.03125f);
        k_tcast<float><<<dim3(16, 16, 1), TPB, 0, stream>>>(oab, 1024, 0, t3, 1024, 0, nullptr);
        k_bgemm<2, 2, 0><<<dim3(8, 32, 1), TPB, 0, stream>>>(
            1024, gbn, 1024, 0, wb + wout, 1024, 0, xbuf, 1024, 0, 0, 1, scales + 2, 1.0f, xsrc, 1024);
        k_bgemm<2, 2, 0><<<dim3(8, 48, 1), TPB, 0, stream>>>(
            1024, wb, 1024, 0, t3, 1024, 0, w_tmp, 1024, 0, 0, 1, nullptr, 1.0f, nullptr, 0);
        k_std_partial<<<256, TPB, 0, stream>>>(w_tmp, (long)WR * 1024, red);
        k_std_final<<<1, TPB, 0, stream>>>(red, (float)((long)WR * 1024), rsWR, scales + 3);
        k_wupdate<<<(int)(((long)WR * 1024 / 4) / TPB), TPB, 0, stream>>>(
            w_cur, wsrc, w_tmp, scales + 3, wb, (long)WR * 1024 / 4);
    }

    // -------- final tea (no w_norm) --------
    k_rms1024b<<<BT, TPB, 0, stream>>>(xbuf, xbn, 1024, 1024);
    k_bgemm<2, 2, 0><<<dim3(24, 32, 1), TPB, 0, stream>>>(
        1024, xbn, 1024, 0, wb, 1024, 0, qkv, 3072, 0, 0, 1, nullptr, 1.0f, nullptr, 0);
    k_rot_split<<<BT, TPB, 0, stream>>>(qkv, cos_in, sin_in, t1, t2, t3);
    k_tcast<unsigned short><<<dim3(1, 32, 32), TPB, 0, stream>>>(
        t3, 64, (long)Tc * 64, t4, 2048, (long)Tc * 64, nullptr);
    // flash-decoding: 5120 split items, then merge (qkv region is dead -> partials)
    k_flash_split<<<dim3(5120), 64, 0, stream>>>(t1, t2, t4, opart, mpart, lpart);
    k_flash_merge<<<dim3(2048), TPB, 0, stream>>>(opart, mpart, lpart, ybn);
    // final swiglu -> d_out
    k_bgemm<2, 2, 0><<<dim3(16, 32, 1), TPB, 0, stream>>>(
        1024, ybn, 1024, 0, wb + wsw, 1024, 0, uv, 2048, 0, 0, 1, nullptr, 1.0f, nullptr, 0);
    k_silu_gate<<<(int)((BT * 1024 / 4) / TPB), TPB, 0, stream>>>(uv, gbn, BT * 1024 / 4);
    k_bgemm<2, 2, 0><<<dim3(8, 32, 1), TPB, 0, stream>>>(
        1024, gbn, 1024, 0, wb + wout, 1024, 0, out, 1024, 0, 0, 1, nullptr, 1.0f, xbuf, 1024);
}